// Round 18
// baseline (1181.310 us; speedup 1.0000x reference)
//
#include <hip/hip_runtime.h>
#include <math.h>
#include <type_traits>

typedef __bf16 bf16_t;
typedef bf16_t bf16x4 __attribute__((ext_vector_type(4)));
typedef bf16_t bf16x8 __attribute__((ext_vector_type(8)));
typedef float  f32x4  __attribute__((ext_vector_type(4)));

#define RMS_EPS 1e-6f

enum { EP_STORE = 0, EP_RESID = 1, EP_SPLIT = 2, EP_SILU = 3, EP_QKV = 4 };

template<int V> using IC = std::integral_constant<int, V>;

static __device__ __forceinline__ f32x4 mfma16(bf16x8 a, bf16x8 b, f32x4 c) {
    return __builtin_amdgcn_mfma_f32_16x16x32_bf16(a, b, c, 0, 0, 0);
}

#define GLDS(gp, lp) __builtin_amdgcn_global_load_lds( \
    (const __attribute__((address_space(1))) void*)(gp), \
    (__attribute__((address_space(3))) void*)(lp), 16, 0, 0)

// counted vector-memory wait (T4): leave N newest loads in flight.
template<int N> static __device__ __forceinline__ void vmwait() {
    if constexpr (N == 0)      asm volatile("s_waitcnt vmcnt(0)" ::: "memory");
    else if constexpr (N == 2) asm volatile("s_waitcnt vmcnt(2)" ::: "memory");
    else if constexpr (N == 3) asm volatile("s_waitcnt vmcnt(3)" ::: "memory");
    else if constexpr (N == 4) asm volatile("s_waitcnt vmcnt(4)" ::: "memory");
    else if constexpr (N == 6) asm volatile("s_waitcnt vmcnt(6)" ::: "memory");
    else if constexpr (N == 8) asm volatile("s_waitcnt vmcnt(8)" ::: "memory");
    __builtin_amdgcn_sched_barrier(0);
}
static __device__ __forceinline__ void bar() { __builtin_amdgcn_s_barrier(); }
static __device__ __forceinline__ void lgkm0() {
    asm volatile("s_waitcnt lgkmcnt(0)" ::: "memory");
    __builtin_amdgcn_sched_barrier(0);   // rule #18: fence MFMA hoisting
}

// C[M,N] = A[M,K]*B[N,K]^T.
// PLANES==2: A split hi/lo, B hi-only (2 MFMAs).  PLANES==1: pure bf16.
// WR x WC wave grid. Counted-vmcnt pipelined K-loop, DEPTH buffers.
// EP_SILU: B is wGU interleaved; even lanes write silu(g)*u at col>>1.
// EP_QKV : fused qk-RMSnorm + RoPE epilogue (wave's WN=64 col span = one head);
//          q/k -> Ch (cols [0,2048)); v written TRANSPOSED: hi -> Cl (= vTh),
//          lo -> (bf16_t*)Cf (= vTl). Per-thread 8-byte contiguous runs.
//          Rope quirk: angle = head_index * freq (reference's cos[:n], n=H).
// blockIdx.z = K-chunk for split-K.
template<int BM, int BN, int WR, int WC, int PLANES, int EPIL, int MINW, int DEPTH>
__global__ __launch_bounds__(WR * WC * 64, MINW)
void gemm_bf16(const bf16_t* __restrict__ Ah, const bf16_t* __restrict__ Al,
               const bf16_t* __restrict__ Bh,
               float* __restrict__ Cf, bf16_t* __restrict__ Ch, bf16_t* __restrict__ Cl,
               int K, int lda, int ldb, int ldc, long long sC,
               const float* __restrict__ qnw, const float* __restrict__ knw)
{
    constexpr int ASZ = BM * 32, BSZ = BN * 32;
    constexpr int NW = WR * WC;
    constexpr int NLD = (BM / 16 * (PLANES >= 2 ? 2 : 1) + BN / 16) / NW;
    __shared__ __align__(16) bf16_t sAh[DEPTH][ASZ], sBh[DEPTH][BSZ];
    __shared__ __align__(16) bf16_t sAl[PLANES >= 2 ? DEPTH : 1][PLANES >= 2 ? ASZ : 8];

    const int gx = gridDim.x;
    int id = blockIdx.x + gx * blockIdx.y;
    if (gridDim.z == 1) {  // bijective XCD swizzle (m204)
        int nwg = gx * gridDim.y;
        int q = nwg >> 3, r = nwg & 7;
        int xcd = id & 7, ix = id >> 3;
        id = (xcd < r ? xcd * (q + 1) : r * (q + 1) + (xcd - r) * q) + ix;
    }
    const int bm = id % gx, bn = id / gx;
    const int row0 = bm * BM, col0 = bn * BN;

    const size_t kofs = (size_t)blockIdx.z * K;
    Ah += kofs;  Bh += kofs;
    if constexpr (PLANES >= 2) Al += kofs;

    const int tid = threadIdx.x, lane = tid & 63, wave = tid >> 6;
    const int lr = lane & 15, lg = lane >> 4;
    constexpr int WM = BM / WR, WN = BN / WC, MF = WM / 16, NF = WN / 16;
    const int wr = wave / WC, wc = wave % WC;

    f32x4 acc[MF][NF];
    #pragma unroll
    for (int m = 0; m < MF; ++m)
        #pragma unroll
        for (int n = 0; n < NF; ++n) acc[m][n] = (f32x4){0.f, 0.f, 0.f, 0.f};

    auto stage = [&](int k0, int p) {
        #pragma unroll
        for (int i = wave; i < BM / 16; i += NW) {
            int s = i * 64 + lane, rr = s >> 2, c = s & 3;
            size_t go = (size_t)(row0 + rr) * lda + k0 + ((c ^ ((rr >> 1) & 3)) << 3);
            GLDS(Ah + go, &sAh[p][i * 512]);
            if constexpr (PLANES >= 2) GLDS(Al + go, &sAl[p][i * 512]);
        }
        #pragma unroll
        for (int i = wave; i < BN / 16; i += NW) {
            int s = i * 64 + lane, rr = s >> 2, c = s & 3;
            size_t go = (size_t)(col0 + rr) * ldb + k0 + ((c ^ ((rr >> 1) & 3)) << 3);
            GLDS(Bh + go, &sBh[p][i * 512]);
        }
    };

    auto compute = [&](int p) {
        bf16x8 ahf[MF], alf[MF], bhf[NF];
        #pragma unroll
        for (int m = 0; m < MF; ++m) {
            int rr = wr * WM + m * 16 + lr;
            int by = rr * 64 + ((lg ^ ((rr >> 1) & 3)) << 4);
            ahf[m] = *(const bf16x8*)((const char*)&sAh[p][0] + by);
            if constexpr (PLANES >= 2)
                alf[m] = *(const bf16x8*)((const char*)&sAl[p][0] + by);
        }
        #pragma unroll
        for (int n = 0; n < NF; ++n) {
            int rr = wc * WN + n * 16 + lr;
            int by = rr * 64 + ((lg ^ ((rr >> 1) & 3)) << 4);
            bhf[n] = *(const bf16x8*)((const char*)&sBh[p][0] + by);
        }
        __builtin_amdgcn_s_setprio(1);
        #pragma unroll
        for (int m = 0; m < MF; ++m)
            #pragma unroll
            for (int n = 0; n < NF; ++n) {
                acc[m][n] = mfma16(ahf[m], bhf[n], acc[m][n]);
                if constexpr (PLANES >= 2)
                    acc[m][n] = mfma16(alf[m], bhf[n], acc[m][n]);
            }
        __builtin_amdgcn_s_setprio(0);
    };

    if constexpr (DEPTH == 3) {
        const int NC = K >> 5;          // 32-wide chunks
        stage(0, 0);
        stage(32, 1);
        for (int j = 0; j + 2 < NC; ++j) {
            stage(32 * (j + 2), (j + 2) % 3);
            vmwait<2 * NLD>(); bar();   // chunk j landed; j+1, j+2 in flight
            compute(j % 3);
            bar();                      // protect buf before next stage overwrites
        }
        vmwait<NLD>(); bar();
        compute((K >> 5) >= 2 ? ((K >> 5) - 2) % 3 : 0);
        vmwait<0>(); bar();
        compute(((K >> 5) - 1) % 3);
    } else {
        stage(0, 0);
        int k0 = 32;
        for (; k0 + 32 < K; k0 += 64) {
            stage(k0, 1);
            vmwait<NLD>(); bar();
            compute(0);
            bar();
            stage(k0 + 32, 0);
            vmwait<NLD>(); bar();
            compute(1);
            bar();
        }
        stage(k0, 1);
        vmwait<NLD>(); bar();
        compute(0);
        bar();
        vmwait<0>(); bar();
        compute(1);
    }

    if constexpr (EPIL == EP_QKV) {
        // wave's col span = [colbase, colbase+64) = one head-dim group
        const int colbase = col0 + wc * WN;          // multiple of 64
        const int typ = colbase >> 10;               // 0=q, 1=k, 2=v
        if (typ < 2) {
            const float* nw = (typ == 0) ? qnw : knw;
            const int hh = (colbase - typ * 1024) >> 6;  // head idx
            constexpr float kLogF = -0.41524101186092029f;  // -log2(10000)/32
            #pragma unroll
            for (int m = 0; m < MF; ++m)
                #pragma unroll
                for (int r = 0; r < 4; ++r) {
                    int grow = row0 + wr * WM + m * 16 + lg * 4 + r;
                    float ss = 0.f;
                    #pragma unroll
                    for (int n = 0; n < NF; ++n) {
                        float v = acc[m][n][r];
                        ss += v * v;
                    }
                    ss += __shfl_xor(ss, 1, 64);
                    ss += __shfl_xor(ss, 2, 64);
                    ss += __shfl_xor(ss, 4, 64);
                    ss += __shfl_xor(ss, 8, 64);
                    float inv = rsqrtf(ss * (1.0f / 64.0f) + RMS_EPS);
                    #pragma unroll
                    for (int n = 0; n < NF; ++n) {
                        int i = n * 16 + lr;
                        float x = acc[m][n][r] * inv * nw[i];
                        float p = __shfl_xor(x, 1, 64);
                        float f = exp2f((float)(i >> 1) * kLogF);
                        float ang = (float)hh * f;
                        float cs = cosf(ang), sn = sinf(ang);
                        float o = (lr & 1) ? (p * sn + x * cs) : (x * cs - p * sn);
                        Ch[(size_t)grow * ldc + colbase + i] = (bf16_t)o;
                    }
                }
        } else {
            // v: write TRANSPOSED planes (vT[vc][grow..grow+3], 8B runs)
            bf16_t* vTh_ = Cl;
            bf16_t* vTl_ = (bf16_t*)Cf;
            const int vcb = colbase - 2048;
            #pragma unroll
            for (int m = 0; m < MF; ++m)
                #pragma unroll
                for (int n = 0; n < NF; ++n) {
                    int vc = vcb + n * 16 + lr;
                    int grow0 = row0 + wr * WM + m * 16 + lg * 4;
                    bf16x4 hv, lv;
                    #pragma unroll
                    for (int r = 0; r < 4; ++r) {
                        float v = acc[m][n][r];
                        bf16_t hb = (bf16_t)v;
                        hv[r] = hb;
                        lv[r] = (bf16_t)(v - (float)hb);
                    }
                    *(bf16x4*)&vTh_[(size_t)vc * 1024 + grow0] = hv;
                    *(bf16x4*)&vTl_[(size_t)vc * 1024 + grow0] = lv;
                }
        }
        return;
    }

    #pragma unroll
    for (int m = 0; m < MF; ++m)
        #pragma unroll
        for (int n = 0; n < NF; ++n)
            #pragma unroll
            for (int r = 0; r < 4; ++r) {
                int grow = row0 + wr * WM + m * 16 + lg * 4 + r;
                int gcol = col0 + wc * WN + n * 16 + lr;
                float v = acc[m][n][r];
                if constexpr (EPIL == EP_SILU) {
                    float pv = __shfl_xor(v, 1, 64);   // partner column (g,u pair)
                    if (!(lr & 1)) {
                        float s = (v / (1.0f + __expf(-v))) * pv;
                        size_t off = (size_t)grow * ldc + (gcol >> 1);
                        Ch[off] = (bf16_t)s;
                    }
                } else {
                    size_t off = (size_t)blockIdx.z * sC + (size_t)grow * ldc + gcol;
                    if constexpr (EPIL == EP_STORE) {
                        Cf[off] = v;
                    } else if constexpr (EPIL == EP_RESID) {
                        Cf[off] += v;
                    } else {  // EP_SPLIT
                        bf16_t hb = (bf16_t)v;
                        Ch[off] = hb;
                        Cl[off] = (bf16_t)(v - (float)hb);
                    }
                }
            }
}

// Logits GEMM, phase-split deep pipeline (T3+T4+T5): 256x256 tile, 8 waves,
// K-tile=64 = 2 ks-chunks of 32 in the proven [256][32] XOR-swizzled layout.
// LDS 128 KB double-buffered; vmcnt(8) counted waits (never drains mid-loop).
__global__ __launch_bounds__(512, 2)
void gemm_logits8(const bf16_t* __restrict__ Ah, const bf16_t* __restrict__ Bh,
                  float* __restrict__ Cf)
{
    constexpr int lda = 1024, ldb = 1024, ldc = 32000;
    constexpr int NT = 16;   // K-tiles of 64
    __shared__ __align__(16) bf16_t sA[2][2][256 * 32];
    __shared__ __align__(16) bf16_t sB[2][2][256 * 32];

    const int gx = gridDim.x;
    int id = blockIdx.x + gx * blockIdx.y;
    {   // bijective XCD swizzle
        int nwg = gx * gridDim.y;
        int q = nwg >> 3, r = nwg & 7;
        int xcd = id & 7, ix = id >> 3;
        id = (xcd < r ? xcd * (q + 1) : r * (q + 1) + (xcd - r) * q) + ix;
    }
    const int bm = id % gx, bn = id / gx;
    const int row0 = bm * 256, col0 = bn * 256;

    const int tid = threadIdx.x, lane = tid & 63, wave = tid >> 6;
    const int lr = lane & 15, lg = lane >> 4;
    const int wr = wave >> 2, wc = wave & 3;   // 2x4 wave grid

    f32x4 acc[8][4];
    #pragma unroll
    for (int m = 0; m < 8; ++m)
        #pragma unroll
        for (int n = 0; n < 4; ++n) acc[m][n] = (f32x4){0.f, 0.f, 0.f, 0.f};

    auto stageA = [&](int chunk, int buf, int ks) {
        int k0 = chunk * 32;
        #pragma unroll
        for (int i = wave; i < 16; i += 8) {
            int s = i * 64 + lane, rr = s >> 2, c = s & 3;
            size_t go = (size_t)(row0 + rr) * lda + k0 + ((c ^ ((rr >> 1) & 3)) << 3);
            GLDS(Ah + go, &sA[buf][ks][i * 512]);
        }
    };
    auto stageB = [&](int chunk, int buf, int ks) {
        int k0 = chunk * 32;
        #pragma unroll
        for (int i = wave; i < 16; i += 8) {
            int s = i * 64 + lane, rr = s >> 2, c = s & 3;
            size_t go = (size_t)(col0 + rr) * ldb + k0 + ((c ^ ((rr >> 1) & 3)) << 3);
            GLDS(Bh + go, &sB[buf][ks][i * 512]);
        }
    };

    auto phase = [&](int t, auto ksc) {
        constexpr int ks = decltype(ksc)::value;
        const int buf = t & 1;
        bf16x8 af[8], bf4[4];
        #pragma unroll
        for (int m = 0; m < 8; ++m) {
            int rr = wr * 128 + m * 16 + lr;
            int by = rr * 64 + ((lg ^ ((rr >> 1) & 3)) << 4);
            af[m] = *(const bf16x8*)((const char*)&sA[buf][ks][0] + by);
        }
        #pragma unroll
        for (int n = 0; n < 4; ++n) {
            int rr = wc * 64 + n * 16 + lr;
            int by = rr * 64 + ((lg ^ ((rr >> 1) & 3)) << 4);
            bf4[n] = *(const bf16x8*)((const char*)&sB[buf][ks][0] + by);
        }
        if constexpr (ks == 0) {
            if (t + 1 < NT) {
                stageA(2 * (t + 1) + 1, (t + 1) & 1, 1);
                stageB(2 * (t + 1) + 1, (t + 1) & 1, 1);
                vmwait<8>();
            } else {
                vmwait<0>();
            }
        } else {
            if (t + 2 < NT) {
                stageA(2 * (t + 2), t & 1, 0);
                stageB(2 * (t + 2), t & 1, 0);
                vmwait<8>();
            } else if (t + 1 < NT) {
                vmwait<4>();
            } else {
                vmwait<0>();
            }
        }
        bar();
        lgkm0();
        __builtin_amdgcn_s_setprio(1);
        #pragma unroll
        for (int m = 0; m < 8; ++m)
            #pragma unroll
            for (int n = 0; n < 4; ++n)
                acc[m][n] = mfma16(af[m], bf4[n], acc[m][n]);
        __builtin_amdgcn_s_setprio(0);
        bar();
    };

    stageA(0, 0, 0); stageB(0, 0, 0);
    stageA(1, 0, 1); stageB(1, 0, 1);
    stageA(2, 1, 0); stageB(2, 1, 0);
    vmwait<8>(); bar();

    for (int t = 0; t < NT; ++t) {
        phase(t, IC<0>{});
        phase(t, IC<1>{});
    }

    #pragma unroll
    for (int m = 0; m < 8; ++m)
        #pragma unroll
        for (int n = 0; n < 4; ++n)
            #pragma unroll
            for (int r = 0; r < 4; ++r) {
                int grow = row0 + wr * 128 + m * 16 + lg * 4 + r;
                int gcol = col0 + wc * 64 + n * 16 + lr;
                Cf[(size_t)grow * ldc + gcol] = acc[m][n][r];
            }
}

// weight-pack body: b2 in [0,4096); handles 4 chunks of 1024 f32 each.
// wq|wk|wv|wo -> wAh [4096x1024]; wg|wu -> wGUh INTERLEAVED; wd -> wdh.
static __device__ __forceinline__ void wsplit_body(
    int b2, int tid,
    const float* wq, const float* wk, const float* wv, const float* wo,
    const float* wg, const float* wu, const float* wd,
    bf16_t* wAh, bf16_t* wGUh, bf16_t* wdh)
{
    #pragma unroll
    for (int k = 0; k < 4; ++k) {
        int b = b2 * 4 + k;
        const float* src;
        bf16_t* dst;
        size_t so, doff;
        if (b < 4096) {
            src = b < 1024 ? wq : b < 2048 ? wk : b < 3072 ? wv : wo;
            so = (size_t)(b & 1023) * 256 + tid;
            doff = (size_t)b * 256 + tid;
            dst = wAh;
        } else if (b < 12288) {
            int bb = b - 4096;
            int row = bb < 4096 ? 2 * bb : 2 * (bb - 4096) + 1;
            src = bb < 4096 ? wg : wu;
            so = (size_t)(bb & 4095) * 256 + tid;
            doff = (size_t)row * 256 + tid;
            dst = wGUh;
        } else {
            src = wd;
            so = (size_t)(b - 12288) * 256 + tid;
            doff = so;
            dst = wdh;
        }
        f32x4 v = ((const f32x4*)src)[so];
        bf16x4 hv;
        #pragma unroll
        for (int j = 0; j < 4; ++j) hv[j] = (bf16_t)v[j];
        ((bf16x4*)dst)[doff] = hv;
    }
}

// blocks 0-1023: h += 4 split-K partials then RMS-norm -> hi plane.
// blocks 1024-5119: pack NEXT layer's weights (skipped if wq == null).
__global__ __launch_bounds__(256)
void reduce_rms_wsplit(const float* __restrict__ p, float* __restrict__ h,
                       const float* __restrict__ w, bf16_t* __restrict__ outh,
                       const float* wq, const float* wk, const float* wv,
                       const float* wo, const float* wg, const float* wu,
                       const float* wd, bf16_t* wAh, bf16_t* wGUh, bf16_t* wdh)
{
    int blk = blockIdx.x, tid = threadIdx.x;
    if (blk >= 1024) {
        if (wq) wsplit_body(blk - 1024, tid, wq, wk, wv, wo, wg, wu, wd,
                            wAh, wGUh, wdh);
        return;
    }
    size_t i = (size_t)blk * 256 + tid;
    const size_t S = (1024 * 1024) / 4;
    f32x4 a = ((const f32x4*)p)[i];
    f32x4 b = ((const f32x4*)p)[i + S];
    f32x4 c = ((const f32x4*)p)[i + 2 * S];
    f32x4 d = ((const f32x4*)p)[i + 3 * S];
    f32x4 hv = ((const f32x4*)h)[i];
    #pragma unroll
    for (int j = 0; j < 4; ++j) hv[j] += (a[j] + b[j]) + (c[j] + d[j]);
    ((f32x4*)h)[i] = hv;

    float ss = hv[0]*hv[0] + hv[1]*hv[1] + hv[2]*hv[2] + hv[3]*hv[3];
    #pragma unroll
    for (int m = 1; m < 64; m <<= 1) ss += __shfl_xor(ss, m, 64);
    __shared__ float red[4];
    if ((tid & 63) == 0) red[tid >> 6] = ss;
    __syncthreads();
    float tot = red[0] + red[1] + red[2] + red[3];
    float inv = rsqrtf(tot * (1.0f / 1024.0f) + RMS_EPS);
    f32x4 wt4 = *(const f32x4*)(w + tid * 4);
    bf16x4 hv4;
    #pragma unroll
    for (int j = 0; j < 4; ++j) hv4[j] = (bf16_t)(hv[j] * inv * wt4[j]);
    ((bf16x4*)outh)[i] = hv4;
}

// blocks 0-1023: gather embed row, write fp32 h, RMS-norm -> hi.
// blocks 1024-5119: pack layer-0 weights.
__global__ __launch_bounds__(256)
void gather_rms_wsplit(const int* __restrict__ ids, const float* __restrict__ embed,
                       const float* __restrict__ w, float* __restrict__ h,
                       bf16_t* __restrict__ outh,
                       const float* wq, const float* wk, const float* wv,
                       const float* wo, const float* wg, const float* wu,
                       const float* wd, bf16_t* wAh, bf16_t* wGUh, bf16_t* wdh)
{
    int blk = blockIdx.x, tid = threadIdx.x;
    if (blk >= 1024) {
        wsplit_body(blk - 1024, tid, wq, wk, wv, wo, wg, wu, wd, wAh, wGUh, wdh);
        return;
    }
    int row = ids[blk];
    f32x4 v = ((const f32x4*)(embed + (size_t)row * 1024))[tid];
    ((f32x4*)(h + (size_t)blk * 1024))[tid] = v;

    float ss = v[0]*v[0] + v[1]*v[1] + v[2]*v[2] + v[3]*v[3];
    #pragma unroll
    for (int m = 1; m < 64; m <<= 1) ss += __shfl_xor(ss, m, 64);
    __shared__ float red[4];
    if ((tid & 63) == 0) red[tid >> 6] = ss;
    __syncthreads();
    float tot = red[0] + red[1] + red[2] + red[3];
    float inv = rsqrtf(tot * (1.0f / 1024.0f) + RMS_EPS);
    f32x4 wt4 = *(const f32x4*)(w + tid * 4);
    bf16x4 hv;
    #pragma unroll
    for (int j = 0; j < 4; ++j) hv[j] = (bf16_t)(v[j] * inv * wt4[j]);
    ((bf16x4*)outh)[(size_t)blk * 256 + tid] = hv;
}

// Flash attention: block (qb,hh) handles q-chunk qb (32 rows), KB=64 keys/tile.
// 512 blocks, 2 waves. Q,K hi-only; V hi+lo; softcap (HW-exp tanh) + causal +
// online softmax fp32; P hi/lo via per-wave LDS; 3-term P.V. O hi-only.
__global__ __launch_bounds__(128, 2)
void flash_attn(const bf16_t* __restrict__ qkvh,
                const bf16_t* __restrict__ vTh, const bf16_t* __restrict__ vTl,
                bf16_t* __restrict__ oh)
{
    __shared__ __align__(16) bf16_t sQ[32*64], sK[64*64], sVh[64*64], sVl[64*64];
    __shared__ __align__(16) bf16_t sPh[32*64], sPl[32*64];

    const int q0 = blockIdx.x * 32;
    const int hh = blockIdx.y;
    const int tid = threadIdx.x, lane = tid & 63, w = tid >> 6;
    const int lr = lane & 15, lg = lane >> 4;

    #pragma unroll
    for (int ii = 0; ii < 2; ++ii) {
        int r0 = w * 16 + ii * 8;
        int r  = r0 + (lane >> 3);
        int i  = lane & 7;
        GLDS(qkvh + (size_t)(q0 + r) * 3072 + hh * 64 + ((i ^ (r & 7)) << 3),
             sQ + r0 * 64);
    }
    __syncthreads();

    bf16x8 qa[2];
    #pragma unroll
    for (int ks = 0; ks < 2; ++ks) {
        int r = w * 16 + lr;
        qa[ks] = *(const bf16x8*)((const char*)sQ + r * 128 +
                                  ((((ks << 2) | lg) ^ (r & 7)) << 4));
    }

    f32x4 o_acc[4];
    #pragma unroll
    for (int n = 0; n < 4; ++n) o_acc[n] = (f32x4){0.f, 0.f, 0.f, 0.f};
    float m_run[4] = {-1e30f, -1e30f, -1e30f, -1e30f};
    float l_run[4] = {0.f, 0.f, 0.f, 0.f};

    const int ntiles = ((q0 + 31) >> 6) + 1;
    for (int t = 0; t < ntiles; ++t) {
        const int kv0 = t * 64;
        #pragma unroll
        for (int ii = 0; ii < 4; ++ii) {
            int r0 = w * 32 + ii * 8;
            int r  = r0 + (lane >> 3);
            int i  = lane & 7;
            GLDS(qkvh + (size_t)(kv0 + r) * 3072 + 1024 + hh * 64 + ((i ^ (r & 7)) << 3),
                 sK + r0 * 64);
            GLDS(vTh + (size_t)(hh * 64 + r) * 1024 + kv0 + ((i ^ (r & 7)) << 3),
                 sVh + r0 * 64);
            GLDS(vTl + (size_t)(hh * 64 + r) * 1024 + kv0 + ((i ^ (r & 7)) << 3),
                 sVl + r0 * 64);
        }
        __syncthreads();

        f32x4 s_acc[4];
        #pragma unroll
        for (int n = 0; n < 4; ++n) s_acc[n] = (f32x4){0.f, 0.f, 0.f, 0.f};
        #pragma unroll
        for (int ks = 0; ks < 2; ++ks)
            #pragma unroll
            for (int n = 0; n < 4; ++n) {
                int r = n * 16 + lr;
                bf16x8 kb = *(const bf16x8*)((const char*)sK + r * 128 +
                                             ((((ks << 2) | lg) ^ (r & 7)) << 4));
                s_acc[n] = mfma16(qa[ks], kb, s_acc[n]);
            }

        #pragma unroll
        for (int j = 0; j < 4; ++j) {
            int qr = q0 + w * 16 + lg * 4 + j;
            float p[4];
            float mx = -1e30f;
            #pragma unroll
            for (int n = 0; n < 4; ++n) {
                float sx = s_acc[n][j] * (0.125f * 0.02f);       // x = s*scale/50
                float v = 50.f * (1.f - 2.f / (1.f + __expf(2.f * sx)));
                int key = kv0 + n * 16 + lr;
                if (key > qr) v = -1e30f;
                p[n] = v;
                mx = fmaxf(mx, v);
            }
            #pragma unroll
            for (int m = 1; m < 16; m <<= 1) mx = fmaxf(mx, __shfl_xor(mx, m, 64));
            float mn = fmaxf(m_run[j], mx);
            float ef = __expf(m_run[j] - mn);
            m_run[j] = mn;
            float rs = 0.f;
            #pragma unroll
            for (int n = 0; n < 4; ++n) {
                float e = __expf(p[n] - mn);
                p[n] = e;
                rs += e;
            }
            #pragma unroll
            for (int m = 1; m < 16; m <<= 1) rs += __shfl_xor(rs, m, 64);
            l_run[j] = l_run[j] * ef + rs;
            #pragma unroll
            for (int n = 0; n < 4; ++n) o_acc[n][j] *= ef;
            int r = w * 16 + lg * 4 + j;
            #pragma unroll
            for (int n = 0; n < 4; ++n) {
                int c = n * 16 + lr;
                int byo = r * 128 + ((((c >> 3) ^ (r & 7)) << 4)) + ((c & 7) << 1);
                bf16_t hb = (bf16_t)p[n];
                *(bf16_t*)((char*)sPh + byo) = hb;
                *(bf16_t*)((char*)sPl + byo) = (bf16_t)(p[n] - (float)hb);
            }
        }

        #pragma unroll
        for (int ks = 0; ks < 2; ++ks) {
            int pr = w * 16 + lr;
            int pby = pr * 128 + ((((ks << 2) | lg) ^ (pr & 7)) << 4);
            bf16x8 pa  = *(const bf16x8*)((const char*)sPh + pby);
            bf16x8 pl_ = *(const bf16x8*)((const char*)sPl + pby);
            #pragma unroll
            for (int n = 0; n < 4; ++n) {
                int vr = n * 16 + lr;
                int vby = vr * 128 + ((((ks << 2) | lg) ^ (vr & 7)) << 4);
                bf16x8 vhf = *(const bf16x8*)((const char*)sVh + vby);
                bf16x8 vlf = *(const bf16x8*)((const char*)sVl + vby);
                o_acc[n] = mfma16(pa,  vhf, o_acc[n]);
                o_acc[n] = mfma16(pl_, vhf, o_acc[n]);
                o_acc[n] = mfma16(pa,  vlf, o_acc[n]);
            }
        }
        __syncthreads();
    }

    #pragma unroll
    for (int j = 0; j < 4; ++j) {
        float inv = 1.0f / l_run[j];
        int qr = q0 + w * 16 + lg * 4 + j;
        #pragma unroll
        for (int n = 0; n < 4; ++n) {
            size_t off = (size_t)qr * 1024 + hh * 64 + n * 16 + lr;
            oh[off] = (bf16_t)(o_acc[n][j] * inv);
        }
    }
}

__global__ __launch_bounds__(256)
void split_kernel(const float* __restrict__ src, bf16_t* __restrict__ hi)
{
    size_t i = (size_t)blockIdx.x * 256 + threadIdx.x;
    f32x4 v = ((const f32x4*)src)[i];
    bf16x4 hv;
    #pragma unroll
    for (int j = 0; j < 4; ++j) hv[j] = (bf16_t)v[j];
    ((bf16x4*)hi)[i] = hv;
}

__global__ __launch_bounds__(256)
void rmsnorm_split(const float* __restrict__ in, const float* __restrict__ w,
                   bf16_t* __restrict__ outh)
{
    int row = blockIdx.x, tid = threadIdx.x;
    f32x4 v = *(const f32x4*)(in + (size_t)row * 1024 + tid * 4);
    float ss = v[0]*v[0] + v[1]*v[1] + v[2]*v[2] + v[3]*v[3];
    #pragma unroll
    for (int m = 1; m < 64; m <<= 1) ss += __shfl_xor(ss, m, 64);
    __shared__ float red[4];
    if ((tid & 63) == 0) red[tid >> 6] = ss;
    __syncthreads();
    float tot = red[0] + red[1] + red[2] + red[3];
    float inv = rsqrtf(tot * (1.0f / 1024.0f) + RMS_EPS);
    f32x4 wt4 = *(const f32x4*)(w + tid * 4);
    bf16x4 hv;
    #pragma unroll
    for (int j = 0; j < 4; ++j) hv[j] = (bf16_t)(v[j] * inv * wt4[j]);
    ((bf16x4*)outh)[(size_t)row * 256 + tid] = hv;
}

extern "C" void kernel_launch(void* const* d_in, const int* in_sizes, int n_in,
                              void* d_out, int out_size, void* d_ws, size_t ws_size,
                              hipStream_t stream)
{
    (void)in_sizes; (void)n_in; (void)out_size; (void)ws_size;
    const int*   x_ids = (const int*)  d_in[0];
    const float* embed = (const float*)d_in[1];
    const float* ln1   = (const float*)d_in[2];
    const float* Wq    = (const float*)d_in[3];
    const float* Wk    = (const float*)d_in[4];
    const float* Wv    = (const float*)d_in[5];
    const float* Wo    = (const float*)d_in[6];
    const float* qn    = (const float*)d_in[7];
    const float* kn    = (const float*)d_in[8];
    const float* ln2   = (const float*)d_in[9];
    const float* Wg    = (const float*)d_in[10];
    const float* Wu    = (const float*)d_in[11];
    const float* Wd    = (const float*)d_in[12];
    const float* lnout = (const float*)d_in[13];
    float* out = (float*)d_out;

    char* ws = (char*)d_ws;
    const size_t MB = 1 << 20;
    float*  h    = (float*) (ws +   0 * MB);  // 4 MB fp32 residual
    bf16_t* hnh  = (bf16_t*)(ws +   4 * MB);
    bf16_t* qkvh = (bf16_t*)(ws +   8 * MB);  // 6 MB [1024][3072] (q,k; v cols unused)
    bf16_t* vTh  = (bf16_t*)(ws +  20 * MB);
    bf16_t* vTl  = (bf16_t*)(ws +  22 * MB);
    bf16_t* oh   = (bf16_t*)(ws +  24 * MB);
    bf16_t* wAh  = (bf16_t*)(ws +  28 * MB);  //  8 MB [4096][1024] hi-only
    bf16_t* wGUh = (bf16_t*)(ws +  36 * MB);  // 16 MB [8192][1024] interleaved hi
    bf16_t* wdh  = (bf16_t*)(ws +  52 * MB);  //  8 MB [1024][4096] hi-only
    bf16_t* silh = (bf16_t*)(ws +  60 * MB);  //  8 MB [1024][4096]
    float*  wdp  = (float*) (ws +  68 * MB);  // 16 MB split-K partials [4][1024][1024]
    bf16_t* eh   = (bf16_t*)(ws +  84 * MB);  // 62.5 MB embed hi (high-water ~147 MB)

    const long long M1 = 1024 * 1024;

    gather_rms_wsplit<<<5120, 256, 0, stream>>>(
        x_ids, embed, ln1, h, hnh,
        Wq, Wk, Wv, Wo, Wg, Wu, Wd, wAh, wGUh, wdh);

    for (int l = 0; l < 6; ++l) {
        // fused QKV + qk-RMSnorm + RoPE + V-transpose (1-plane, 3-buffer):
        // q,k -> qkvh; v -> vTh (via Cl) / vTl (via Cf) transposed
        gemm_bf16<64,128,2,2,1,EP_QKV,4,3><<<dim3(16,24),256,0,stream>>>(
            hnh, nullptr, wAh, (float*)vTl, qkvh, vTh, 1024, 1024, 1024, 3072, 0,
            qn + l * 64, kn + l * 64);

        // fused scores+softcap+mask+softmax+PV; O hi-only
        flash_attn<<<dim3(32,16), 128, 0, stream>>>(qkvh, vTh, vTl, oh);

        // Wo residual (1-plane, 3-buffer, 64^2 tiles)
        gemm_bf16<64,64,2,2,1,EP_RESID,4,3><<<dim3(16,16),256,0,stream>>>(
            oh, nullptr, wAh + 3 * M1, h, nullptr, nullptr, 1024, 1024, 1024, 1024, 0,
            nullptr, nullptr);

        rmsnorm_split<<<1024, 256, 0, stream>>>(h, ln2 + l * 1024, hnh);

        // fused gate+up+silu (1-plane, 128x256, 8 waves, 3-buffer): sil hi
        gemm_bf16<128,256,2,4,1,EP_SILU,4,3><<<dim3(8,32),512,0,stream>>>(
            hnh, nullptr, wGUh, nullptr, silh, nullptr, 1024, 1024, 1024, 4096, 0,
            nullptr, nullptr);

        // down-proj: split-K x4 (1-plane, 3-buffer) -> partials
        gemm_bf16<128,128,2,2,1,EP_STORE,4,3><<<dim3(8,8,4),256,0,stream>>>(
            silh, nullptr, wdh, wdp, nullptr, nullptr, 1024, 4096, 4096, 1024, M1,
            nullptr, nullptr);

        // reduce partials into h + next pre-norm + pack next layer's weights
        const float* wnext = (l < 5) ? (ln1 + (l + 1) * 1024) : lnout;
        if (l < 5) {
            reduce_rms_wsplit<<<5120, 256, 0, stream>>>(
                wdp, h, wnext, hnh,
                Wq + (size_t)(l+1) * M1, Wk + (size_t)(l+1) * M1,
                Wv + (size_t)(l+1) * M1, Wo + (size_t)(l+1) * M1,
                Wg + (size_t)(l+1) * 4 * M1, Wu + (size_t)(l+1) * 4 * M1,
                Wd + (size_t)(l+1) * 4 * M1, wAh, wGUh, wdh);
        } else {
            reduce_rms_wsplit<<<1024, 256, 0, stream>>>(
                wdp, h, wnext, hnh,
                nullptr, nullptr, nullptr, nullptr, nullptr, nullptr, nullptr,
                wAh, wGUh, wdh);
        }
    }

    split_kernel<<<32000, 256, 0, stream>>>(embed, eh);
    // logits: phase-split deep pipeline, 256x256, 8 waves, 128 KB LDS
    gemm_logits8<<<dim3(4,125), 512, 0, stream>>>(hnh, eh, out);
}

// Round 19
// 1155.798 us; speedup vs baseline: 1.0221x; 1.0221x over previous
//
#include <hip/hip_runtime.h>
#include <math.h>
#include <type_traits>

typedef __bf16 bf16_t;
typedef bf16_t bf16x4 __attribute__((ext_vector_type(4)));
typedef bf16_t bf16x8 __attribute__((ext_vector_type(8)));
typedef float  f32x4  __attribute__((ext_vector_type(4)));

#define RMS_EPS 1e-6f

enum { EP_STORE = 0, EP_RESID = 1, EP_SPLIT = 2, EP_SILU = 3, EP_QKV = 4 };

template<int V> using IC = std::integral_constant<int, V>;

static __device__ __forceinline__ f32x4 mfma16(bf16x8 a, bf16x8 b, f32x4 c) {
    return __builtin_amdgcn_mfma_f32_16x16x32_bf16(a, b, c, 0, 0, 0);
}

#define GLDS(gp, lp) __builtin_amdgcn_global_load_lds( \
    (const __attribute__((address_space(1))) void*)(gp), \
    (__attribute__((address_space(3))) void*)(lp), 16, 0, 0)

// counted vector-memory wait (T4): leave N newest loads in flight.
template<int N> static __device__ __forceinline__ void vmwait() {
    if constexpr (N == 0)      asm volatile("s_waitcnt vmcnt(0)" ::: "memory");
    else if constexpr (N == 2) asm volatile("s_waitcnt vmcnt(2)" ::: "memory");
    else if constexpr (N == 3) asm volatile("s_waitcnt vmcnt(3)" ::: "memory");
    else if constexpr (N == 4) asm volatile("s_waitcnt vmcnt(4)" ::: "memory");
    else if constexpr (N == 6) asm volatile("s_waitcnt vmcnt(6)" ::: "memory");
    else if constexpr (N == 8) asm volatile("s_waitcnt vmcnt(8)" ::: "memory");
    __builtin_amdgcn_sched_barrier(0);
}
static __device__ __forceinline__ void bar() { __builtin_amdgcn_s_barrier(); }
static __device__ __forceinline__ void lgkm0() {
    asm volatile("s_waitcnt lgkmcnt(0)" ::: "memory");
    __builtin_amdgcn_sched_barrier(0);   // rule #18: fence MFMA hoisting
}

// C[M,N] = A[M,K]*B[N,K]^T.
// PLANES==2: A split hi/lo, B hi-only (2 MFMAs).  PLANES==1: pure bf16.
// WR x WC wave grid. Counted-vmcnt pipelined K-loop, DEPTH buffers.
// NO setprio here: T5 is measured-negative on barrier-lockstep GEMMs (m190).
// EP_SILU: B is wGU interleaved; even lanes write silu(g)*u at col>>1.
// EP_QKV : fused qk-RMSnorm + RoPE epilogue (wave's WN=64 col span = one head);
//          q/k -> Ch (cols [0,2048)); v written TRANSPOSED: hi -> Cl (= vTh),
//          lo -> (bf16_t*)Cf (= vTl). Per-thread 8-byte contiguous runs.
//          Rope quirk: angle = head_index * freq (reference's cos[:n], n=H).
// blockIdx.z = K-chunk for split-K.
template<int BM, int BN, int WR, int WC, int PLANES, int EPIL, int MINW, int DEPTH>
__global__ __launch_bounds__(WR * WC * 64, MINW)
void gemm_bf16(const bf16_t* __restrict__ Ah, const bf16_t* __restrict__ Al,
               const bf16_t* __restrict__ Bh,
               float* __restrict__ Cf, bf16_t* __restrict__ Ch, bf16_t* __restrict__ Cl,
               int K, int lda, int ldb, int ldc, long long sC,
               const float* __restrict__ qnw, const float* __restrict__ knw)
{
    constexpr int ASZ = BM * 32, BSZ = BN * 32;
    constexpr int NW = WR * WC;
    constexpr int NLD = (BM / 16 * (PLANES >= 2 ? 2 : 1) + BN / 16) / NW;
    __shared__ __align__(16) bf16_t sAh[DEPTH][ASZ], sBh[DEPTH][BSZ];
    __shared__ __align__(16) bf16_t sAl[PLANES >= 2 ? DEPTH : 1][PLANES >= 2 ? ASZ : 8];

    const int gx = gridDim.x;
    int id = blockIdx.x + gx * blockIdx.y;
    if (gridDim.z == 1) {  // bijective XCD swizzle (m204)
        int nwg = gx * gridDim.y;
        int q = nwg >> 3, r = nwg & 7;
        int xcd = id & 7, ix = id >> 3;
        id = (xcd < r ? xcd * (q + 1) : r * (q + 1) + (xcd - r) * q) + ix;
    }
    const int bm = id % gx, bn = id / gx;
    const int row0 = bm * BM, col0 = bn * BN;

    const size_t kofs = (size_t)blockIdx.z * K;
    Ah += kofs;  Bh += kofs;
    if constexpr (PLANES >= 2) Al += kofs;

    const int tid = threadIdx.x, lane = tid & 63, wave = tid >> 6;
    const int lr = lane & 15, lg = lane >> 4;
    constexpr int WM = BM / WR, WN = BN / WC, MF = WM / 16, NF = WN / 16;
    const int wr = wave / WC, wc = wave % WC;

    f32x4 acc[MF][NF];
    #pragma unroll
    for (int m = 0; m < MF; ++m)
        #pragma unroll
        for (int n = 0; n < NF; ++n) acc[m][n] = (f32x4){0.f, 0.f, 0.f, 0.f};

    auto stage = [&](int k0, int p) {
        #pragma unroll
        for (int i = wave; i < BM / 16; i += NW) {
            int s = i * 64 + lane, rr = s >> 2, c = s & 3;
            size_t go = (size_t)(row0 + rr) * lda + k0 + ((c ^ ((rr >> 1) & 3)) << 3);
            GLDS(Ah + go, &sAh[p][i * 512]);
            if constexpr (PLANES >= 2) GLDS(Al + go, &sAl[p][i * 512]);
        }
        #pragma unroll
        for (int i = wave; i < BN / 16; i += NW) {
            int s = i * 64 + lane, rr = s >> 2, c = s & 3;
            size_t go = (size_t)(col0 + rr) * ldb + k0 + ((c ^ ((rr >> 1) & 3)) << 3);
            GLDS(Bh + go, &sBh[p][i * 512]);
        }
    };

    auto compute = [&](int p) {
        bf16x8 ahf[MF], alf[MF], bhf[NF];
        #pragma unroll
        for (int m = 0; m < MF; ++m) {
            int rr = wr * WM + m * 16 + lr;
            int by = rr * 64 + ((lg ^ ((rr >> 1) & 3)) << 4);
            ahf[m] = *(const bf16x8*)((const char*)&sAh[p][0] + by);
            if constexpr (PLANES >= 2)
                alf[m] = *(const bf16x8*)((const char*)&sAl[p][0] + by);
        }
        #pragma unroll
        for (int n = 0; n < NF; ++n) {
            int rr = wc * WN + n * 16 + lr;
            int by = rr * 64 + ((lg ^ ((rr >> 1) & 3)) << 4);
            bhf[n] = *(const bf16x8*)((const char*)&sBh[p][0] + by);
        }
        #pragma unroll
        for (int m = 0; m < MF; ++m)
            #pragma unroll
            for (int n = 0; n < NF; ++n) {
                acc[m][n] = mfma16(ahf[m], bhf[n], acc[m][n]);
                if constexpr (PLANES >= 2)
                    acc[m][n] = mfma16(alf[m], bhf[n], acc[m][n]);
            }
    };

    if constexpr (DEPTH == 3) {
        const int NC = K >> 5;          // 32-wide chunks
        stage(0, 0);
        stage(32, 1);
        for (int j = 0; j + 2 < NC; ++j) {
            stage(32 * (j + 2), (j + 2) % 3);
            vmwait<2 * NLD>(); bar();   // chunk j landed; j+1, j+2 in flight
            compute(j % 3);
            bar();                      // protect buf before next stage overwrites
        }
        vmwait<NLD>(); bar();
        compute((K >> 5) >= 2 ? ((K >> 5) - 2) % 3 : 0);
        vmwait<0>(); bar();
        compute(((K >> 5) - 1) % 3);
    } else {
        stage(0, 0);
        int k0 = 32;
        for (; k0 + 32 < K; k0 += 64) {
            stage(k0, 1);
            vmwait<NLD>(); bar();
            compute(0);
            bar();
            stage(k0 + 32, 0);
            vmwait<NLD>(); bar();
            compute(1);
            bar();
        }
        stage(k0, 1);
        vmwait<NLD>(); bar();
        compute(0);
        bar();
        vmwait<0>(); bar();
        compute(1);
    }

    if constexpr (EPIL == EP_QKV) {
        // wave's col span = [colbase, colbase+64) = one head-dim group
        const int colbase = col0 + wc * WN;          // multiple of 64
        const int typ = colbase >> 10;               // 0=q, 1=k, 2=v
        if (typ < 2) {
            const float* nw = (typ == 0) ? qnw : knw;
            const int hh = (colbase - typ * 1024) >> 6;  // head idx
            constexpr float kLogF = -0.41524101186092029f;  // -log2(10000)/32
            #pragma unroll
            for (int m = 0; m < MF; ++m)
                #pragma unroll
                for (int r = 0; r < 4; ++r) {
                    int grow = row0 + wr * WM + m * 16 + lg * 4 + r;
                    float ss = 0.f;
                    #pragma unroll
                    for (int n = 0; n < NF; ++n) {
                        float v = acc[m][n][r];
                        ss += v * v;
                    }
                    ss += __shfl_xor(ss, 1, 64);
                    ss += __shfl_xor(ss, 2, 64);
                    ss += __shfl_xor(ss, 4, 64);
                    ss += __shfl_xor(ss, 8, 64);
                    float inv = rsqrtf(ss * (1.0f / 64.0f) + RMS_EPS);
                    #pragma unroll
                    for (int n = 0; n < NF; ++n) {
                        int i = n * 16 + lr;
                        float x = acc[m][n][r] * inv * nw[i];
                        float p = __shfl_xor(x, 1, 64);
                        float f = exp2f((float)(i >> 1) * kLogF);
                        float ang = (float)hh * f;
                        float cs = cosf(ang), sn = sinf(ang);
                        float o = (lr & 1) ? (p * sn + x * cs) : (x * cs - p * sn);
                        Ch[(size_t)grow * ldc + colbase + i] = (bf16_t)o;
                    }
                }
        } else {
            // v: write TRANSPOSED planes (vT[vc][grow..grow+3], 8B runs)
            bf16_t* vTh_ = Cl;
            bf16_t* vTl_ = (bf16_t*)Cf;
            const int vcb = colbase - 2048;
            #pragma unroll
            for (int m = 0; m < MF; ++m)
                #pragma unroll
                for (int n = 0; n < NF; ++n) {
                    int vc = vcb + n * 16 + lr;
                    int grow0 = row0 + wr * WM + m * 16 + lg * 4;
                    bf16x4 hv, lv;
                    #pragma unroll
                    for (int r = 0; r < 4; ++r) {
                        float v = acc[m][n][r];
                        bf16_t hb = (bf16_t)v;
                        hv[r] = hb;
                        lv[r] = (bf16_t)(v - (float)hb);
                    }
                    *(bf16x4*)&vTh_[(size_t)vc * 1024 + grow0] = hv;
                    *(bf16x4*)&vTl_[(size_t)vc * 1024 + grow0] = lv;
                }
        }
        return;
    }

    #pragma unroll
    for (int m = 0; m < MF; ++m)
        #pragma unroll
        for (int n = 0; n < NF; ++n)
            #pragma unroll
            for (int r = 0; r < 4; ++r) {
                int grow = row0 + wr * WM + m * 16 + lg * 4 + r;
                int gcol = col0 + wc * WN + n * 16 + lr;
                float v = acc[m][n][r];
                if constexpr (EPIL == EP_SILU) {
                    float pv = __shfl_xor(v, 1, 64);   // partner column (g,u pair)
                    if (!(lr & 1)) {
                        float s = (v / (1.0f + __expf(-v))) * pv;
                        size_t off = (size_t)grow * ldc + (gcol >> 1);
                        Ch[off] = (bf16_t)s;
                    }
                } else {
                    size_t off = (size_t)blockIdx.z * sC + (size_t)grow * ldc + gcol;
                    if constexpr (EPIL == EP_STORE) {
                        Cf[off] = v;
                    } else if constexpr (EPIL == EP_RESID) {
                        Cf[off] += v;
                    } else {  // EP_SPLIT
                        bf16_t hb = (bf16_t)v;
                        Ch[off] = hb;
                        Cl[off] = (bf16_t)(v - (float)hb);
                    }
                }
            }
}

// Logits GEMM, phase-split deep pipeline (T3+T4+T5): 256x256 tile, 8 waves,
// K-tile=64 = 2 ks-chunks of 32 in the proven [256][32] XOR-swizzled layout.
// LDS 128 KB double-buffered; vmcnt(8) counted waits (never drains mid-loop).
// setprio kept HERE (phase-split structure = role-diverse waves; T5 applies).
__global__ __launch_bounds__(512, 2)
void gemm_logits8(const bf16_t* __restrict__ Ah, const bf16_t* __restrict__ Bh,
                  float* __restrict__ Cf)
{
    constexpr int lda = 1024, ldb = 1024, ldc = 32000;
    constexpr int NT = 16;   // K-tiles of 64
    __shared__ __align__(16) bf16_t sA[2][2][256 * 32];
    __shared__ __align__(16) bf16_t sB[2][2][256 * 32];

    const int gx = gridDim.x;
    int id = blockIdx.x + gx * blockIdx.y;
    {   // bijective XCD swizzle
        int nwg = gx * gridDim.y;
        int q = nwg >> 3, r = nwg & 7;
        int xcd = id & 7, ix = id >> 3;
        id = (xcd < r ? xcd * (q + 1) : r * (q + 1) + (xcd - r) * q) + ix;
    }
    const int bm = id % gx, bn = id / gx;
    const int row0 = bm * 256, col0 = bn * 256;

    const int tid = threadIdx.x, lane = tid & 63, wave = tid >> 6;
    const int lr = lane & 15, lg = lane >> 4;
    const int wr = wave >> 2, wc = wave & 3;   // 2x4 wave grid

    f32x4 acc[8][4];
    #pragma unroll
    for (int m = 0; m < 8; ++m)
        #pragma unroll
        for (int n = 0; n < 4; ++n) acc[m][n] = (f32x4){0.f, 0.f, 0.f, 0.f};

    auto stageA = [&](int chunk, int buf, int ks) {
        int k0 = chunk * 32;
        #pragma unroll
        for (int i = wave; i < 16; i += 8) {
            int s = i * 64 + lane, rr = s >> 2, c = s & 3;
            size_t go = (size_t)(row0 + rr) * lda + k0 + ((c ^ ((rr >> 1) & 3)) << 3);
            GLDS(Ah + go, &sA[buf][ks][i * 512]);
        }
    };
    auto stageB = [&](int chunk, int buf, int ks) {
        int k0 = chunk * 32;
        #pragma unroll
        for (int i = wave; i < 16; i += 8) {
            int s = i * 64 + lane, rr = s >> 2, c = s & 3;
            size_t go = (size_t)(col0 + rr) * ldb + k0 + ((c ^ ((rr >> 1) & 3)) << 3);
            GLDS(Bh + go, &sB[buf][ks][i * 512]);
        }
    };

    auto phase = [&](int t, auto ksc) {
        constexpr int ks = decltype(ksc)::value;
        const int buf = t & 1;
        bf16x8 af[8], bf4[4];
        #pragma unroll
        for (int m = 0; m < 8; ++m) {
            int rr = wr * 128 + m * 16 + lr;
            int by = rr * 64 + ((lg ^ ((rr >> 1) & 3)) << 4);
            af[m] = *(const bf16x8*)((const char*)&sA[buf][ks][0] + by);
        }
        #pragma unroll
        for (int n = 0; n < 4; ++n) {
            int rr = wc * 64 + n * 16 + lr;
            int by = rr * 64 + ((lg ^ ((rr >> 1) & 3)) << 4);
            bf4[n] = *(const bf16x8*)((const char*)&sB[buf][ks][0] + by);
        }
        if constexpr (ks == 0) {
            if (t + 1 < NT) {
                stageA(2 * (t + 1) + 1, (t + 1) & 1, 1);
                stageB(2 * (t + 1) + 1, (t + 1) & 1, 1);
                vmwait<8>();
            } else {
                vmwait<0>();
            }
        } else {
            if (t + 2 < NT) {
                stageA(2 * (t + 2), t & 1, 0);
                stageB(2 * (t + 2), t & 1, 0);
                vmwait<8>();
            } else if (t + 1 < NT) {
                vmwait<4>();
            } else {
                vmwait<0>();
            }
        }
        bar();
        lgkm0();
        __builtin_amdgcn_s_setprio(1);
        #pragma unroll
        for (int m = 0; m < 8; ++m)
            #pragma unroll
            for (int n = 0; n < 4; ++n)
                acc[m][n] = mfma16(af[m], bf4[n], acc[m][n]);
        __builtin_amdgcn_s_setprio(0);
        bar();
    };

    stageA(0, 0, 0); stageB(0, 0, 0);
    stageA(1, 0, 1); stageB(1, 0, 1);
    stageA(2, 1, 0); stageB(2, 1, 0);
    vmwait<8>(); bar();

    for (int t = 0; t < NT; ++t) {
        phase(t, IC<0>{});
        phase(t, IC<1>{});
    }

    #pragma unroll
    for (int m = 0; m < 8; ++m)
        #pragma unroll
        for (int n = 0; n < 4; ++n)
            #pragma unroll
            for (int r = 0; r < 4; ++r) {
                int grow = row0 + wr * 128 + m * 16 + lg * 4 + r;
                int gcol = col0 + wc * 64 + n * 16 + lr;
                Cf[(size_t)grow * ldc + gcol] = acc[m][n][r];
            }
}

// weight-pack body: b2 in [0,4096); handles 4 chunks of 1024 f32 each.
// wq|wk|wv|wo -> wAh [4096x1024]; wg|wu -> wGUh INTERLEAVED; wd -> wdh.
static __device__ __forceinline__ void wsplit_body(
    int b2, int tid,
    const float* wq, const float* wk, const float* wv, const float* wo,
    const float* wg, const float* wu, const float* wd,
    bf16_t* wAh, bf16_t* wGUh, bf16_t* wdh)
{
    #pragma unroll
    for (int k = 0; k < 4; ++k) {
        int b = b2 * 4 + k;
        const float* src;
        bf16_t* dst;
        size_t so, doff;
        if (b < 4096) {
            src = b < 1024 ? wq : b < 2048 ? wk : b < 3072 ? wv : wo;
            so = (size_t)(b & 1023) * 256 + tid;
            doff = (size_t)b * 256 + tid;
            dst = wAh;
        } else if (b < 12288) {
            int bb = b - 4096;
            int row = bb < 4096 ? 2 * bb : 2 * (bb - 4096) + 1;
            src = bb < 4096 ? wg : wu;
            so = (size_t)(bb & 4095) * 256 + tid;
            doff = (size_t)row * 256 + tid;
            dst = wGUh;
        } else {
            src = wd;
            so = (size_t)(b - 12288) * 256 + tid;
            doff = so;
            dst = wdh;
        }
        f32x4 v = ((const f32x4*)src)[so];
        bf16x4 hv;
        #pragma unroll
        for (int j = 0; j < 4; ++j) hv[j] = (bf16_t)v[j];
        ((bf16x4*)dst)[doff] = hv;
    }
}

// blocks 0-1023: h += 4 split-K partials then RMS-norm -> hi plane.
// blocks 1024-5119: pack NEXT layer's weights (skipped if wq == null).
__global__ __launch_bounds__(256)
void reduce_rms_wsplit(const float* __restrict__ p, float* __restrict__ h,
                       const float* __restrict__ w, bf16_t* __restrict__ outh,
                       const float* wq, const float* wk, const float* wv,
                       const float* wo, const float* wg, const float* wu,
                       const float* wd, bf16_t* wAh, bf16_t* wGUh, bf16_t* wdh)
{
    int blk = blockIdx.x, tid = threadIdx.x;
    if (blk >= 1024) {
        if (wq) wsplit_body(blk - 1024, tid, wq, wk, wv, wo, wg, wu, wd,
                            wAh, wGUh, wdh);
        return;
    }
    size_t i = (size_t)blk * 256 + tid;
    const size_t S = (1024 * 1024) / 4;
    f32x4 a = ((const f32x4*)p)[i];
    f32x4 b = ((const f32x4*)p)[i + S];
    f32x4 c = ((const f32x4*)p)[i + 2 * S];
    f32x4 d = ((const f32x4*)p)[i + 3 * S];
    f32x4 hv = ((const f32x4*)h)[i];
    #pragma unroll
    for (int j = 0; j < 4; ++j) hv[j] += (a[j] + b[j]) + (c[j] + d[j]);
    ((f32x4*)h)[i] = hv;

    float ss = hv[0]*hv[0] + hv[1]*hv[1] + hv[2]*hv[2] + hv[3]*hv[3];
    #pragma unroll
    for (int m = 1; m < 64; m <<= 1) ss += __shfl_xor(ss, m, 64);
    __shared__ float red[4];
    if ((tid & 63) == 0) red[tid >> 6] = ss;
    __syncthreads();
    float tot = red[0] + red[1] + red[2] + red[3];
    float inv = rsqrtf(tot * (1.0f / 1024.0f) + RMS_EPS);
    f32x4 wt4 = *(const f32x4*)(w + tid * 4);
    bf16x4 hv4;
    #pragma unroll
    for (int j = 0; j < 4; ++j) hv4[j] = (bf16_t)(hv[j] * inv * wt4[j]);
    ((bf16x4*)outh)[i] = hv4;
}

// blocks 0-1023: gather embed row, write fp32 h, RMS-norm -> hi.
// blocks 1024-5119: pack layer-0 weights.
// blocks 5120-13119: convert embed (32000x1024 f32) -> eh bf16 (4 chunks/blk).
__global__ __launch_bounds__(256)
void gather_rms_wsplit(const int* __restrict__ ids, const float* __restrict__ embed,
                       const float* __restrict__ w, float* __restrict__ h,
                       bf16_t* __restrict__ outh,
                       const float* wq, const float* wk, const float* wv,
                       const float* wo, const float* wg, const float* wu,
                       const float* wd, bf16_t* wAh, bf16_t* wGUh, bf16_t* wdh,
                       bf16_t* __restrict__ eh)
{
    int blk = blockIdx.x, tid = threadIdx.x;
    if (blk >= 5120) {
        int b2 = blk - 5120;
        #pragma unroll
        for (int k = 0; k < 4; ++k) {
            size_t so = ((size_t)b2 * 4 + k) * 256 + tid;
            f32x4 v = ((const f32x4*)embed)[so];
            bf16x4 hv;
            #pragma unroll
            for (int j = 0; j < 4; ++j) hv[j] = (bf16_t)v[j];
            ((bf16x4*)eh)[so] = hv;
        }
        return;
    }
    if (blk >= 1024) {
        wsplit_body(blk - 1024, tid, wq, wk, wv, wo, wg, wu, wd, wAh, wGUh, wdh);
        return;
    }
    int row = ids[blk];
    f32x4 v = ((const f32x4*)(embed + (size_t)row * 1024))[tid];
    ((f32x4*)(h + (size_t)blk * 1024))[tid] = v;

    float ss = v[0]*v[0] + v[1]*v[1] + v[2]*v[2] + v[3]*v[3];
    #pragma unroll
    for (int m = 1; m < 64; m <<= 1) ss += __shfl_xor(ss, m, 64);
    __shared__ float red[4];
    if ((tid & 63) == 0) red[tid >> 6] = ss;
    __syncthreads();
    float tot = red[0] + red[1] + red[2] + red[3];
    float inv = rsqrtf(tot * (1.0f / 1024.0f) + RMS_EPS);
    f32x4 wt4 = *(const f32x4*)(w + tid * 4);
    bf16x4 hv;
    #pragma unroll
    for (int j = 0; j < 4; ++j) hv[j] = (bf16_t)(v[j] * inv * wt4[j]);
    ((bf16x4*)outh)[(size_t)blk * 256 + tid] = hv;
}

// Flash attention: block (qb,hh) handles q-chunk qb (32 rows), KB=64 keys/tile.
// 512 blocks, 2 waves. Q,K hi-only; V hi+lo; softcap (HW-exp tanh) + causal +
// online softmax fp32; P hi/lo via per-wave LDS; 3-term P.V. O hi-only.
__global__ __launch_bounds__(128, 2)
void flash_attn(const bf16_t* __restrict__ qkvh,
                const bf16_t* __restrict__ vTh, const bf16_t* __restrict__ vTl,
                bf16_t* __restrict__ oh)
{
    __shared__ __align__(16) bf16_t sQ[32*64], sK[64*64], sVh[64*64], sVl[64*64];
    __shared__ __align__(16) bf16_t sPh[32*64], sPl[32*64];

    const int q0 = blockIdx.x * 32;
    const int hh = blockIdx.y;
    const int tid = threadIdx.x, lane = tid & 63, w = tid >> 6;
    const int lr = lane & 15, lg = lane >> 4;

    #pragma unroll
    for (int ii = 0; ii < 2; ++ii) {
        int r0 = w * 16 + ii * 8;
        int r  = r0 + (lane >> 3);
        int i  = lane & 7;
        GLDS(qkvh + (size_t)(q0 + r) * 3072 + hh * 64 + ((i ^ (r & 7)) << 3),
             sQ + r0 * 64);
    }
    __syncthreads();

    bf16x8 qa[2];
    #pragma unroll
    for (int ks = 0; ks < 2; ++ks) {
        int r = w * 16 + lr;
        qa[ks] = *(const bf16x8*)((const char*)sQ + r * 128 +
                                  ((((ks << 2) | lg) ^ (r & 7)) << 4));
    }

    f32x4 o_acc[4];
    #pragma unroll
    for (int n = 0; n < 4; ++n) o_acc[n] = (f32x4){0.f, 0.f, 0.f, 0.f};
    float m_run[4] = {-1e30f, -1e30f, -1e30f, -1e30f};
    float l_run[4] = {0.f, 0.f, 0.f, 0.f};

    const int ntiles = ((q0 + 31) >> 6) + 1;
    for (int t = 0; t < ntiles; ++t) {
        const int kv0 = t * 64;
        #pragma unroll
        for (int ii = 0; ii < 4; ++ii) {
            int r0 = w * 32 + ii * 8;
            int r  = r0 + (lane >> 3);
            int i  = lane & 7;
            GLDS(qkvh + (size_t)(kv0 + r) * 3072 + 1024 + hh * 64 + ((i ^ (r & 7)) << 3),
                 sK + r0 * 64);
            GLDS(vTh + (size_t)(hh * 64 + r) * 1024 + kv0 + ((i ^ (r & 7)) << 3),
                 sVh + r0 * 64);
            GLDS(vTl + (size_t)(hh * 64 + r) * 1024 + kv0 + ((i ^ (r & 7)) << 3),
                 sVl + r0 * 64);
        }
        __syncthreads();

        f32x4 s_acc[4];
        #pragma unroll
        for (int n = 0; n < 4; ++n) s_acc[n] = (f32x4){0.f, 0.f, 0.f, 0.f};
        #pragma unroll
        for (int ks = 0; ks < 2; ++ks)
            #pragma unroll
            for (int n = 0; n < 4; ++n) {
                int r = n * 16 + lr;
                bf16x8 kb = *(const bf16x8*)((const char*)sK + r * 128 +
                                             ((((ks << 2) | lg) ^ (r & 7)) << 4));
                s_acc[n] = mfma16(qa[ks], kb, s_acc[n]);
            }

        #pragma unroll
        for (int j = 0; j < 4; ++j) {
            int qr = q0 + w * 16 + lg * 4 + j;
            float p[4];
            float mx = -1e30f;
            #pragma unroll
            for (int n = 0; n < 4; ++n) {
                float sx = s_acc[n][j] * (0.125f * 0.02f);       // x = s*scale/50
                float v = 50.f * (1.f - 2.f / (1.f + __expf(2.f * sx)));
                int key = kv0 + n * 16 + lr;
                if (key > qr) v = -1e30f;
                p[n] = v;
                mx = fmaxf(mx, v);
            }
            #pragma unroll
            for (int m = 1; m < 16; m <<= 1) mx = fmaxf(mx, __shfl_xor(mx, m, 64));
            float mn = fmaxf(m_run[j], mx);
            float ef = __expf(m_run[j] - mn);
            m_run[j] = mn;
            float rs = 0.f;
            #pragma unroll
            for (int n = 0; n < 4; ++n) {
                float e = __expf(p[n] - mn);
                p[n] = e;
                rs += e;
            }
            #pragma unroll
            for (int m = 1; m < 16; m <<= 1) rs += __shfl_xor(rs, m, 64);
            l_run[j] = l_run[j] * ef + rs;
            #pragma unroll
            for (int n = 0; n < 4; ++n) o_acc[n][j] *= ef;
            int r = w * 16 + lg * 4 + j;
            #pragma unroll
            for (int n = 0; n < 4; ++n) {
                int c = n * 16 + lr;
                int byo = r * 128 + ((((c >> 3) ^ (r & 7)) << 4)) + ((c & 7) << 1);
                bf16_t hb = (bf16_t)p[n];
                *(bf16_t*)((char*)sPh + byo) = hb;
                *(bf16_t*)((char*)sPl + byo) = (bf16_t)(p[n] - (float)hb);
            }
        }

        #pragma unroll
        for (int ks = 0; ks < 2; ++ks) {
            int pr = w * 16 + lr;
            int pby = pr * 128 + ((((ks << 2) | lg) ^ (pr & 7)) << 4);
            bf16x8 pa  = *(const bf16x8*)((const char*)sPh + pby);
            bf16x8 pl_ = *(const bf16x8*)((const char*)sPl + pby);
            #pragma unroll
            for (int n = 0; n < 4; ++n) {
                int vr = n * 16 + lr;
                int vby = vr * 128 + ((((ks << 2) | lg) ^ (vr & 7)) << 4);
                bf16x8 vhf = *(const bf16x8*)((const char*)sVh + vby);
                bf16x8 vlf = *(const bf16x8*)((const char*)sVl + vby);
                o_acc[n] = mfma16(pa,  vhf, o_acc[n]);
                o_acc[n] = mfma16(pl_, vhf, o_acc[n]);
                o_acc[n] = mfma16(pa,  vlf, o_acc[n]);
            }
        }
        __syncthreads();
    }

    #pragma unroll
    for (int j = 0; j < 4; ++j) {
        float inv = 1.0f / l_run[j];
        int qr = q0 + w * 16 + lg * 4 + j;
        #pragma unroll
        for (int n = 0; n < 4; ++n) {
            size_t off = (size_t)qr * 1024 + hh * 64 + n * 16 + lr;
            oh[off] = (bf16_t)(o_acc[n][j] * inv);
        }
    }
}

__global__ __launch_bounds__(256)
void rmsnorm_split(const float* __restrict__ in, const float* __restrict__ w,
                   bf16_t* __restrict__ outh)
{
    int row = blockIdx.x, tid = threadIdx.x;
    f32x4 v = *(const f32x4*)(in + (size_t)row * 1024 + tid * 4);
    float ss = v[0]*v[0] + v[1]*v[1] + v[2]*v[2] + v[3]*v[3];
    #pragma unroll
    for (int m = 1; m < 64; m <<= 1) ss += __shfl_xor(ss, m, 64);
    __shared__ float red[4];
    if ((tid & 63) == 0) red[tid >> 6] = ss;
    __syncthreads();
    float tot = red[0] + red[1] + red[2] + red[3];
    float inv = rsqrtf(tot * (1.0f / 1024.0f) + RMS_EPS);
    f32x4 wt4 = *(const f32x4*)(w + tid * 4);
    bf16x4 hv;
    #pragma unroll
    for (int j = 0; j < 4; ++j) hv[j] = (bf16_t)(v[j] * inv * wt4[j]);
    ((bf16x4*)outh)[(size_t)row * 256 + tid] = hv;
}

extern "C" void kernel_launch(void* const* d_in, const int* in_sizes, int n_in,
                              void* d_out, int out_size, void* d_ws, size_t ws_size,
                              hipStream_t stream)
{
    (void)in_sizes; (void)n_in; (void)out_size; (void)ws_size;
    const int*   x_ids = (const int*)  d_in[0];
    const float* embed = (const float*)d_in[1];
    const float* ln1   = (const float*)d_in[2];
    const float* Wq    = (const float*)d_in[3];
    const float* Wk    = (const float*)d_in[4];
    const float* Wv    = (const float*)d_in[5];
    const float* Wo    = (const float*)d_in[6];
    const float* qn    = (const float*)d_in[7];
    const float* kn    = (const float*)d_in[8];
    const float* ln2   = (const float*)d_in[9];
    const float* Wg    = (const float*)d_in[10];
    const float* Wu    = (const float*)d_in[11];
    const float* Wd    = (const float*)d_in[12];
    const float* lnout = (const float*)d_in[13];
    float* out = (float*)d_out;

    char* ws = (char*)d_ws;
    const size_t MB = 1 << 20;
    float*  h    = (float*) (ws +   0 * MB);  // 4 MB fp32 residual
    bf16_t* hnh  = (bf16_t*)(ws +   4 * MB);
    bf16_t* qkvh = (bf16_t*)(ws +   8 * MB);  // 6 MB [1024][3072] (q,k; v cols unused)
    bf16_t* vTh  = (bf16_t*)(ws +  20 * MB);
    bf16_t* vTl  = (bf16_t*)(ws +  22 * MB);
    bf16_t* oh   = (bf16_t*)(ws +  24 * MB);
    bf16_t* wAh  = (bf16_t*)(ws +  28 * MB);  //  8 MB [4096][1024] hi-only
    bf16_t* wGUh = (bf16_t*)(ws +  36 * MB);  // 16 MB [8192][1024] interleaved hi
    bf16_t* wdh  = (bf16_t*)(ws +  52 * MB);  //  8 MB [1024][4096] hi-only
    bf16_t* silh = (bf16_t*)(ws +  60 * MB);  //  8 MB [1024][4096]
    float*  wdp  = (float*) (ws +  68 * MB);  // 16 MB split-K partials [4][1024][1024]
    bf16_t* eh   = (bf16_t*)(ws +  84 * MB);  // 62.5 MB embed hi (high-water ~147 MB)

    const long long M1 = 1024 * 1024;

    // gather+rms (1024) | layer-0 weight pack (4096) | embed->bf16 (8000)
    gather_rms_wsplit<<<13120, 256, 0, stream>>>(
        x_ids, embed, ln1, h, hnh,
        Wq, Wk, Wv, Wo, Wg, Wu, Wd, wAh, wGUh, wdh, eh);

    for (int l = 0; l < 6; ++l) {
        // fused QKV + qk-RMSnorm + RoPE + V-transpose (1-plane, 3-buffer):
        // q,k -> qkvh; v -> vTh (via Cl) / vTl (via Cf) transposed
        gemm_bf16<64,128,2,2,1,EP_QKV,4,3><<<dim3(16,24),256,0,stream>>>(
            hnh, nullptr, wAh, (float*)vTl, qkvh, vTh, 1024, 1024, 1024, 3072, 0,
            qn + l * 64, kn + l * 64);

        // fused scores+softcap+mask+softmax+PV; O hi-only
        flash_attn<<<dim3(32,16), 128, 0, stream>>>(qkvh, vTh, vTl, oh);

        // Wo residual (1-plane, 3-buffer, 64^2 tiles)
        gemm_bf16<64,64,2,2,1,EP_RESID,4,3><<<dim3(16,16),256,0,stream>>>(
            oh, nullptr, wAh + 3 * M1, h, nullptr, nullptr, 1024, 1024, 1024, 1024, 0,
            nullptr, nullptr);

        rmsnorm_split<<<1024, 256, 0, stream>>>(h, ln2 + l * 1024, hnh);

        // fused gate+up+silu (1-plane, 128x256, 8 waves, 3-buffer): sil hi
        gemm_bf16<128,256,2,4,1,EP_SILU,4,3><<<dim3(8,32),512,0,stream>>>(
            hnh, nullptr, wGUh, nullptr, silh, nullptr, 1024, 1024, 1024, 4096, 0,
            nullptr, nullptr);

        // down-proj: split-K x4 (1-plane, 3-buffer) -> partials
        gemm_bf16<128,128,2,2,1,EP_STORE,4,3><<<dim3(8,8,4),256,0,stream>>>(
            silh, nullptr, wdh, wdp, nullptr, nullptr, 1024, 4096, 4096, 1024, M1,
            nullptr, nullptr);

        // reduce partials into h + next pre-norm + pack next layer's weights
        const float* wnext = (l < 5) ? (ln1 + (l + 1) * 1024) : lnout;
        if (l < 5) {
            reduce_rms_wsplit<<<5120, 256, 0, stream>>>(
                wdp, h, wnext, hnh,
                Wq + (size_t)(l+1) * M1, Wk + (size_t)(l+1) * M1,
                Wv + (size_t)(l+1) * M1, Wo + (size_t)(l+1) * M1,
                Wg + (size_t)(l+1) * 4 * M1, Wu + (size_t)(l+1) * 4 * M1,
                Wd + (size_t)(l+1) * 4 * M1, wAh, wGUh, wdh);
        } else {
            reduce_rms_wsplit<<<1024, 256, 0, stream>>>(
                wdp, h, wnext, hnh,
                nullptr, nullptr, nullptr, nullptr, nullptr, nullptr, nullptr,
                wAh, wGUh, wdh);
        }
    }

    // logits: phase-split deep pipeline, 256x256, 8 waves, 128 KB LDS
    gemm_logits8<<<dim3(4,125), 512, 0, stream>>>(hnh, eh, out);
}

// Round 20
// 1124.572 us; speedup vs baseline: 1.0505x; 1.0278x over previous
//
#include <hip/hip_runtime.h>
#include <math.h>
#include <type_traits>

typedef __bf16 bf16_t;
typedef bf16_t bf16x4 __attribute__((ext_vector_type(4)));
typedef bf16_t bf16x8 __attribute__((ext_vector_type(8)));
typedef float  f32x4  __attribute__((ext_vector_type(4)));

#define RMS_EPS 1e-6f

enum { EP_STORE = 0, EP_RESID = 1, EP_SPLIT = 2, EP_SILU = 3, EP_QKV = 4 };

template<int V> using IC = std::integral_constant<int, V>;

static __device__ __forceinline__ f32x4 mfma16(bf16x8 a, bf16x8 b, f32x4 c) {
    return __builtin_amdgcn_mfma_f32_16x16x32_bf16(a, b, c, 0, 0, 0);
}

#define GLDS(gp, lp) __builtin_amdgcn_global_load_lds( \
    (const __attribute__((address_space(1))) void*)(gp), \
    (__attribute__((address_space(3))) void*)(lp), 16, 0, 0)

// counted vector-memory wait (T4): leave N newest loads in flight.
template<int N> static __device__ __forceinline__ void vmwait() {
    if constexpr (N == 0)      asm volatile("s_waitcnt vmcnt(0)" ::: "memory");
    else if constexpr (N == 2) asm volatile("s_waitcnt vmcnt(2)" ::: "memory");
    else if constexpr (N == 3) asm volatile("s_waitcnt vmcnt(3)" ::: "memory");
    else if constexpr (N == 4) asm volatile("s_waitcnt vmcnt(4)" ::: "memory");
    else if constexpr (N == 6) asm volatile("s_waitcnt vmcnt(6)" ::: "memory");
    else if constexpr (N == 8) asm volatile("s_waitcnt vmcnt(8)" ::: "memory");
    __builtin_amdgcn_sched_barrier(0);
}
static __device__ __forceinline__ void bar() { __builtin_amdgcn_s_barrier(); }
static __device__ __forceinline__ void lgkm0() {
    asm volatile("s_waitcnt lgkmcnt(0)" ::: "memory");
    __builtin_amdgcn_sched_barrier(0);   // rule #18: fence MFMA hoisting
}

// C[M,N] = A[M,K]*B[N,K]^T.
// PLANES==2: A split hi/lo, B hi-only (2 MFMAs).  PLANES==1: pure bf16.
// WR x WC wave grid. Counted-vmcnt pipelined K-loop, DEPTH buffers.
// NO setprio here: T5 is measured-negative on barrier-lockstep GEMMs (m190).
// EP_QKV : fused qk-RMSnorm + RoPE epilogue (wave's WN=64 col span = one head);
//          q/k -> Ch (cols [0,2048)); v written TRANSPOSED: hi -> Cl (= vTh),
//          lo -> (bf16_t*)Cf (= vTl). Per-thread 8-byte contiguous runs.
//          Rope quirk: angle = head_index * freq (reference's cos[:n], n=H).
// blockIdx.z = K-chunk for split-K.
template<int BM, int BN, int WR, int WC, int PLANES, int EPIL, int MINW, int DEPTH>
__global__ __launch_bounds__(WR * WC * 64, MINW)
void gemm_bf16(const bf16_t* __restrict__ Ah, const bf16_t* __restrict__ Al,
               const bf16_t* __restrict__ Bh,
               float* __restrict__ Cf, bf16_t* __restrict__ Ch, bf16_t* __restrict__ Cl,
               int K, int lda, int ldb, int ldc, long long sC,
               const float* __restrict__ qnw, const float* __restrict__ knw)
{
    constexpr int ASZ = BM * 32, BSZ = BN * 32;
    constexpr int NW = WR * WC;
    constexpr int NLD = (BM / 16 * (PLANES >= 2 ? 2 : 1) + BN / 16) / NW;
    __shared__ __align__(16) bf16_t sAh[DEPTH][ASZ], sBh[DEPTH][BSZ];
    __shared__ __align__(16) bf16_t sAl[PLANES >= 2 ? DEPTH : 1][PLANES >= 2 ? ASZ : 8];

    const int gx = gridDim.x;
    int id = blockIdx.x + gx * blockIdx.y;
    if (gridDim.z == 1) {  // bijective XCD swizzle (m204)
        int nwg = gx * gridDim.y;
        int q = nwg >> 3, r = nwg & 7;
        int xcd = id & 7, ix = id >> 3;
        id = (xcd < r ? xcd * (q + 1) : r * (q + 1) + (xcd - r) * q) + ix;
    }
    const int bm = id % gx, bn = id / gx;
    const int row0 = bm * BM, col0 = bn * BN;

    const size_t kofs = (size_t)blockIdx.z * K;
    Ah += kofs;  Bh += kofs;
    if constexpr (PLANES >= 2) Al += kofs;

    const int tid = threadIdx.x, lane = tid & 63, wave = tid >> 6;
    const int lr = lane & 15, lg = lane >> 4;
    constexpr int WM = BM / WR, WN = BN / WC, MF = WM / 16, NF = WN / 16;
    const int wr = wave / WC, wc = wave % WC;

    f32x4 acc[MF][NF];
    #pragma unroll
    for (int m = 0; m < MF; ++m)
        #pragma unroll
        for (int n = 0; n < NF; ++n) acc[m][n] = (f32x4){0.f, 0.f, 0.f, 0.f};

    auto stage = [&](int k0, int p) {
        #pragma unroll
        for (int i = wave; i < BM / 16; i += NW) {
            int s = i * 64 + lane, rr = s >> 2, c = s & 3;
            size_t go = (size_t)(row0 + rr) * lda + k0 + ((c ^ ((rr >> 1) & 3)) << 3);
            GLDS(Ah + go, &sAh[p][i * 512]);
            if constexpr (PLANES >= 2) GLDS(Al + go, &sAl[p][i * 512]);
        }
        #pragma unroll
        for (int i = wave; i < BN / 16; i += NW) {
            int s = i * 64 + lane, rr = s >> 2, c = s & 3;
            size_t go = (size_t)(col0 + rr) * ldb + k0 + ((c ^ ((rr >> 1) & 3)) << 3);
            GLDS(Bh + go, &sBh[p][i * 512]);
        }
    };

    auto compute = [&](int p) {
        bf16x8 ahf[MF], alf[MF], bhf[NF];
        #pragma unroll
        for (int m = 0; m < MF; ++m) {
            int rr = wr * WM + m * 16 + lr;
            int by = rr * 64 + ((lg ^ ((rr >> 1) & 3)) << 4);
            ahf[m] = *(const bf16x8*)((const char*)&sAh[p][0] + by);
            if constexpr (PLANES >= 2)
                alf[m] = *(const bf16x8*)((const char*)&sAl[p][0] + by);
        }
        #pragma unroll
        for (int n = 0; n < NF; ++n) {
            int rr = wc * WN + n * 16 + lr;
            int by = rr * 64 + ((lg ^ ((rr >> 1) & 3)) << 4);
            bhf[n] = *(const bf16x8*)((const char*)&sBh[p][0] + by);
        }
        #pragma unroll
        for (int m = 0; m < MF; ++m)
            #pragma unroll
            for (int n = 0; n < NF; ++n) {
                acc[m][n] = mfma16(ahf[m], bhf[n], acc[m][n]);
                if constexpr (PLANES >= 2)
                    acc[m][n] = mfma16(alf[m], bhf[n], acc[m][n]);
            }
    };

    if constexpr (DEPTH == 3) {
        const int NC = K >> 5;          // 32-wide chunks
        stage(0, 0);
        stage(32, 1);
        for (int j = 0; j + 2 < NC; ++j) {
            stage(32 * (j + 2), (j + 2) % 3);
            vmwait<2 * NLD>(); bar();   // chunk j landed; j+1, j+2 in flight
            compute(j % 3);
            bar();                      // protect buf before next stage overwrites
        }
        vmwait<NLD>(); bar();
        compute((K >> 5) >= 2 ? ((K >> 5) - 2) % 3 : 0);
        vmwait<0>(); bar();
        compute(((K >> 5) - 1) % 3);
    } else {
        stage(0, 0);
        int k0 = 32;
        for (; k0 + 32 < K; k0 += 64) {
            stage(k0, 1);
            vmwait<NLD>(); bar();
            compute(0);
            bar();
            stage(k0 + 32, 0);
            vmwait<NLD>(); bar();
            compute(1);
            bar();
        }
        stage(k0, 1);
        vmwait<NLD>(); bar();
        compute(0);
        bar();
        vmwait<0>(); bar();
        compute(1);
    }

    if constexpr (EPIL == EP_QKV) {
        // wave's col span = [colbase, colbase+64) = one head-dim group
        const int colbase = col0 + wc * WN;          // multiple of 64
        const int typ = colbase >> 10;               // 0=q, 1=k, 2=v
        if (typ < 2) {
            const float* nw = (typ == 0) ? qnw : knw;
            const int hh = (colbase - typ * 1024) >> 6;  // head idx
            constexpr float kLogF = -0.41524101186092029f;  // -log2(10000)/32
            #pragma unroll
            for (int m = 0; m < MF; ++m)
                #pragma unroll
                for (int r = 0; r < 4; ++r) {
                    int grow = row0 + wr * WM + m * 16 + lg * 4 + r;
                    float ss = 0.f;
                    #pragma unroll
                    for (int n = 0; n < NF; ++n) {
                        float v = acc[m][n][r];
                        ss += v * v;
                    }
                    ss += __shfl_xor(ss, 1, 64);
                    ss += __shfl_xor(ss, 2, 64);
                    ss += __shfl_xor(ss, 4, 64);
                    ss += __shfl_xor(ss, 8, 64);
                    float inv = rsqrtf(ss * (1.0f / 64.0f) + RMS_EPS);
                    #pragma unroll
                    for (int n = 0; n < NF; ++n) {
                        int i = n * 16 + lr;
                        float x = acc[m][n][r] * inv * nw[i];
                        float p = __shfl_xor(x, 1, 64);
                        float f = exp2f((float)(i >> 1) * kLogF);
                        float ang = (float)hh * f;
                        float cs = cosf(ang), sn = sinf(ang);
                        float o = (lr & 1) ? (p * sn + x * cs) : (x * cs - p * sn);
                        Ch[(size_t)grow * ldc + colbase + i] = (bf16_t)o;
                    }
                }
        } else {
            // v: write TRANSPOSED planes (vT[vc][grow..grow+3], 8B runs)
            bf16_t* vTh_ = Cl;
            bf16_t* vTl_ = (bf16_t*)Cf;
            const int vcb = colbase - 2048;
            #pragma unroll
            for (int m = 0; m < MF; ++m)
                #pragma unroll
                for (int n = 0; n < NF; ++n) {
                    int vc = vcb + n * 16 + lr;
                    int grow0 = row0 + wr * WM + m * 16 + lg * 4;
                    bf16x4 hv, lv;
                    #pragma unroll
                    for (int r = 0; r < 4; ++r) {
                        float v = acc[m][n][r];
                        bf16_t hb = (bf16_t)v;
                        hv[r] = hb;
                        lv[r] = (bf16_t)(v - (float)hb);
                    }
                    *(bf16x4*)&vTh_[(size_t)vc * 1024 + grow0] = hv;
                    *(bf16x4*)&vTl_[(size_t)vc * 1024 + grow0] = lv;
                }
        }
        return;
    }

    #pragma unroll
    for (int m = 0; m < MF; ++m)
        #pragma unroll
        for (int n = 0; n < NF; ++n)
            #pragma unroll
            for (int r = 0; r < 4; ++r) {
                int grow = row0 + wr * WM + m * 16 + lg * 4 + r;
                int gcol = col0 + wc * WN + n * 16 + lr;
                float v = acc[m][n][r];
                size_t off = (size_t)blockIdx.z * sC + (size_t)grow * ldc + gcol;
                if constexpr (EPIL == EP_STORE) {
                    Cf[off] = v;
                } else if constexpr (EPIL == EP_RESID) {
                    Cf[off] += v;
                } else if constexpr (EPIL == EP_SPLIT) {
                    bf16_t hb = (bf16_t)v;
                    Ch[off] = hb;
                    Cl[off] = (bf16_t)(v - (float)hb);
                }
            }
}

// GU GEMM (sil = silu(g)*u, 128x256 tile, 8 waves, DEPTH-3 counted-vmcnt)
// PLUS fused next-layer weight pack on blockIdx.z==1 blocks (disjoint
// destination buffer set; overlaps HBM-bound pack with MFMA-bound GEMM).
__global__ __launch_bounds__(512, 4)
void gemm_gu_pack(const bf16_t* __restrict__ Ah, const bf16_t* __restrict__ Bh,
                  bf16_t* __restrict__ Ch,
                  const float* wq, const float* wk, const float* wv,
                  const float* wo, const float* wg, const float* wu,
                  const float* wd, bf16_t* wAd, bf16_t* wGUd, bf16_t* wdd)
{
    constexpr int lda = 1024, ldb = 1024, ldc = 4096, K = 1024;
    const int tid = threadIdx.x;

    if (blockIdx.z == 1) {     // pack next layer's weights -> other buffer set
        if (!wq) return;
        int base = ((int)blockIdx.y * 8 + (int)blockIdx.x) * 512 + tid;
        #pragma unroll 4
        for (int j = 0; j < 32; ++j) {
            int v = j * 131072 + base;      // 0..4194303 f32x4 units
            f32x4 val;
            bf16_t* dst;
            size_t doff;
            if (v < (1 << 20)) {            // wq|wk|wv|wo -> wAd [4096x1024]
                int b = v >> 8, col = v & 255;
                const float* src = b < 1024 ? wq : b < 2048 ? wk : b < 3072 ? wv : wo;
                val = ((const f32x4*)src)[(size_t)(b & 1023) * 256 + col];
                dst = wAd; doff = (size_t)b * 256 + col;
            } else if (v < 3 * (1 << 20)) { // wg|wu INTERLEAVED -> wGUd
                int u = v - (1 << 20);
                int bb = u >> 8, col = u & 255;
                int row = bb < 4096 ? 2 * bb : 2 * (bb - 4096) + 1;
                const float* src = bb < 4096 ? wg : wu;
                val = ((const f32x4*)src)[(size_t)(bb & 4095) * 256 + col];
                dst = wGUd; doff = (size_t)row * 256 + col;
            } else {                        // wd -> wdd
                int u = v - 3 * (1 << 20);
                val = ((const f32x4*)wd)[u];
                dst = wdd; doff = (size_t)u;
            }
            bf16x4 hv;
            #pragma unroll
            for (int q2 = 0; q2 < 4; ++q2) hv[q2] = (bf16_t)val[q2];
            ((bf16x4*)dst)[doff] = hv;
        }
        return;
    }

    __shared__ __align__(16) bf16_t sA[3][128 * 32], sB[3][256 * 32];

    int id = blockIdx.x + 8 * blockIdx.y;
    {   // bijective XCD swizzle (nwg = 256)
        int q = 256 >> 3;
        int xcd = id & 7, ix = id >> 3;
        id = xcd * q + ix;
    }
    const int bm = id % 8, bn = id / 8;
    const int row0 = bm * 128, col0 = bn * 256;

    const int lane = tid & 63, wave = tid >> 6;
    const int lr = lane & 15, lg = lane >> 4;
    const int wr = wave >> 2, wc = wave & 3;   // 2x4 waves; WM=WN=64

    f32x4 acc[4][4];
    #pragma unroll
    for (int m = 0; m < 4; ++m)
        #pragma unroll
        for (int n = 0; n < 4; ++n) acc[m][n] = (f32x4){0.f, 0.f, 0.f, 0.f};

    auto stage = [&](int k0, int p) {
        {
            int i = wave;
            int s = i * 64 + lane, rr = s >> 2, c = s & 3;
            size_t go = (size_t)(row0 + rr) * lda + k0 + ((c ^ ((rr >> 1) & 3)) << 3);
            GLDS(Ah + go, &sA[p][i * 512]);
        }
        #pragma unroll
        for (int i = wave; i < 16; i += 8) {
            int s = i * 64 + lane, rr = s >> 2, c = s & 3;
            size_t go = (size_t)(col0 + rr) * ldb + k0 + ((c ^ ((rr >> 1) & 3)) << 3);
            GLDS(Bh + go, &sB[p][i * 512]);
        }
    };

    auto compute = [&](int p) {
        bf16x8 af[4], bf4[4];
        #pragma unroll
        for (int m = 0; m < 4; ++m) {
            int rr = wr * 64 + m * 16 + lr;
            int by = rr * 64 + ((lg ^ ((rr >> 1) & 3)) << 4);
            af[m] = *(const bf16x8*)((const char*)&sA[p][0] + by);
        }
        #pragma unroll
        for (int n = 0; n < 4; ++n) {
            int rr = wc * 64 + n * 16 + lr;
            int by = rr * 64 + ((lg ^ ((rr >> 1) & 3)) << 4);
            bf4[n] = *(const bf16x8*)((const char*)&sB[p][0] + by);
        }
        #pragma unroll
        for (int m = 0; m < 4; ++m)
            #pragma unroll
            for (int n = 0; n < 4; ++n)
                acc[m][n] = mfma16(af[m], bf4[n], acc[m][n]);
    };

    const int NC = K >> 5;   // 32 chunks; NLD = 3
    stage(0, 0);
    stage(32, 1);
    for (int j = 0; j + 2 < NC; ++j) {
        stage(32 * (j + 2), (j + 2) % 3);
        vmwait<6>(); bar();
        compute(j % 3);
        bar();
    }
    vmwait<3>(); bar();
    compute((NC - 2) % 3);
    vmwait<0>(); bar();
    compute((NC - 1) % 3);

    // silu(g)*u epilogue: adjacent lanes hold the (g,u) pair
    #pragma unroll
    for (int m = 0; m < 4; ++m)
        #pragma unroll
        for (int n = 0; n < 4; ++n)
            #pragma unroll
            for (int r = 0; r < 4; ++r) {
                int grow = row0 + wr * 64 + m * 16 + lg * 4 + r;
                int gcol = col0 + wc * 64 + n * 16 + lr;
                float v = acc[m][n][r];
                float pv = __shfl_xor(v, 1, 64);
                if (!(lr & 1)) {
                    float s = (v / (1.0f + __expf(-v))) * pv;
                    Ch[(size_t)grow * ldc + (gcol >> 1)] = (bf16_t)s;
                }
            }
}

// Logits GEMM, phase-split deep pipeline (T3+T4+T5): 256x256 tile, 8 waves,
// K-tile=64 = 2 ks-chunks of 32 in the proven [256][32] XOR-swizzled layout.
// LDS 128 KB double-buffered; vmcnt(8) counted waits (never drains mid-loop).
__global__ __launch_bounds__(512, 2)
void gemm_logits8(const bf16_t* __restrict__ Ah, const bf16_t* __restrict__ Bh,
                  float* __restrict__ Cf)
{
    constexpr int lda = 1024, ldb = 1024, ldc = 32000;
    constexpr int NT = 16;   // K-tiles of 64
    __shared__ __align__(16) bf16_t sA[2][2][256 * 32];
    __shared__ __align__(16) bf16_t sB[2][2][256 * 32];

    const int gx = gridDim.x;
    int id = blockIdx.x + gx * blockIdx.y;
    {   // bijective XCD swizzle
        int nwg = gx * gridDim.y;
        int q = nwg >> 3, r = nwg & 7;
        int xcd = id & 7, ix = id >> 3;
        id = (xcd < r ? xcd * (q + 1) : r * (q + 1) + (xcd - r) * q) + ix;
    }
    const int bm = id % gx, bn = id / gx;
    const int row0 = bm * 256, col0 = bn * 256;

    const int tid = threadIdx.x, lane = tid & 63, wave = tid >> 6;
    const int lr = lane & 15, lg = lane >> 4;
    const int wr = wave >> 2, wc = wave & 3;   // 2x4 wave grid

    f32x4 acc[8][4];
    #pragma unroll
    for (int m = 0; m < 8; ++m)
        #pragma unroll
        for (int n = 0; n < 4; ++n) acc[m][n] = (f32x4){0.f, 0.f, 0.f, 0.f};

    auto stageA = [&](int chunk, int buf, int ks) {
        int k0 = chunk * 32;
        #pragma unroll
        for (int i = wave; i < 16; i += 8) {
            int s = i * 64 + lane, rr = s >> 2, c = s & 3;
            size_t go = (size_t)(row0 + rr) * lda + k0 + ((c ^ ((rr >> 1) & 3)) << 3);
            GLDS(Ah + go, &sA[buf][ks][i * 512]);
        }
    };
    auto stageB = [&](int chunk, int buf, int ks) {
        int k0 = chunk * 32;
        #pragma unroll
        for (int i = wave; i < 16; i += 8) {
            int s = i * 64 + lane, rr = s >> 2, c = s & 3;
            size_t go = (size_t)(col0 + rr) * ldb + k0 + ((c ^ ((rr >> 1) & 3)) << 3);
            GLDS(Bh + go, &sB[buf][ks][i * 512]);
        }
    };

    auto phase = [&](int t, auto ksc) {
        constexpr int ks = decltype(ksc)::value;
        const int buf = t & 1;
        bf16x8 af[8], bf4[4];
        #pragma unroll
        for (int m = 0; m < 8; ++m) {
            int rr = wr * 128 + m * 16 + lr;
            int by = rr * 64 + ((lg ^ ((rr >> 1) & 3)) << 4);
            af[m] = *(const bf16x8*)((const char*)&sA[buf][ks][0] + by);
        }
        #pragma unroll
        for (int n = 0; n < 4; ++n) {
            int rr = wc * 64 + n * 16 + lr;
            int by = rr * 64 + ((lg ^ ((rr >> 1) & 3)) << 4);
            bf4[n] = *(const bf16x8*)((const char*)&sB[buf][ks][0] + by);
        }
        if constexpr (ks == 0) {
            if (t + 1 < NT) {
                stageA(2 * (t + 1) + 1, (t + 1) & 1, 1);
                stageB(2 * (t + 1) + 1, (t + 1) & 1, 1);
                vmwait<8>();
            } else {
                vmwait<0>();
            }
        } else {
            if (t + 2 < NT) {
                stageA(2 * (t + 2), t & 1, 0);
                stageB(2 * (t + 2), t & 1, 0);
                vmwait<8>();
            } else if (t + 1 < NT) {
                vmwait<4>();
            } else {
                vmwait<0>();
            }
        }
        bar();
        lgkm0();
        __builtin_amdgcn_s_setprio(1);
        #pragma unroll
        for (int m = 0; m < 8; ++m)
            #pragma unroll
            for (int n = 0; n < 4; ++n)
                acc[m][n] = mfma16(af[m], bf4[n], acc[m][n]);
        __builtin_amdgcn_s_setprio(0);
        bar();
    };

    stageA(0, 0, 0); stageB(0, 0, 0);
    stageA(1, 0, 1); stageB(1, 0, 1);
    stageA(2, 1, 0); stageB(2, 1, 0);
    vmwait<8>(); bar();

    for (int t = 0; t < NT; ++t) {
        phase(t, IC<0>{});
        phase(t, IC<1>{});
    }

    #pragma unroll
    for (int m = 0; m < 8; ++m)
        #pragma unroll
        for (int n = 0; n < 4; ++n)
            #pragma unroll
            for (int r = 0; r < 4; ++r) {
                int grow = row0 + wr * 128 + m * 16 + lg * 4 + r;
                int gcol = col0 + wc * 64 + n * 16 + lr;
                Cf[(size_t)grow * ldc + gcol] = acc[m][n][r];
            }
}

// weight-pack body: b2 in [0,4096); handles 4 chunks of 1024 f32 each.
static __device__ __forceinline__ void wsplit_body(
    int b2, int tid,
    const float* wq, const float* wk, const float* wv, const float* wo,
    const float* wg, const float* wu, const float* wd,
    bf16_t* wAh, bf16_t* wGUh, bf16_t* wdh)
{
    #pragma unroll
    for (int k = 0; k < 4; ++k) {
        int b = b2 * 4 + k;
        const float* src;
        bf16_t* dst;
        size_t so, doff;
        if (b < 4096) {
            src = b < 1024 ? wq : b < 2048 ? wk : b < 3072 ? wv : wo;
            so = (size_t)(b & 1023) * 256 + tid;
            doff = (size_t)b * 256 + tid;
            dst = wAh;
        } else if (b < 12288) {
            int bb = b - 4096;
            int row = bb < 4096 ? 2 * bb : 2 * (bb - 4096) + 1;
            src = bb < 4096 ? wg : wu;
            so = (size_t)(bb & 4095) * 256 + tid;
            doff = (size_t)row * 256 + tid;
            dst = wGUh;
        } else {
            src = wd;
            so = (size_t)(b - 12288) * 256 + tid;
            doff = so;
            dst = wdh;
        }
        f32x4 v = ((const f32x4*)src)[so];
        bf16x4 hv;
        #pragma unroll
        for (int j = 0; j < 4; ++j) hv[j] = (bf16_t)v[j];
        ((bf16x4*)dst)[doff] = hv;
    }
}

// blocks 0-1023: h += 4 split-K partials then RMS-norm -> hi plane.
__global__ __launch_bounds__(256)
void reduce_rms(const float* __restrict__ p, float* __restrict__ h,
                const float* __restrict__ w, bf16_t* __restrict__ outh)
{
    int blk = blockIdx.x, tid = threadIdx.x;
    size_t i = (size_t)blk * 256 + tid;
    const size_t S = (1024 * 1024) / 4;
    f32x4 a = ((const f32x4*)p)[i];
    f32x4 b = ((const f32x4*)p)[i + S];
    f32x4 c = ((const f32x4*)p)[i + 2 * S];
    f32x4 d = ((const f32x4*)p)[i + 3 * S];
    f32x4 hv = ((const f32x4*)h)[i];
    #pragma unroll
    for (int j = 0; j < 4; ++j) hv[j] += (a[j] + b[j]) + (c[j] + d[j]);
    ((f32x4*)h)[i] = hv;

    float ss = hv[0]*hv[0] + hv[1]*hv[1] + hv[2]*hv[2] + hv[3]*hv[3];
    #pragma unroll
    for (int m = 1; m < 64; m <<= 1) ss += __shfl_xor(ss, m, 64);
    __shared__ float red[4];
    if ((tid & 63) == 0) red[tid >> 6] = ss;
    __syncthreads();
    float tot = red[0] + red[1] + red[2] + red[3];
    float inv = rsqrtf(tot * (1.0f / 1024.0f) + RMS_EPS);
    f32x4 wt4 = *(const f32x4*)(w + tid * 4);
    bf16x4 hv4;
    #pragma unroll
    for (int j = 0; j < 4; ++j) hv4[j] = (bf16_t)(hv[j] * inv * wt4[j]);
    ((bf16x4*)outh)[i] = hv4;
}

// blocks 0-1023: gather embed row, write fp32 h, RMS-norm -> hi.
// blocks 1024-5119: pack layer-0 weights (set 0).
// blocks 5120-13119: convert embed (32000x1024 f32) -> eh bf16 (4 chunks/blk).
__global__ __launch_bounds__(256)
void gather_rms_wsplit(const int* __restrict__ ids, const float* __restrict__ embed,
                       const float* __restrict__ w, float* __restrict__ h,
                       bf16_t* __restrict__ outh,
                       const float* wq, const float* wk, const float* wv,
                       const float* wo, const float* wg, const float* wu,
                       const float* wd, bf16_t* wAh, bf16_t* wGUh, bf16_t* wdh,
                       bf16_t* __restrict__ eh)
{
    int blk = blockIdx.x, tid = threadIdx.x;
    if (blk >= 5120) {
        int b2 = blk - 5120;
        #pragma unroll
        for (int k = 0; k < 4; ++k) {
            size_t so = ((size_t)b2 * 4 + k) * 256 + tid;
            f32x4 v = ((const f32x4*)embed)[so];
            bf16x4 hv;
            #pragma unroll
            for (int j = 0; j < 4; ++j) hv[j] = (bf16_t)v[j];
            ((bf16x4*)eh)[so] = hv;
        }
        return;
    }
    if (blk >= 1024) {
        wsplit_body(blk - 1024, tid, wq, wk, wv, wo, wg, wu, wd, wAh, wGUh, wdh);
        return;
    }
    int row = ids[blk];
    f32x4 v = ((const f32x4*)(embed + (size_t)row * 1024))[tid];
    ((f32x4*)(h + (size_t)blk * 1024))[tid] = v;

    float ss = v[0]*v[0] + v[1]*v[1] + v[2]*v[2] + v[3]*v[3];
    #pragma unroll
    for (int m = 1; m < 64; m <<= 1) ss += __shfl_xor(ss, m, 64);
    __shared__ float red[4];
    if ((tid & 63) == 0) red[tid >> 6] = ss;
    __syncthreads();
    float tot = red[0] + red[1] + red[2] + red[3];
    float inv = rsqrtf(tot * (1.0f / 1024.0f) + RMS_EPS);
    f32x4 wt4 = *(const f32x4*)(w + tid * 4);
    bf16x4 hv;
    #pragma unroll
    for (int j = 0; j < 4; ++j) hv[j] = (bf16_t)(v[j] * inv * wt4[j]);
    ((bf16x4*)outh)[(size_t)blk * 256 + tid] = hv;
}

// Flash attention: block (qb,hh) handles q-chunk qb (32 rows), KB=64 keys/tile.
// 512 blocks, 2 waves. Q,K hi-only; V hi+lo; softcap (HW-exp tanh) + causal +
// online softmax fp32; P hi/lo via per-wave LDS; 3-term P.V. O hi-only.
__global__ __launch_bounds__(128, 2)
void flash_attn(const bf16_t* __restrict__ qkvh,
                const bf16_t* __restrict__ vTh, const bf16_t* __restrict__ vTl,
                bf16_t* __restrict__ oh)
{
    __shared__ __align__(16) bf16_t sQ[32*64], sK[64*64], sVh[64*64], sVl[64*64];
    __shared__ __align__(16) bf16_t sPh[32*64], sPl[32*64];

    const int q0 = blockIdx.x * 32;
    const int hh = blockIdx.y;
    const int tid = threadIdx.x, lane = tid & 63, w = tid >> 6;
    const int lr = lane & 15, lg = lane >> 4;

    #pragma unroll
    for (int ii = 0; ii < 2; ++ii) {
        int r0 = w * 16 + ii * 8;
        int r  = r0 + (lane >> 3);
        int i  = lane & 7;
        GLDS(qkvh + (size_t)(q0 + r) * 3072 + hh * 64 + ((i ^ (r & 7)) << 3),
             sQ + r0 * 64);
    }
    __syncthreads();

    bf16x8 qa[2];
    #pragma unroll
    for (int ks = 0; ks < 2; ++ks) {
        int r = w * 16 + lr;
        qa[ks] = *(const bf16x8*)((const char*)sQ + r * 128 +
                                  ((((ks << 2) | lg) ^ (r & 7)) << 4));
    }

    f32x4 o_acc[4];
    #pragma unroll
    for (int n = 0; n < 4; ++n) o_acc[n] = (f32x4){0.f, 0.f, 0.f, 0.f};
    float m_run[4] = {-1e30f, -1e30f, -1e30f, -1e30f};
    float l_run[4] = {0.f, 0.f, 0.f, 0.f};

    const int ntiles = ((q0 + 31) >> 6) + 1;
    for (int t = 0; t < ntiles; ++t) {
        const int kv0 = t * 64;
        #pragma unroll
        for (int ii = 0; ii < 4; ++ii) {
            int r0 = w * 32 + ii * 8;
            int r  = r0 + (lane >> 3);
            int i  = lane & 7;
            GLDS(qkvh + (size_t)(kv0 + r) * 3072 + 1024 + hh * 64 + ((i ^ (r & 7)) << 3),
                 sK + r0 * 64);
            GLDS(vTh + (size_t)(hh * 64 + r) * 1024 + kv0 + ((i ^ (r & 7)) << 3),
                 sVh + r0 * 64);
            GLDS(vTl + (size_t)(hh * 64 + r) * 1024 + kv0 + ((i ^ (r & 7)) << 3),
                 sVl + r0 * 64);
        }
        __syncthreads();

        f32x4 s_acc[4];
        #pragma unroll
        for (int n = 0; n < 4; ++n) s_acc[n] = (f32x4){0.f, 0.f, 0.f, 0.f};
        #pragma unroll
        for (int ks = 0; ks < 2; ++ks)
            #pragma unroll
            for (int n = 0; n < 4; ++n) {
                int r = n * 16 + lr;
                bf16x8 kb = *(const bf16x8*)((const char*)sK + r * 128 +
                                             ((((ks << 2) | lg) ^ (r & 7)) << 4));
                s_acc[n] = mfma16(qa[ks], kb, s_acc[n]);
            }

        #pragma unroll
        for (int j = 0; j < 4; ++j) {
            int qr = q0 + w * 16 + lg * 4 + j;
            float p[4];
            float mx = -1e30f;
            #pragma unroll
            for (int n = 0; n < 4; ++n) {
                float sx = s_acc[n][j] * (0.125f * 0.02f);       // x = s*scale/50
                float v = 50.f * (1.f - 2.f / (1.f + __expf(2.f * sx)));
                int key = kv0 + n * 16 + lr;
                if (key > qr) v = -1e30f;
                p[n] = v;
                mx = fmaxf(mx, v);
            }
            #pragma unroll
            for (int m = 1; m < 16; m <<= 1) mx = fmaxf(mx, __shfl_xor(mx, m, 64));
            float mn = fmaxf(m_run[j], mx);
            float ef = __expf(m_run[j] - mn);
            m_run[j] = mn;
            float rs = 0.f;
            #pragma unroll
            for (int n = 0; n < 4; ++n) {
                float e = __expf(p[n] - mn);
                p[n] = e;
                rs += e;
            }
            #pragma unroll
            for (int m = 1; m < 16; m <<= 1) rs += __shfl_xor(rs, m, 64);
            l_run[j] = l_run[j] * ef + rs;
            #pragma unroll
            for (int n = 0; n < 4; ++n) o_acc[n][j] *= ef;
            int r = w * 16 + lg * 4 + j;
            #pragma unroll
            for (int n = 0; n < 4; ++n) {
                int c = n * 16 + lr;
                int byo = r * 128 + ((((c >> 3) ^ (r & 7)) << 4)) + ((c & 7) << 1);
                bf16_t hb = (bf16_t)p[n];
                *(bf16_t*)((char*)sPh + byo) = hb;
                *(bf16_t*)((char*)sPl + byo) = (bf16_t)(p[n] - (float)hb);
            }
        }

        #pragma unroll
        for (int ks = 0; ks < 2; ++ks) {
            int pr = w * 16 + lr;
            int pby = pr * 128 + ((((ks << 2) | lg) ^ (pr & 7)) << 4);
            bf16x8 pa  = *(const bf16x8*)((const char*)sPh + pby);
            bf16x8 pl_ = *(const bf16x8*)((const char*)sPl + pby);
            #pragma unroll
            for (int n = 0; n < 4; ++n) {
                int vr = n * 16 + lr;
                int vby = vr * 128 + ((((ks << 2) | lg) ^ (vr & 7)) << 4);
                bf16x8 vhf = *(const bf16x8*)((const char*)sVh + vby);
                bf16x8 vlf = *(const bf16x8*)((const char*)sVl + vby);
                o_acc[n] = mfma16(pa,  vhf, o_acc[n]);
                o_acc[n] = mfma16(pl_, vhf, o_acc[n]);
                o_acc[n] = mfma16(pa,  vlf, o_acc[n]);
            }
        }
        __syncthreads();
    }

    #pragma unroll
    for (int j = 0; j < 4; ++j) {
        float inv = 1.0f / l_run[j];
        int qr = q0 + w * 16 + lg * 4 + j;
        #pragma unroll
        for (int n = 0; n < 4; ++n) {
            size_t off = (size_t)qr * 1024 + hh * 64 + n * 16 + lr;
            oh[off] = (bf16_t)(o_acc[n][j] * inv);
        }
    }
}

__global__ __launch_bounds__(256)
void rmsnorm_split(const float* __restrict__ in, const float* __restrict__ w,
                   bf16_t* __restrict__ outh)
{
    int row = blockIdx.x, tid = threadIdx.x;
    f32x4 v = *(const f32x4*)(in + (size_t)row * 1024 + tid * 4);
    float ss = v[0]*v[0] + v[1]*v[1] + v[2]*v[2] + v[3]*v[3];
    #pragma unroll
    for (int m = 1; m < 64; m <<= 1) ss += __shfl_xor(ss, m, 64);
    __shared__ float red[4];
    if ((tid & 63) == 0) red[tid >> 6] = ss;
    __syncthreads();
    float tot = red[0] + red[1] + red[2] + red[3];
    float inv = rsqrtf(tot * (1.0f / 1024.0f) + RMS_EPS);
    f32x4 wt4 = *(const f32x4*)(w + tid * 4);
    bf16x4 hv;
    #pragma unroll
    for (int j = 0; j < 4; ++j) hv[j] = (bf16_t)(v[j] * inv * wt4[j]);
    ((bf16x4*)outh)[(size_t)row * 256 + tid] = hv;
}

extern "C" void kernel_launch(void* const* d_in, const int* in_sizes, int n_in,
                              void* d_out, int out_size, void* d_ws, size_t ws_size,
                              hipStream_t stream)
{
    (void)in_sizes; (void)n_in; (void)out_size; (void)ws_size;
    const int*   x_ids = (const int*)  d_in[0];
    const float* embed = (const float*)d_in[1];
    const float* ln1   = (const float*)d_in[2];
    const float* Wq    = (const float*)d_in[3];
    const float* Wk    = (const float*)d_in[4];
    const float* Wv    = (const float*)d_in[5];
    const float* Wo    = (const float*)d_in[6];
    const float* qn    = (const float*)d_in[7];
    const float* kn    = (const float*)d_in[8];
    const float* ln2   = (const float*)d_in[9];
    const float* Wg    = (const float*)d_in[10];
    const float* Wu    = (const float*)d_in[11];
    const float* Wd    = (const float*)d_in[12];
    const float* lnout = (const float*)d_in[13];
    float* out = (float*)d_out;

    char* ws = (char*)d_ws;
    const size_t MB = 1 << 20;
    float*  h    = (float*) (ws +   0 * MB);  // 4 MB fp32 residual
    bf16_t* hnh  = (bf16_t*)(ws +   4 * MB);
    bf16_t* qkvh = (bf16_t*)(ws +   8 * MB);  // 6 MB [1024][3072] (q,k cols)
    bf16_t* vTh  = (bf16_t*)(ws +  20 * MB);
    bf16_t* vTl  = (bf16_t*)(ws +  22 * MB);
    bf16_t* oh   = (bf16_t*)(ws +  24 * MB);
    // double-buffered packed weight sets (layer l uses set l&1):
    bf16_t* wA[2]  = {(bf16_t*)(ws +  28 * MB), (bf16_t*)(ws +  84 * MB)};
    bf16_t* wGU[2] = {(bf16_t*)(ws +  36 * MB), (bf16_t*)(ws +  92 * MB)};
    bf16_t* wD[2]  = {(bf16_t*)(ws +  52 * MB), (bf16_t*)(ws + 108 * MB)};
    bf16_t* silh = (bf16_t*)(ws +  60 * MB);  //  8 MB [1024][4096]
    float*  wdp  = (float*) (ws +  68 * MB);  // 16 MB split-K partials
    bf16_t* eh   = (bf16_t*)(ws + 116 * MB);  // 62.5 MB (high-water ~179 MB)

    const long long M1 = 1024 * 1024;

    // gather+rms (1024) | layer-0 weight pack (4096) | embed->bf16 (8000)
    gather_rms_wsplit<<<13120, 256, 0, stream>>>(
        x_ids, embed, ln1, h, hnh,
        Wq, Wk, Wv, Wo, Wg, Wu, Wd, wA[0], wGU[0], wD[0], eh);

    for (int l = 0; l < 6; ++l) {
        const int s = l & 1, nx = s ^ 1;

        // fused QKV + qk-RMSnorm + RoPE + V-transpose (1-plane, 3-buffer)
        gemm_bf16<64,128,2,2,1,EP_QKV,4,3><<<dim3(16,24),256,0,stream>>>(
            hnh, nullptr, wA[s], (float*)vTl, qkvh, vTh, 1024, 1024, 1024, 3072, 0,
            qn + l * 64, kn + l * 64);

        // fused scores+softcap+mask+softmax+PV; O hi-only
        flash_attn<<<dim3(32,16), 128, 0, stream>>>(qkvh, vTh, vTl, oh);

        // Wo residual (1-plane, 3-buffer, 64^2 tiles)
        gemm_bf16<64,64,2,2,1,EP_RESID,4,3><<<dim3(16,16),256,0,stream>>>(
            oh, nullptr, wA[s] + 3 * M1, h, nullptr, nullptr, 1024, 1024, 1024, 1024, 0,
            nullptr, nullptr);

        rmsnorm_split<<<1024, 256, 0, stream>>>(h, ln2 + l * 1024, hnh);

        // fused gate+up+silu GEMM + NEXT-layer weight pack (z=1 blocks)
        gemm_gu_pack<<<dim3(8,32,2), 512, 0, stream>>>(
            hnh, wGU[s], silh,
            l < 5 ? Wq + (size_t)(l+1) * M1 : nullptr,
            l < 5 ? Wk + (size_t)(l+1) * M1 : nullptr,
            l < 5 ? Wv + (size_t)(l+1) * M1 : nullptr,
            l < 5 ? Wo + (size_t)(l+1) * M1 : nullptr,
            l < 5 ? Wg + (size_t)(l+1) * 4 * M1 : nullptr,
            l < 5 ? Wu + (size_t)(l+1) * 4 * M1 : nullptr,
            l < 5 ? Wd + (size_t)(l+1) * 4 * M1 : nullptr,
            wA[nx], wGU[nx], wD[nx]);

        // down-proj: split-K x4 (1-plane, 3-buffer) -> partials
        gemm_bf16<128,128,2,2,1,EP_STORE,4,3><<<dim3(8,8,4),256,0,stream>>>(
            silh, nullptr, wD[s], wdp, nullptr, nullptr, 1024, 4096, 4096, 1024, M1,
            nullptr, nullptr);

        // reduce partials into h + next pre-norm (ln1[l+1], or ln_out last)
        const float* wnext = (l < 5) ? (ln1 + (l + 1) * 1024) : lnout;
        reduce_rms<<<1024, 256, 0, stream>>>(wdp, h, wnext, hnh);
    }

    // logits: phase-split deep pipeline, 256x256, 8 waves, 128 KB LDS
    gemm_logits8<<<dim3(4,125), 512, 0, stream>>>(hnh, eh, out);
}

// Round 21
// 1094.616 us; speedup vs baseline: 1.0792x; 1.0274x over previous
//
#include <hip/hip_runtime.h>
#include <math.h>
#include <type_traits>

typedef __bf16 bf16_t;
typedef bf16_t bf16x4 __attribute__((ext_vector_type(4)));
typedef bf16_t bf16x8 __attribute__((ext_vector_type(8)));
typedef float  f32x4  __attribute__((ext_vector_type(4)));

#define RMS_EPS 1e-6f

enum { EP_STORE = 0, EP_RESID = 1, EP_SPLIT = 2, EP_SILU = 3, EP_QKV = 4 };

template<int V> using IC = std::integral_constant<int, V>;

static __device__ __forceinline__ f32x4 mfma16(bf16x8 a, bf16x8 b, f32x4 c) {
    return __builtin_amdgcn_mfma_f32_16x16x32_bf16(a, b, c, 0, 0, 0);
}

#define GLDS(gp, lp) __builtin_amdgcn_global_load_lds( \
    (const __attribute__((address_space(1))) void*)(gp), \
    (__attribute__((address_space(3))) void*)(lp), 16, 0, 0)

// counted vector-memory wait (T4): leave N newest loads in flight.
template<int N> static __device__ __forceinline__ void vmwait() {
    if constexpr (N == 0)      asm volatile("s_waitcnt vmcnt(0)" ::: "memory");
    else if constexpr (N == 2) asm volatile("s_waitcnt vmcnt(2)" ::: "memory");
    else if constexpr (N == 3) asm volatile("s_waitcnt vmcnt(3)" ::: "memory");
    else if constexpr (N == 4) asm volatile("s_waitcnt vmcnt(4)" ::: "memory");
    else if constexpr (N == 6) asm volatile("s_waitcnt vmcnt(6)" ::: "memory");
    else if constexpr (N == 8) asm volatile("s_waitcnt vmcnt(8)" ::: "memory");
    __builtin_amdgcn_sched_barrier(0);
}
static __device__ __forceinline__ void bar() { __builtin_amdgcn_s_barrier(); }
static __device__ __forceinline__ void lgkm0() {
    asm volatile("s_waitcnt lgkmcnt(0)" ::: "memory");
    __builtin_amdgcn_sched_barrier(0);   // rule #18: fence MFMA hoisting
}

// C[M,N] = A[M,K]*B[N,K]^T.
// PLANES==2: A split hi/lo, B hi-only (2 MFMAs).  PLANES==1: pure bf16.
// WR x WC wave grid. Counted-vmcnt pipelined K-loop, DEPTH buffers.
// NO setprio here: T5 is measured-negative on barrier-lockstep GEMMs (m190).
// EP_QKV : fused qk-RMSnorm + RoPE epilogue (wave's WN=64 col span = one head);
//          q/k -> Ch (cols [0,2048)); v written TRANSPOSED: hi -> Cl (= vTh),
//          lo -> (bf16_t*)Cf (= vTl). Per-thread 8-byte contiguous runs.
//          Rope quirk: angle = head_index * freq (reference's cos[:n], n=H).
// blockIdx.z = K-chunk for split-K.
template<int BM, int BN, int WR, int WC, int PLANES, int EPIL, int MINW, int DEPTH>
__global__ __launch_bounds__(WR * WC * 64, MINW)
void gemm_bf16(const bf16_t* __restrict__ Ah, const bf16_t* __restrict__ Al,
               const bf16_t* __restrict__ Bh,
               float* __restrict__ Cf, bf16_t* __restrict__ Ch, bf16_t* __restrict__ Cl,
               int K, int lda, int ldb, int ldc, long long sC,
               const float* __restrict__ qnw, const float* __restrict__ knw)
{
    constexpr int ASZ = BM * 32, BSZ = BN * 32;
    constexpr int NW = WR * WC;
    constexpr int NLD = (BM / 16 * (PLANES >= 2 ? 2 : 1) + BN / 16) / NW;
    __shared__ __align__(16) bf16_t sAh[DEPTH][ASZ], sBh[DEPTH][BSZ];
    __shared__ __align__(16) bf16_t sAl[PLANES >= 2 ? DEPTH : 1][PLANES >= 2 ? ASZ : 8];

    const int gx = gridDim.x;
    int id = blockIdx.x + gx * blockIdx.y;
    if (gridDim.z == 1) {  // bijective XCD swizzle (m204)
        int nwg = gx * gridDim.y;
        int q = nwg >> 3, r = nwg & 7;
        int xcd = id & 7, ix = id >> 3;
        id = (xcd < r ? xcd * (q + 1) : r * (q + 1) + (xcd - r) * q) + ix;
    }
    const int bm = id % gx, bn = id / gx;
    const int row0 = bm * BM, col0 = bn * BN;

    const size_t kofs = (size_t)blockIdx.z * K;
    Ah += kofs;  Bh += kofs;
    if constexpr (PLANES >= 2) Al += kofs;

    const int tid = threadIdx.x, lane = tid & 63, wave = tid >> 6;
    const int lr = lane & 15, lg = lane >> 4;
    constexpr int WM = BM / WR, WN = BN / WC, MF = WM / 16, NF = WN / 16;
    const int wr = wave / WC, wc = wave % WC;

    f32x4 acc[MF][NF];
    #pragma unroll
    for (int m = 0; m < MF; ++m)
        #pragma unroll
        for (int n = 0; n < NF; ++n) acc[m][n] = (f32x4){0.f, 0.f, 0.f, 0.f};

    auto stage = [&](int k0, int p) {
        #pragma unroll
        for (int i = wave; i < BM / 16; i += NW) {
            int s = i * 64 + lane, rr = s >> 2, c = s & 3;
            size_t go = (size_t)(row0 + rr) * lda + k0 + ((c ^ ((rr >> 1) & 3)) << 3);
            GLDS(Ah + go, &sAh[p][i * 512]);
            if constexpr (PLANES >= 2) GLDS(Al + go, &sAl[p][i * 512]);
        }
        #pragma unroll
        for (int i = wave; i < BN / 16; i += NW) {
            int s = i * 64 + lane, rr = s >> 2, c = s & 3;
            size_t go = (size_t)(col0 + rr) * ldb + k0 + ((c ^ ((rr >> 1) & 3)) << 3);
            GLDS(Bh + go, &sBh[p][i * 512]);
        }
    };

    auto compute = [&](int p) {
        bf16x8 ahf[MF], alf[MF], bhf[NF];
        #pragma unroll
        for (int m = 0; m < MF; ++m) {
            int rr = wr * WM + m * 16 + lr;
            int by = rr * 64 + ((lg ^ ((rr >> 1) & 3)) << 4);
            ahf[m] = *(const bf16x8*)((const char*)&sAh[p][0] + by);
            if constexpr (PLANES >= 2)
                alf[m] = *(const bf16x8*)((const char*)&sAl[p][0] + by);
        }
        #pragma unroll
        for (int n = 0; n < NF; ++n) {
            int rr = wc * WN + n * 16 + lr;
            int by = rr * 64 + ((lg ^ ((rr >> 1) & 3)) << 4);
            bhf[n] = *(const bf16x8*)((const char*)&sBh[p][0] + by);
        }
        #pragma unroll
        for (int m = 0; m < MF; ++m)
            #pragma unroll
            for (int n = 0; n < NF; ++n) {
                acc[m][n] = mfma16(ahf[m], bhf[n], acc[m][n]);
                if constexpr (PLANES >= 2)
                    acc[m][n] = mfma16(alf[m], bhf[n], acc[m][n]);
            }
    };

    if constexpr (DEPTH == 3) {
        const int NC = K >> 5;          // 32-wide chunks
        stage(0, 0);
        stage(32, 1);
        for (int j = 0; j + 2 < NC; ++j) {
            stage(32 * (j + 2), (j + 2) % 3);
            vmwait<2 * NLD>(); bar();   // chunk j landed; j+1, j+2 in flight
            compute(j % 3);
            bar();                      // protect buf before next stage overwrites
        }
        vmwait<NLD>(); bar();
        compute((K >> 5) >= 2 ? ((K >> 5) - 2) % 3 : 0);
        vmwait<0>(); bar();
        compute(((K >> 5) - 1) % 3);
    } else {
        stage(0, 0);
        int k0 = 32;
        for (; k0 + 32 < K; k0 += 64) {
            stage(k0, 1);
            vmwait<NLD>(); bar();
            compute(0);
            bar();
            stage(k0 + 32, 0);
            vmwait<NLD>(); bar();
            compute(1);
            bar();
        }
        stage(k0, 1);
        vmwait<NLD>(); bar();
        compute(0);
        bar();
        vmwait<0>(); bar();
        compute(1);
    }

    if constexpr (EPIL == EP_QKV) {
        // wave's col span = [colbase, colbase+64) = one head-dim group
        const int colbase = col0 + wc * WN;          // multiple of 64
        const int typ = colbase >> 10;               // 0=q, 1=k, 2=v
        if (typ < 2) {
            const float* nw = (typ == 0) ? qnw : knw;
            const int hh = (colbase - typ * 1024) >> 6;  // head idx
            constexpr float kLogF = -0.41524101186092029f;  // -log2(10000)/32
            #pragma unroll
            for (int m = 0; m < MF; ++m)
                #pragma unroll
                for (int r = 0; r < 4; ++r) {
                    int grow = row0 + wr * WM + m * 16 + lg * 4 + r;
                    float ss = 0.f;
                    #pragma unroll
                    for (int n = 0; n < NF; ++n) {
                        float v = acc[m][n][r];
                        ss += v * v;
                    }
                    ss += __shfl_xor(ss, 1, 64);
                    ss += __shfl_xor(ss, 2, 64);
                    ss += __shfl_xor(ss, 4, 64);
                    ss += __shfl_xor(ss, 8, 64);
                    float inv = rsqrtf(ss * (1.0f / 64.0f) + RMS_EPS);
                    #pragma unroll
                    for (int n = 0; n < NF; ++n) {
                        int i = n * 16 + lr;
                        float x = acc[m][n][r] * inv * nw[i];
                        float p = __shfl_xor(x, 1, 64);
                        float f = exp2f((float)(i >> 1) * kLogF);
                        float ang = (float)hh * f;
                        float cs = cosf(ang), sn = sinf(ang);
                        float o = (lr & 1) ? (p * sn + x * cs) : (x * cs - p * sn);
                        Ch[(size_t)grow * ldc + colbase + i] = (bf16_t)o;
                    }
                }
        } else {
            // v: write TRANSPOSED planes (vT[vc][grow..grow+3], 8B runs)
            bf16_t* vTh_ = Cl;
            bf16_t* vTl_ = (bf16_t*)Cf;
            const int vcb = colbase - 2048;
            #pragma unroll
            for (int m = 0; m < MF; ++m)
                #pragma unroll
                for (int n = 0; n < NF; ++n) {
                    int vc = vcb + n * 16 + lr;
                    int grow0 = row0 + wr * WM + m * 16 + lg * 4;
                    bf16x4 hv, lv;
                    #pragma unroll
                    for (int r = 0; r < 4; ++r) {
                        float v = acc[m][n][r];
                        bf16_t hb = (bf16_t)v;
                        hv[r] = hb;
                        lv[r] = (bf16_t)(v - (float)hb);
                    }
                    *(bf16x4*)&vTh_[(size_t)vc * 1024 + grow0] = hv;
                    *(bf16x4*)&vTl_[(size_t)vc * 1024 + grow0] = lv;
                }
        }
        return;
    }

    #pragma unroll
    for (int m = 0; m < MF; ++m)
        #pragma unroll
        for (int n = 0; n < NF; ++n)
            #pragma unroll
            for (int r = 0; r < 4; ++r) {
                int grow = row0 + wr * WM + m * 16 + lg * 4 + r;
                int gcol = col0 + wc * WN + n * 16 + lr;
                float v = acc[m][n][r];
                size_t off = (size_t)blockIdx.z * sC + (size_t)grow * ldc + gcol;
                if constexpr (EPIL == EP_STORE) {
                    Cf[off] = v;
                } else if constexpr (EPIL == EP_RESID) {
                    Cf[off] += v;
                } else if constexpr (EPIL == EP_SPLIT) {
                    bf16_t hb = (bf16_t)v;
                    Ch[off] = hb;
                    Cl[off] = (bf16_t)(v - (float)hb);
                }
            }
}

// GU GEMM (sil = silu(g)*u, 128x256 tile, 8 waves, DEPTH-3 counted-vmcnt)
// PLUS z==1: next-layer weight pack (disjoint dst buffer set)
// PLUS z==2: embed->bf16 conversion slice [es, ee) in f32x4 units.
// Both memory sections overlap with the MFMA-bound GEMM blocks.
__global__ __launch_bounds__(512, 4)
void gemm_gu_pack(const bf16_t* __restrict__ Ah, const bf16_t* __restrict__ Bh,
                  bf16_t* __restrict__ Ch,
                  const float* wq, const float* wk, const float* wv,
                  const float* wo, const float* wg, const float* wu,
                  const float* wd, bf16_t* wAd, bf16_t* wGUd, bf16_t* wdd,
                  const float* __restrict__ embed, bf16_t* __restrict__ eh,
                  int es, int ee)
{
    constexpr int lda = 1024, ldb = 1024, ldc = 4096, K = 1024;
    const int tid = threadIdx.x;

    if (blockIdx.z == 2) {     // embed->bf16 conversion slice
        int base = ((int)blockIdx.y * 8 + (int)blockIdx.x) * 512 + tid;
        for (int j = 0; j < 11; ++j) {
            int u = es + j * 131072 + base;
            if (u < ee) {
                f32x4 v = ((const f32x4*)embed)[u];
                bf16x4 hv;
                #pragma unroll
                for (int q2 = 0; q2 < 4; ++q2) hv[q2] = (bf16_t)v[q2];
                ((bf16x4*)eh)[u] = hv;
            }
        }
        return;
    }

    if (blockIdx.z == 1) {     // pack next layer's weights -> other buffer set
        if (!wq) return;
        int base = ((int)blockIdx.y * 8 + (int)blockIdx.x) * 512 + tid;
        #pragma unroll 4
        for (int j = 0; j < 32; ++j) {
            int v = j * 131072 + base;      // 0..4194303 f32x4 units
            f32x4 val;
            bf16_t* dst;
            size_t doff;
            if (v < (1 << 20)) {            // wq|wk|wv|wo -> wAd [4096x1024]
                int b = v >> 8, col = v & 255;
                const float* src = b < 1024 ? wq : b < 2048 ? wk : b < 3072 ? wv : wo;
                val = ((const f32x4*)src)[(size_t)(b & 1023) * 256 + col];
                dst = wAd; doff = (size_t)b * 256 + col;
            } else if (v < 3 * (1 << 20)) { // wg|wu INTERLEAVED -> wGUd
                int u = v - (1 << 20);
                int bb = u >> 8, col = u & 255;
                int row = bb < 4096 ? 2 * bb : 2 * (bb - 4096) + 1;
                const float* src = bb < 4096 ? wg : wu;
                val = ((const f32x4*)src)[(size_t)(bb & 4095) * 256 + col];
                dst = wGUd; doff = (size_t)row * 256 + col;
            } else {                        // wd -> wdd
                int u = v - 3 * (1 << 20);
                val = ((const f32x4*)wd)[u];
                dst = wdd; doff = (size_t)u;
            }
            bf16x4 hv;
            #pragma unroll
            for (int q2 = 0; q2 < 4; ++q2) hv[q2] = (bf16_t)val[q2];
            ((bf16x4*)dst)[doff] = hv;
        }
        return;
    }

    __shared__ __align__(16) bf16_t sA[3][128 * 32], sB[3][256 * 32];

    int id = blockIdx.x + 8 * blockIdx.y;
    {   // bijective XCD swizzle (nwg = 256)
        int q = 256 >> 3;
        int xcd = id & 7, ix = id >> 3;
        id = xcd * q + ix;
    }
    const int bm = id % 8, bn = id / 8;
    const int row0 = bm * 128, col0 = bn * 256;

    const int lane = tid & 63, wave = tid >> 6;
    const int lr = lane & 15, lg = lane >> 4;
    const int wr = wave >> 2, wc = wave & 3;   // 2x4 waves; WM=WN=64

    f32x4 acc[4][4];
    #pragma unroll
    for (int m = 0; m < 4; ++m)
        #pragma unroll
        for (int n = 0; n < 4; ++n) acc[m][n] = (f32x4){0.f, 0.f, 0.f, 0.f};

    auto stage = [&](int k0, int p) {
        {
            int i = wave;
            int s = i * 64 + lane, rr = s >> 2, c = s & 3;
            size_t go = (size_t)(row0 + rr) * lda + k0 + ((c ^ ((rr >> 1) & 3)) << 3);
            GLDS(Ah + go, &sA[p][i * 512]);
        }
        #pragma unroll
        for (int i = wave; i < 16; i += 8) {
            int s = i * 64 + lane, rr = s >> 2, c = s & 3;
            size_t go = (size_t)(col0 + rr) * ldb + k0 + ((c ^ ((rr >> 1) & 3)) << 3);
            GLDS(Bh + go, &sB[p][i * 512]);
        }
    };

    auto compute = [&](int p) {
        bf16x8 af[4], bf4[4];
        #pragma unroll
        for (int m = 0; m < 4; ++m) {
            int rr = wr * 64 + m * 16 + lr;
            int by = rr * 64 + ((lg ^ ((rr >> 1) & 3)) << 4);
            af[m] = *(const bf16x8*)((const char*)&sA[p][0] + by);
        }
        #pragma unroll
        for (int n = 0; n < 4; ++n) {
            int rr = wc * 64 + n * 16 + lr;
            int by = rr * 64 + ((lg ^ ((rr >> 1) & 3)) << 4);
            bf4[n] = *(const bf16x8*)((const char*)&sB[p][0] + by);
        }
        #pragma unroll
        for (int m = 0; m < 4; ++m)
            #pragma unroll
            for (int n = 0; n < 4; ++n)
                acc[m][n] = mfma16(af[m], bf4[n], acc[m][n]);
    };

    const int NC = K >> 5;   // 32 chunks; NLD = 3
    stage(0, 0);
    stage(32, 1);
    for (int j = 0; j + 2 < NC; ++j) {
        stage(32 * (j + 2), (j + 2) % 3);
        vmwait<6>(); bar();
        compute(j % 3);
        bar();
    }
    vmwait<3>(); bar();
    compute((NC - 2) % 3);
    vmwait<0>(); bar();
    compute((NC - 1) % 3);

    // silu(g)*u epilogue: adjacent lanes hold the (g,u) pair
    #pragma unroll
    for (int m = 0; m < 4; ++m)
        #pragma unroll
        for (int n = 0; n < 4; ++n)
            #pragma unroll
            for (int r = 0; r < 4; ++r) {
                int grow = row0 + wr * 64 + m * 16 + lg * 4 + r;
                int gcol = col0 + wc * 64 + n * 16 + lr;
                float v = acc[m][n][r];
                float pv = __shfl_xor(v, 1, 64);
                if (!(lr & 1)) {
                    float s = (v / (1.0f + __expf(-v))) * pv;
                    Ch[(size_t)grow * ldc + (gcol >> 1)] = (bf16_t)s;
                }
            }
}

// Logits GEMM, phase-split deep pipeline (T3+T4+T5): 256x256 tile, 8 waves,
// K-tile=64 = 2 ks-chunks of 32 in the proven [256][32] XOR-swizzled layout.
// LDS 128 KB double-buffered; vmcnt(8) counted waits (never drains mid-loop).
__global__ __launch_bounds__(512, 2)
void gemm_logits8(const bf16_t* __restrict__ Ah, const bf16_t* __restrict__ Bh,
                  float* __restrict__ Cf)
{
    constexpr int lda = 1024, ldb = 1024, ldc = 32000;
    constexpr int NT = 16;   // K-tiles of 64
    __shared__ __align__(16) bf16_t sA[2][2][256 * 32];
    __shared__ __align__(16) bf16_t sB[2][2][256 * 32];

    const int gx = gridDim.x;
    int id = blockIdx.x + gx * blockIdx.y;
    {   // bijective XCD swizzle
        int nwg = gx * gridDim.y;
        int q = nwg >> 3, r = nwg & 7;
        int xcd = id & 7, ix = id >> 3;
        id = (xcd < r ? xcd * (q + 1) : r * (q + 1) + (xcd - r) * q) + ix;
    }
    const int bm = id % gx, bn = id / gx;
    const int row0 = bm * 256, col0 = bn * 256;

    const int tid = threadIdx.x, lane = tid & 63, wave = tid >> 6;
    const int lr = lane & 15, lg = lane >> 4;
    const int wr = wave >> 2, wc = wave & 3;   // 2x4 wave grid

    f32x4 acc[8][4];
    #pragma unroll
    for (int m = 0; m < 8; ++m)
        #pragma unroll
        for (int n = 0; n < 4; ++n) acc[m][n] = (f32x4){0.f, 0.f, 0.f, 0.f};

    auto stageA = [&](int chunk, int buf, int ks) {
        int k0 = chunk * 32;
        #pragma unroll
        for (int i = wave; i < 16; i += 8) {
            int s = i * 64 + lane, rr = s >> 2, c = s & 3;
            size_t go = (size_t)(row0 + rr) * lda + k0 + ((c ^ ((rr >> 1) & 3)) << 3);
            GLDS(Ah + go, &sA[buf][ks][i * 512]);
        }
    };
    auto stageB = [&](int chunk, int buf, int ks) {
        int k0 = chunk * 32;
        #pragma unroll
        for (int i = wave; i < 16; i += 8) {
            int s = i * 64 + lane, rr = s >> 2, c = s & 3;
            size_t go = (size_t)(col0 + rr) * ldb + k0 + ((c ^ ((rr >> 1) & 3)) << 3);
            GLDS(Bh + go, &sB[buf][ks][i * 512]);
        }
    };

    auto phase = [&](int t, auto ksc) {
        constexpr int ks = decltype(ksc)::value;
        const int buf = t & 1;
        bf16x8 af[8], bf4[4];
        #pragma unroll
        for (int m = 0; m < 8; ++m) {
            int rr = wr * 128 + m * 16 + lr;
            int by = rr * 64 + ((lg ^ ((rr >> 1) & 3)) << 4);
            af[m] = *(const bf16x8*)((const char*)&sA[buf][ks][0] + by);
        }
        #pragma unroll
        for (int n = 0; n < 4; ++n) {
            int rr = wc * 64 + n * 16 + lr;
            int by = rr * 64 + ((lg ^ ((rr >> 1) & 3)) << 4);
            bf4[n] = *(const bf16x8*)((const char*)&sB[buf][ks][0] + by);
        }
        if constexpr (ks == 0) {
            if (t + 1 < NT) {
                stageA(2 * (t + 1) + 1, (t + 1) & 1, 1);
                stageB(2 * (t + 1) + 1, (t + 1) & 1, 1);
                vmwait<8>();
            } else {
                vmwait<0>();
            }
        } else {
            if (t + 2 < NT) {
                stageA(2 * (t + 2), t & 1, 0);
                stageB(2 * (t + 2), t & 1, 0);
                vmwait<8>();
            } else if (t + 1 < NT) {
                vmwait<4>();
            } else {
                vmwait<0>();
            }
        }
        bar();
        lgkm0();
        __builtin_amdgcn_s_setprio(1);
        #pragma unroll
        for (int m = 0; m < 8; ++m)
            #pragma unroll
            for (int n = 0; n < 4; ++n)
                acc[m][n] = mfma16(af[m], bf4[n], acc[m][n]);
        __builtin_amdgcn_s_setprio(0);
        bar();
    };

    stageA(0, 0, 0); stageB(0, 0, 0);
    stageA(1, 0, 1); stageB(1, 0, 1);
    stageA(2, 1, 0); stageB(2, 1, 0);
    vmwait<8>(); bar();

    for (int t = 0; t < NT; ++t) {
        phase(t, IC<0>{});
        phase(t, IC<1>{});
    }

    #pragma unroll
    for (int m = 0; m < 8; ++m)
        #pragma unroll
        for (int n = 0; n < 4; ++n)
            #pragma unroll
            for (int r = 0; r < 4; ++r) {
                int grow = row0 + wr * 128 + m * 16 + lg * 4 + r;
                int gcol = col0 + wc * 64 + n * 16 + lr;
                Cf[(size_t)grow * ldc + gcol] = acc[m][n][r];
            }
}

// weight-pack body: b2 in [0,4096); handles 4 chunks of 1024 f32 each.
static __device__ __forceinline__ void wsplit_body(
    int b2, int tid,
    const float* wq, const float* wk, const float* wv, const float* wo,
    const float* wg, const float* wu, const float* wd,
    bf16_t* wAh, bf16_t* wGUh, bf16_t* wdh)
{
    #pragma unroll
    for (int k = 0; k < 4; ++k) {
        int b = b2 * 4 + k;
        const float* src;
        bf16_t* dst;
        size_t so, doff;
        if (b < 4096) {
            src = b < 1024 ? wq : b < 2048 ? wk : b < 3072 ? wv : wo;
            so = (size_t)(b & 1023) * 256 + tid;
            doff = (size_t)b * 256 + tid;
            dst = wAh;
        } else if (b < 12288) {
            int bb = b - 4096;
            int row = bb < 4096 ? 2 * bb : 2 * (bb - 4096) + 1;
            src = bb < 4096 ? wg : wu;
            so = (size_t)(bb & 4095) * 256 + tid;
            doff = (size_t)row * 256 + tid;
            dst = wGUh;
        } else {
            src = wd;
            so = (size_t)(b - 12288) * 256 + tid;
            doff = so;
            dst = wdh;
        }
        f32x4 v = ((const f32x4*)src)[so];
        bf16x4 hv;
        #pragma unroll
        for (int j = 0; j < 4; ++j) hv[j] = (bf16_t)v[j];
        ((bf16x4*)dst)[doff] = hv;
    }
}

// blocks 0-1023: h += 4 split-K partials then RMS-norm -> hi plane.
__global__ __launch_bounds__(256)
void reduce_rms(const float* __restrict__ p, float* __restrict__ h,
                const float* __restrict__ w, bf16_t* __restrict__ outh)
{
    int blk = blockIdx.x, tid = threadIdx.x;
    size_t i = (size_t)blk * 256 + tid;
    const size_t S = (1024 * 1024) / 4;
    f32x4 a = ((const f32x4*)p)[i];
    f32x4 b = ((const f32x4*)p)[i + S];
    f32x4 c = ((const f32x4*)p)[i + 2 * S];
    f32x4 d = ((const f32x4*)p)[i + 3 * S];
    f32x4 hv = ((const f32x4*)h)[i];
    #pragma unroll
    for (int j = 0; j < 4; ++j) hv[j] += (a[j] + b[j]) + (c[j] + d[j]);
    ((f32x4*)h)[i] = hv;

    float ss = hv[0]*hv[0] + hv[1]*hv[1] + hv[2]*hv[2] + hv[3]*hv[3];
    #pragma unroll
    for (int m = 1; m < 64; m <<= 1) ss += __shfl_xor(ss, m, 64);
    __shared__ float red[4];
    if ((tid & 63) == 0) red[tid >> 6] = ss;
    __syncthreads();
    float tot = red[0] + red[1] + red[2] + red[3];
    float inv = rsqrtf(tot * (1.0f / 1024.0f) + RMS_EPS);
    f32x4 wt4 = *(const f32x4*)(w + tid * 4);
    bf16x4 hv4;
    #pragma unroll
    for (int j = 0; j < 4; ++j) hv4[j] = (bf16_t)(hv[j] * inv * wt4[j]);
    ((bf16x4*)outh)[i] = hv4;
}

// blocks 0-1023: gather embed row, write fp32 h, RMS-norm -> hi.
// blocks 1024-5119: pack layer-0 weights (set 0).
__global__ __launch_bounds__(256)
void gather_rms_wsplit(const int* __restrict__ ids, const float* __restrict__ embed,
                       const float* __restrict__ w, float* __restrict__ h,
                       bf16_t* __restrict__ outh,
                       const float* wq, const float* wk, const float* wv,
                       const float* wo, const float* wg, const float* wu,
                       const float* wd, bf16_t* wAh, bf16_t* wGUh, bf16_t* wdh)
{
    int blk = blockIdx.x, tid = threadIdx.x;
    if (blk >= 1024) {
        wsplit_body(blk - 1024, tid, wq, wk, wv, wo, wg, wu, wd, wAh, wGUh, wdh);
        return;
    }
    int row = ids[blk];
    f32x4 v = ((const f32x4*)(embed + (size_t)row * 1024))[tid];
    ((f32x4*)(h + (size_t)blk * 1024))[tid] = v;

    float ss = v[0]*v[0] + v[1]*v[1] + v[2]*v[2] + v[3]*v[3];
    #pragma unroll
    for (int m = 1; m < 64; m <<= 1) ss += __shfl_xor(ss, m, 64);
    __shared__ float red[4];
    if ((tid & 63) == 0) red[tid >> 6] = ss;
    __syncthreads();
    float tot = red[0] + red[1] + red[2] + red[3];
    float inv = rsqrtf(tot * (1.0f / 1024.0f) + RMS_EPS);
    f32x4 wt4 = *(const f32x4*)(w + tid * 4);
    bf16x4 hv;
    #pragma unroll
    for (int j = 0; j < 4; ++j) hv[j] = (bf16_t)(v[j] * inv * wt4[j]);
    ((bf16x4*)outh)[(size_t)blk * 256 + tid] = hv;
}

// Flash attention: block (qb,hh) handles q-chunk qb (32 rows), KB=64 keys/tile.
// 512 blocks, 2 waves. Q,K hi-only; V hi+lo; softcap (HW-exp tanh) + causal +
// online softmax fp32; P hi/lo via per-wave LDS; 3-term P.V. O hi-only.
__global__ __launch_bounds__(128, 2)
void flash_attn(const bf16_t* __restrict__ qkvh,
                const bf16_t* __restrict__ vTh, const bf16_t* __restrict__ vTl,
                bf16_t* __restrict__ oh)
{
    __shared__ __align__(16) bf16_t sQ[32*64], sK[64*64], sVh[64*64], sVl[64*64];
    __shared__ __align__(16) bf16_t sPh[32*64], sPl[32*64];

    const int q0 = blockIdx.x * 32;
    const int hh = blockIdx.y;
    const int tid = threadIdx.x, lane = tid & 63, w = tid >> 6;
    const int lr = lane & 15, lg = lane >> 4;

    #pragma unroll
    for (int ii = 0; ii < 2; ++ii) {
        int r0 = w * 16 + ii * 8;
        int r  = r0 + (lane >> 3);
        int i  = lane & 7;
        GLDS(qkvh + (size_t)(q0 + r) * 3072 + hh * 64 + ((i ^ (r & 7)) << 3),
             sQ + r0 * 64);
    }
    __syncthreads();

    bf16x8 qa[2];
    #pragma unroll
    for (int ks = 0; ks < 2; ++ks) {
        int r = w * 16 + lr;
        qa[ks] = *(const bf16x8*)((const char*)sQ + r * 128 +
                                  ((((ks << 2) | lg) ^ (r & 7)) << 4));
    }

    f32x4 o_acc[4];
    #pragma unroll
    for (int n = 0; n < 4; ++n) o_acc[n] = (f32x4){0.f, 0.f, 0.f, 0.f};
    float m_run[4] = {-1e30f, -1e30f, -1e30f, -1e30f};
    float l_run[4] = {0.f, 0.f, 0.f, 0.f};

    const int ntiles = ((q0 + 31) >> 6) + 1;
    for (int t = 0; t < ntiles; ++t) {
        const int kv0 = t * 64;
        #pragma unroll
        for (int ii = 0; ii < 4; ++ii) {
            int r0 = w * 32 + ii * 8;
            int r  = r0 + (lane >> 3);
            int i  = lane & 7;
            GLDS(qkvh + (size_t)(kv0 + r) * 3072 + 1024 + hh * 64 + ((i ^ (r & 7)) << 3),
                 sK + r0 * 64);
            GLDS(vTh + (size_t)(hh * 64 + r) * 1024 + kv0 + ((i ^ (r & 7)) << 3),
                 sVh + r0 * 64);
            GLDS(vTl + (size_t)(hh * 64 + r) * 1024 + kv0 + ((i ^ (r & 7)) << 3),
                 sVl + r0 * 64);
        }
        __syncthreads();

        f32x4 s_acc[4];
        #pragma unroll
        for (int n = 0; n < 4; ++n) s_acc[n] = (f32x4){0.f, 0.f, 0.f, 0.f};
        #pragma unroll
        for (int ks = 0; ks < 2; ++ks)
            #pragma unroll
            for (int n = 0; n < 4; ++n) {
                int r = n * 16 + lr;
                bf16x8 kb = *(const bf16x8*)((const char*)sK + r * 128 +
                                             ((((ks << 2) | lg) ^ (r & 7)) << 4));
                s_acc[n] = mfma16(qa[ks], kb, s_acc[n]);
            }

        #pragma unroll
        for (int j = 0; j < 4; ++j) {
            int qr = q0 + w * 16 + lg * 4 + j;
            float p[4];
            float mx = -1e30f;
            #pragma unroll
            for (int n = 0; n < 4; ++n) {
                float sx = s_acc[n][j] * (0.125f * 0.02f);       // x = s*scale/50
                float v = 50.f * (1.f - 2.f / (1.f + __expf(2.f * sx)));
                int key = kv0 + n * 16 + lr;
                if (key > qr) v = -1e30f;
                p[n] = v;
                mx = fmaxf(mx, v);
            }
            #pragma unroll
            for (int m = 1; m < 16; m <<= 1) mx = fmaxf(mx, __shfl_xor(mx, m, 64));
            float mn = fmaxf(m_run[j], mx);
            float ef = __expf(m_run[j] - mn);
            m_run[j] = mn;
            float rs = 0.f;
            #pragma unroll
            for (int n = 0; n < 4; ++n) {
                float e = __expf(p[n] - mn);
                p[n] = e;
                rs += e;
            }
            #pragma unroll
            for (int m = 1; m < 16; m <<= 1) rs += __shfl_xor(rs, m, 64);
            l_run[j] = l_run[j] * ef + rs;
            #pragma unroll
            for (int n = 0; n < 4; ++n) o_acc[n][j] *= ef;
            int r = w * 16 + lg * 4 + j;
            #pragma unroll
            for (int n = 0; n < 4; ++n) {
                int c = n * 16 + lr;
                int byo = r * 128 + ((((c >> 3) ^ (r & 7)) << 4)) + ((c & 7) << 1);
                bf16_t hb = (bf16_t)p[n];
                *(bf16_t*)((char*)sPh + byo) = hb;
                *(bf16_t*)((char*)sPl + byo) = (bf16_t)(p[n] - (float)hb);
            }
        }

        #pragma unroll
        for (int ks = 0; ks < 2; ++ks) {
            int pr = w * 16 + lr;
            int pby = pr * 128 + ((((ks << 2) | lg) ^ (pr & 7)) << 4);
            bf16x8 pa  = *(const bf16x8*)((const char*)sPh + pby);
            bf16x8 pl_ = *(const bf16x8*)((const char*)sPl + pby);
            #pragma unroll
            for (int n = 0; n < 4; ++n) {
                int vr = n * 16 + lr;
                int vby = vr * 128 + ((((ks << 2) | lg) ^ (vr & 7)) << 4);
                bf16x8 vhf = *(const bf16x8*)((const char*)sVh + vby);
                bf16x8 vlf = *(const bf16x8*)((const char*)sVl + vby);
                o_acc[n] = mfma16(pa,  vhf, o_acc[n]);
                o_acc[n] = mfma16(pl_, vhf, o_acc[n]);
                o_acc[n] = mfma16(pa,  vlf, o_acc[n]);
            }
        }
        __syncthreads();
    }

    #pragma unroll
    for (int j = 0; j < 4; ++j) {
        float inv = 1.0f / l_run[j];
        int qr = q0 + w * 16 + lg * 4 + j;
        #pragma unroll
        for (int n = 0; n < 4; ++n) {
            size_t off = (size_t)qr * 1024 + hh * 64 + n * 16 + lr;
            oh[off] = (bf16_t)(o_acc[n][j] * inv);
        }
    }
}

__global__ __launch_bounds__(256)
void rmsnorm_split(const float* __restrict__ in, const float* __restrict__ w,
                   bf16_t* __restrict__ outh)
{
    int row = blockIdx.x, tid = threadIdx.x;
    f32x4 v = *(const f32x4*)(in + (size_t)row * 1024 + tid * 4);
    float ss = v[0]*v[0] + v[1]*v[1] + v[2]*v[2] + v[3]*v[3];
    #pragma unroll
    for (int m = 1; m < 64; m <<= 1) ss += __shfl_xor(ss, m, 64);
    __shared__ float red[4];
    if ((tid & 63) == 0) red[tid >> 6] = ss;
    __syncthreads();
    float tot = red[0] + red[1] + red[2] + red[3];
    float inv = rsqrtf(tot * (1.0f / 1024.0f) + RMS_EPS);
    f32x4 wt4 = *(const f32x4*)(w + tid * 4);
    bf16x4 hv;
    #pragma unroll
    for (int j = 0; j < 4; ++j) hv[j] = (bf16_t)(v[j] * inv * wt4[j]);
    ((bf16x4*)outh)[(size_t)row * 256 + tid] = hv;
}

extern "C" void kernel_launch(void* const* d_in, const int* in_sizes, int n_in,
                              void* d_out, int out_size, void* d_ws, size_t ws_size,
                              hipStream_t stream)
{
    (void)in_sizes; (void)n_in; (void)out_size; (void)ws_size;
    const int*   x_ids = (const int*)  d_in[0];
    const float* embed = (const float*)d_in[1];
    const float* ln1   = (const float*)d_in[2];
    const float* Wq    = (const float*)d_in[3];
    const float* Wk    = (const float*)d_in[4];
    const float* Wv    = (const float*)d_in[5];
    const float* Wo    = (const float*)d_in[6];
    const float* qn    = (const float*)d_in[7];
    const float* kn    = (const float*)d_in[8];
    const float* ln2   = (const float*)d_in[9];
    const float* Wg    = (const float*)d_in[10];
    const float* Wu    = (const float*)d_in[11];
    const float* Wd    = (const float*)d_in[12];
    const float* lnout = (const float*)d_in[13];
    float* out = (float*)d_out;

    char* ws = (char*)d_ws;
    const size_t MB = 1 << 20;
    float*  h    = (float*) (ws +   0 * MB);  // 4 MB fp32 residual
    bf16_t* hnh  = (bf16_t*)(ws +   4 * MB);
    bf16_t* qkvh = (bf16_t*)(ws +   8 * MB);  // 6 MB [1024][3072] (q,k cols)
    bf16_t* vTh  = (bf16_t*)(ws +  20 * MB);
    bf16_t* vTl  = (bf16_t*)(ws +  22 * MB);
    bf16_t* oh   = (bf16_t*)(ws +  24 * MB);
    // double-buffered packed weight sets (layer l uses set l&1):
    bf16_t* wA[2]  = {(bf16_t*)(ws +  28 * MB), (bf16_t*)(ws +  84 * MB)};
    bf16_t* wGU[2] = {(bf16_t*)(ws +  36 * MB), (bf16_t*)(ws +  92 * MB)};
    bf16_t* wD[2]  = {(bf16_t*)(ws +  52 * MB), (bf16_t*)(ws + 108 * MB)};
    bf16_t* silh = (bf16_t*)(ws +  60 * MB);  //  8 MB [1024][4096]
    float*  wdp  = (float*) (ws +  68 * MB);  // 16 MB split-K partials
    bf16_t* eh   = (bf16_t*)(ws + 116 * MB);  // 62.5 MB (high-water ~179 MB)

    const long long M1 = 1024 * 1024;
    const int ETOT = 8192000;                 // embed f32x4 units
    const int ESL  = 1365334;                 // per-layer conversion slice

    // gather+rms (1024) | layer-0 weight pack (4096)
    gather_rms_wsplit<<<5120, 256, 0, stream>>>(
        x_ids, embed, ln1, h, hnh,
        Wq, Wk, Wv, Wo, Wg, Wu, Wd, wA[0], wGU[0], wD[0]);

    for (int l = 0; l < 6; ++l) {
        const int s = l & 1, nx = s ^ 1;

        // fused QKV + qk-RMSnorm + RoPE + V-transpose (1-plane, 3-buffer)
        gemm_bf16<64,128,2,2,1,EP_QKV,4,3><<<dim3(16,24),256,0,stream>>>(
            hnh, nullptr, wA[s], (float*)vTl, qkvh, vTh, 1024, 1024, 1024, 3072, 0,
            qn + l * 64, kn + l * 64);

        // fused scores+softcap+mask+softmax+PV; O hi-only
        flash_attn<<<dim3(32,16), 128, 0, stream>>>(qkvh, vTh, vTl, oh);

        // Wo residual (1-plane, 3-buffer, 64^2 tiles)
        gemm_bf16<64,64,2,2,1,EP_RESID,4,3><<<dim3(16,16),256,0,stream>>>(
            oh, nullptr, wA[s] + 3 * M1, h, nullptr, nullptr, 1024, 1024, 1024, 1024, 0,
            nullptr, nullptr);

        rmsnorm_split<<<1024, 256, 0, stream>>>(h, ln2 + l * 1024, hnh);

        // fused gate+up+silu GEMM + next-layer weight pack (z=1)
        //                         + embed->bf16 slice l (z=2)
        int es = l * ESL, ee = (l + 1) * ESL < ETOT ? (l + 1) * ESL : ETOT;
        gemm_gu_pack<<<dim3(8,32,3), 512, 0, stream>>>(
            hnh, wGU[s], silh,
            l < 5 ? Wq + (size_t)(l+1) * M1 : nullptr,
            l < 5 ? Wk + (size_t)(l+1) * M1 : nullptr,
            l < 5 ? Wv + (size_t)(l+1) * M1 : nullptr,
            l < 5 ? Wo + (size_t)(l+1) * M1 : nullptr,
            l < 5 ? Wg + (size_t)(l+1) * 4 * M1 : nullptr,
            l < 5 ? Wu + (size_t)(l+1) * 4 * M1 : nullptr,
            l < 5 ? Wd + (size_t)(l+1) * 4 * M1 : nullptr,
            wA[nx], wGU[nx], wD[nx],
            embed, eh, es, ee);

        // down-proj: split-K x4 (1-plane, 3-buffer) -> partials
        gemm_bf16<128,128,2,2,1,EP_STORE,4,3><<<dim3(8,8,4),256,0,stream>>>(
            silh, nullptr, wD[s], wdp, nullptr, nullptr, 1024, 4096, 4096, 1024, M1,
            nullptr, nullptr);

        // reduce partials into h + next pre-norm (ln1[l+1], or ln_out last)
        const float* wnext = (l < 5) ? (ln1 + (l + 1) * 1024) : lnout;
        reduce_rms<<<1024, 256, 0, stream>>>(wdp, h, wnext, hnh);
    }

    // logits: phase-split deep pipeline, 256x256, 8 waves, 128 KB LDS
    gemm_logits8<<<dim3(4,125), 512, 0, stream>>>(hnh, eh, out);
}

// Round 22
// 1039.704 us; speedup vs baseline: 1.1362x; 1.0528x over previous
//
#include <hip/hip_runtime.h>
#include <math.h>
#include <type_traits>

typedef __bf16 bf16_t;
typedef bf16_t bf16x4 __attribute__((ext_vector_type(4)));
typedef bf16_t bf16x8 __attribute__((ext_vector_type(8)));
typedef float  f32x4  __attribute__((ext_vector_type(4)));

#define RMS_EPS 1e-6f

enum { EP_STORE = 0, EP_RESID = 1, EP_SPLIT = 2, EP_SILU = 3, EP_QKV = 4 };

template<int V> using IC = std::integral_constant<int, V>;

static __device__ __forceinline__ f32x4 mfma16(bf16x8 a, bf16x8 b, f32x4 c) {
    return __builtin_amdgcn_mfma_f32_16x16x32_bf16(a, b, c, 0, 0, 0);
}

#define GLDS(gp, lp) __builtin_amdgcn_global_load_lds( \
    (const __attribute__((address_space(1))) void*)(gp), \
    (__attribute__((address_space(3))) void*)(lp), 16, 0, 0)

// counted vector-memory wait (T4): leave N newest loads in flight.
template<int N> static __device__ __forceinline__ void vmwait() {
    if constexpr (N == 0)       asm volatile("s_waitcnt vmcnt(0)" ::: "memory");
    else if constexpr (N == 2)  asm volatile("s_waitcnt vmcnt(2)" ::: "memory");
    else if constexpr (N == 3)  asm volatile("s_waitcnt vmcnt(3)" ::: "memory");
    else if constexpr (N == 4)  asm volatile("s_waitcnt vmcnt(4)" ::: "memory");
    else if constexpr (N == 6)  asm volatile("s_waitcnt vmcnt(6)" ::: "memory");
    else if constexpr (N == 8)  asm volatile("s_waitcnt vmcnt(8)" ::: "memory");
    else if constexpr (N == 12) asm volatile("s_waitcnt vmcnt(12)" ::: "memory");
    __builtin_amdgcn_sched_barrier(0);
}
static __device__ __forceinline__ void bar() { __builtin_amdgcn_s_barrier(); }
static __device__ __forceinline__ void lgkm0() {
    asm volatile("s_waitcnt lgkmcnt(0)" ::: "memory");
    __builtin_amdgcn_sched_barrier(0);   // rule #18: fence MFMA hoisting
}

// C[M,N] = A[M,K]*B[N,K]^T.
// PLANES==2: A split hi/lo, B hi-only (2 MFMAs).  PLANES==1: pure bf16.
// WR x WC wave grid. Counted-vmcnt pipelined K-loop, DEPTH buffers.
// NO setprio here: T5 is measured-negative on barrier-lockstep GEMMs (m190).
// EP_QKV : fused qk-RMSnorm + RoPE epilogue (wave's WN=64 col span = one head);
//          rope cos/sin from precomputed tables (bitwise == on-the-fly calc);
//          q/k -> Ch (cols [0,2048)); v written TRANSPOSED: hi -> Cl (= vTh),
//          lo -> (bf16_t*)Cf (= vTl). Per-thread 8-byte contiguous runs.
//          Rope quirk: angle = head_index * freq (reference's cos[:n], n=H).
// blockIdx.z = K-chunk for split-K.
template<int BM, int BN, int WR, int WC, int PLANES, int EPIL, int MINW, int DEPTH>
__global__ __launch_bounds__(WR * WC * 64, MINW)
void gemm_bf16(const bf16_t* __restrict__ Ah, const bf16_t* __restrict__ Al,
               const bf16_t* __restrict__ Bh,
               float* __restrict__ Cf, bf16_t* __restrict__ Ch, bf16_t* __restrict__ Cl,
               int K, int lda, int ldb, int ldc, long long sC,
               const float* __restrict__ qnw, const float* __restrict__ knw,
               const float* __restrict__ ctab, const float* __restrict__ stab)
{
    constexpr int ASZ = BM * 32, BSZ = BN * 32;
    constexpr int NW = WR * WC;
    constexpr int NLD = (BM / 16 * (PLANES >= 2 ? 2 : 1) + BN / 16) / NW;
    __shared__ __align__(16) bf16_t sAh[DEPTH][ASZ], sBh[DEPTH][BSZ];
    __shared__ __align__(16) bf16_t sAl[PLANES >= 2 ? DEPTH : 1][PLANES >= 2 ? ASZ : 8];

    const int gx = gridDim.x;
    int id = blockIdx.x + gx * blockIdx.y;
    if (gridDim.z == 1) {  // bijective XCD swizzle (m204)
        int nwg = gx * gridDim.y;
        int q = nwg >> 3, r = nwg & 7;
        int xcd = id & 7, ix = id >> 3;
        id = (xcd < r ? xcd * (q + 1) : r * (q + 1) + (xcd - r) * q) + ix;
    }
    const int bm = id % gx, bn = id / gx;
    const int row0 = bm * BM, col0 = bn * BN;

    const size_t kofs = (size_t)blockIdx.z * K;
    Ah += kofs;  Bh += kofs;
    if constexpr (PLANES >= 2) Al += kofs;

    const int tid = threadIdx.x, lane = tid & 63, wave = tid >> 6;
    const int lr = lane & 15, lg = lane >> 4;
    constexpr int WM = BM / WR, WN = BN / WC, MF = WM / 16, NF = WN / 16;
    const int wr = wave / WC, wc = wave % WC;

    f32x4 acc[MF][NF];
    #pragma unroll
    for (int m = 0; m < MF; ++m)
        #pragma unroll
        for (int n = 0; n < NF; ++n) acc[m][n] = (f32x4){0.f, 0.f, 0.f, 0.f};

    auto stage = [&](int k0, int p) {
        #pragma unroll
        for (int i = wave; i < BM / 16; i += NW) {
            int s = i * 64 + lane, rr = s >> 2, c = s & 3;
            size_t go = (size_t)(row0 + rr) * lda + k0 + ((c ^ ((rr >> 1) & 3)) << 3);
            GLDS(Ah + go, &sAh[p][i * 512]);
            if constexpr (PLANES >= 2) GLDS(Al + go, &sAl[p][i * 512]);
        }
        #pragma unroll
        for (int i = wave; i < BN / 16; i += NW) {
            int s = i * 64 + lane, rr = s >> 2, c = s & 3;
            size_t go = (size_t)(col0 + rr) * ldb + k0 + ((c ^ ((rr >> 1) & 3)) << 3);
            GLDS(Bh + go, &sBh[p][i * 512]);
        }
    };

    auto compute = [&](int p) {
        bf16x8 ahf[MF], alf[MF], bhf[NF];
        #pragma unroll
        for (int m = 0; m < MF; ++m) {
            int rr = wr * WM + m * 16 + lr;
            int by = rr * 64 + ((lg ^ ((rr >> 1) & 3)) << 4);
            ahf[m] = *(const bf16x8*)((const char*)&sAh[p][0] + by);
            if constexpr (PLANES >= 2)
                alf[m] = *(const bf16x8*)((const char*)&sAl[p][0] + by);
        }
        #pragma unroll
        for (int n = 0; n < NF; ++n) {
            int rr = wc * WN + n * 16 + lr;
            int by = rr * 64 + ((lg ^ ((rr >> 1) & 3)) << 4);
            bhf[n] = *(const bf16x8*)((const char*)&sBh[p][0] + by);
        }
        #pragma unroll
        for (int m = 0; m < MF; ++m)
            #pragma unroll
            for (int n = 0; n < NF; ++n) {
                acc[m][n] = mfma16(ahf[m], bhf[n], acc[m][n]);
                if constexpr (PLANES >= 2)
                    acc[m][n] = mfma16(alf[m], bhf[n], acc[m][n]);
            }
    };

    if constexpr (DEPTH == 3) {
        const int NC = K >> 5;          // 32-wide chunks
        stage(0, 0);
        stage(32, 1);
        for (int j = 0; j + 2 < NC; ++j) {
            stage(32 * (j + 2), (j + 2) % 3);
            vmwait<2 * NLD>(); bar();   // chunk j landed; j+1, j+2 in flight
            compute(j % 3);
            bar();                      // protect buf before next stage overwrites
        }
        vmwait<NLD>(); bar();
        compute((K >> 5) >= 2 ? ((K >> 5) - 2) % 3 : 0);
        vmwait<0>(); bar();
        compute(((K >> 5) - 1) % 3);
    } else {
        stage(0, 0);
        int k0 = 32;
        for (; k0 + 32 < K; k0 += 64) {
            stage(k0, 1);
            vmwait<NLD>(); bar();
            compute(0);
            bar();
            stage(k0 + 32, 0);
            vmwait<NLD>(); bar();
            compute(1);
            bar();
        }
        stage(k0, 1);
        vmwait<NLD>(); bar();
        compute(0);
        bar();
        vmwait<0>(); bar();
        compute(1);
    }

    if constexpr (EPIL == EP_QKV) {
        // wave's col span = [colbase, colbase+64) = one head-dim group
        const int colbase = col0 + wc * WN;          // multiple of 64
        const int typ = colbase >> 10;               // 0=q, 1=k, 2=v
        if (typ < 2) {
            const float* nw = (typ == 0) ? qnw : knw;
            const int hh = (colbase - typ * 1024) >> 6;  // head idx
            #pragma unroll
            for (int m = 0; m < MF; ++m)
                #pragma unroll
                for (int r = 0; r < 4; ++r) {
                    int grow = row0 + wr * WM + m * 16 + lg * 4 + r;
                    float ss = 0.f;
                    #pragma unroll
                    for (int n = 0; n < NF; ++n) {
                        float v = acc[m][n][r];
                        ss += v * v;
                    }
                    ss += __shfl_xor(ss, 1, 64);
                    ss += __shfl_xor(ss, 2, 64);
                    ss += __shfl_xor(ss, 4, 64);
                    ss += __shfl_xor(ss, 8, 64);
                    float inv = rsqrtf(ss * (1.0f / 64.0f) + RMS_EPS);
                    #pragma unroll
                    for (int n = 0; n < NF; ++n) {
                        int i = n * 16 + lr;
                        float x = acc[m][n][r] * inv * nw[i];
                        float p = __shfl_xor(x, 1, 64);
                        float cs = ctab[(hh << 5) + (i >> 1)];
                        float sn = stab[(hh << 5) + (i >> 1)];
                        float o = (lr & 1) ? (p * sn + x * cs) : (x * cs - p * sn);
                        Ch[(size_t)grow * ldc + colbase + i] = (bf16_t)o;
                    }
                }
        } else {
            // v: write TRANSPOSED planes (vT[vc][grow..grow+3], 8B runs)
            bf16_t* vTh_ = Cl;
            bf16_t* vTl_ = (bf16_t*)Cf;
            const int vcb = colbase - 2048;
            #pragma unroll
            for (int m = 0; m < MF; ++m)
                #pragma unroll
                for (int n = 0; n < NF; ++n) {
                    int vc = vcb + n * 16 + lr;
                    int grow0 = row0 + wr * WM + m * 16 + lg * 4;
                    bf16x4 hv, lv;
                    #pragma unroll
                    for (int r = 0; r < 4; ++r) {
                        float v = acc[m][n][r];
                        bf16_t hb = (bf16_t)v;
                        hv[r] = hb;
                        lv[r] = (bf16_t)(v - (float)hb);
                    }
                    *(bf16x4*)&vTh_[(size_t)vc * 1024 + grow0] = hv;
                    *(bf16x4*)&vTl_[(size_t)vc * 1024 + grow0] = lv;
                }
        }
        return;
    }

    #pragma unroll
    for (int m = 0; m < MF; ++m)
        #pragma unroll
        for (int n = 0; n < NF; ++n)
            #pragma unroll
            for (int r = 0; r < 4; ++r) {
                int grow = row0 + wr * WM + m * 16 + lg * 4 + r;
                int gcol = col0 + wc * WN + n * 16 + lr;
                float v = acc[m][n][r];
                size_t off = (size_t)blockIdx.z * sC + (size_t)grow * ldc + gcol;
                if constexpr (EPIL == EP_STORE) {
                    Cf[off] = v;
                } else if constexpr (EPIL == EP_RESID) {
                    Cf[off] += v;
                } else if constexpr (EPIL == EP_SPLIT) {
                    bf16_t hb = (bf16_t)v;
                    Ch[off] = hb;
                    Cl[off] = (bf16_t)(v - (float)hb);
                }
            }
}

// GU GEMM (sil = silu(g)*u, 128x256 tile, 8 waves, DEPTH-3 counted-vmcnt)
// PLUS z==1: next-layer weight pack (disjoint dst buffer set)
// PLUS z==2: embed->bf16 conversion slice [es, ee) in f32x4 units.
__global__ __launch_bounds__(512, 4)
void gemm_gu_pack(const bf16_t* __restrict__ Ah, const bf16_t* __restrict__ Bh,
                  bf16_t* __restrict__ Ch,
                  const float* wq, const float* wk, const float* wv,
                  const float* wo, const float* wg, const float* wu,
                  const float* wd, bf16_t* wAd, bf16_t* wGUd, bf16_t* wdd,
                  const float* __restrict__ embed, bf16_t* __restrict__ eh,
                  int es, int ee)
{
    constexpr int lda = 1024, ldb = 1024, ldc = 4096, K = 1024;
    const int tid = threadIdx.x;

    if (blockIdx.z == 2) {     // embed->bf16 conversion slice
        int base = ((int)blockIdx.y * 8 + (int)blockIdx.x) * 512 + tid;
        for (int j = 0; j < 11; ++j) {
            int u = es + j * 131072 + base;
            if (u < ee) {
                f32x4 v = ((const f32x4*)embed)[u];
                bf16x4 hv;
                #pragma unroll
                for (int q2 = 0; q2 < 4; ++q2) hv[q2] = (bf16_t)v[q2];
                ((bf16x4*)eh)[u] = hv;
            }
        }
        return;
    }

    if (blockIdx.z == 1) {     // pack next layer's weights -> other buffer set
        if (!wq) return;
        int base = ((int)blockIdx.y * 8 + (int)blockIdx.x) * 512 + tid;
        #pragma unroll 4
        for (int j = 0; j < 32; ++j) {
            int v = j * 131072 + base;      // 0..4194303 f32x4 units
            f32x4 val;
            bf16_t* dst;
            size_t doff;
            if (v < (1 << 20)) {            // wq|wk|wv|wo -> wAd [4096x1024]
                int b = v >> 8, col = v & 255;
                const float* src = b < 1024 ? wq : b < 2048 ? wk : b < 3072 ? wv : wo;
                val = ((const f32x4*)src)[(size_t)(b & 1023) * 256 + col];
                dst = wAd; doff = (size_t)b * 256 + col;
            } else if (v < 3 * (1 << 20)) { // wg|wu INTERLEAVED -> wGUd
                int u = v - (1 << 20);
                int bb = u >> 8, col = u & 255;
                int row = bb < 4096 ? 2 * bb : 2 * (bb - 4096) + 1;
                const float* src = bb < 4096 ? wg : wu;
                val = ((const f32x4*)src)[(size_t)(bb & 4095) * 256 + col];
                dst = wGUd; doff = (size_t)row * 256 + col;
            } else {                        // wd -> wdd
                int u = v - 3 * (1 << 20);
                val = ((const f32x4*)wd)[u];
                dst = wdd; doff = (size_t)u;
            }
            bf16x4 hv;
            #pragma unroll
            for (int q2 = 0; q2 < 4; ++q2) hv[q2] = (bf16_t)val[q2];
            ((bf16x4*)dst)[doff] = hv;
        }
        return;
    }

    __shared__ __align__(16) bf16_t sA[3][128 * 32], sB[3][256 * 32];

    int id = blockIdx.x + 8 * blockIdx.y;
    {   // bijective XCD swizzle (nwg = 256)
        int q = 256 >> 3;
        int xcd = id & 7, ix = id >> 3;
        id = xcd * q + ix;
    }
    const int bm = id % 8, bn = id / 8;
    const int row0 = bm * 128, col0 = bn * 256;

    const int lane = tid & 63, wave = tid >> 6;
    const int lr = lane & 15, lg = lane >> 4;
    const int wr = wave >> 2, wc = wave & 3;   // 2x4 waves; WM=WN=64

    f32x4 acc[4][4];
    #pragma unroll
    for (int m = 0; m < 4; ++m)
        #pragma unroll
        for (int n = 0; n < 4; ++n) acc[m][n] = (f32x4){0.f, 0.f, 0.f, 0.f};

    auto stage = [&](int k0, int p) {
        {
            int i = wave;
            int s = i * 64 + lane, rr = s >> 2, c = s & 3;
            size_t go = (size_t)(row0 + rr) * lda + k0 + ((c ^ ((rr >> 1) & 3)) << 3);
            GLDS(Ah + go, &sA[p][i * 512]);
        }
        #pragma unroll
        for (int i = wave; i < 16; i += 8) {
            int s = i * 64 + lane, rr = s >> 2, c = s & 3;
            size_t go = (size_t)(col0 + rr) * ldb + k0 + ((c ^ ((rr >> 1) & 3)) << 3);
            GLDS(Bh + go, &sB[p][i * 512]);
        }
    };

    auto compute = [&](int p) {
        bf16x8 af[4], bf4[4];
        #pragma unroll
        for (int m = 0; m < 4; ++m) {
            int rr = wr * 64 + m * 16 + lr;
            int by = rr * 64 + ((lg ^ ((rr >> 1) & 3)) << 4);
            af[m] = *(const bf16x8*)((const char*)&sA[p][0] + by);
        }
        #pragma unroll
        for (int n = 0; n < 4; ++n) {
            int rr = wc * 64 + n * 16 + lr;
            int by = rr * 64 + ((lg ^ ((rr >> 1) & 3)) << 4);
            bf4[n] = *(const bf16x8*)((const char*)&sB[p][0] + by);
        }
        #pragma unroll
        for (int m = 0; m < 4; ++m)
            #pragma unroll
            for (int n = 0; n < 4; ++n)
                acc[m][n] = mfma16(af[m], bf4[n], acc[m][n]);
    };

    const int NC = K >> 5;   // 32 chunks; NLD = 3
    stage(0, 0);
    stage(32, 1);
    for (int j = 0; j + 2 < NC; ++j) {
        stage(32 * (j + 2), (j + 2) % 3);
        vmwait<6>(); bar();
        compute(j % 3);
        bar();
    }
    vmwait<3>(); bar();
    compute((NC - 2) % 3);
    vmwait<0>(); bar();
    compute((NC - 1) % 3);

    // silu(g)*u epilogue: adjacent lanes hold the (g,u) pair
    #pragma unroll
    for (int m = 0; m < 4; ++m)
        #pragma unroll
        for (int n = 0; n < 4; ++n)
            #pragma unroll
            for (int r = 0; r < 4; ++r) {
                int grow = row0 + wr * 64 + m * 16 + lg * 4 + r;
                int gcol = col0 + wc * 64 + n * 16 + lr;
                float v = acc[m][n][r];
                float pv = __shfl_xor(v, 1, 64);
                if (!(lr & 1)) {
                    float s = (v / (1.0f + __expf(-v))) * pv;
                    Ch[(size_t)grow * ldc + (gcol >> 1)] = (bf16_t)s;
                }
            }
}

// Logits GEMM, phase-split deep pipeline (T3+T4+T5): 256x256 tile, 8 waves,
// K-tile=64 = 2 ks-chunks of 32 in the proven [256][32] XOR-swizzled layout.
// LDS 128 KB double-buffered; vmcnt(8) counted waits (never drains mid-loop).
__global__ __launch_bounds__(512, 2)
void gemm_logits8(const bf16_t* __restrict__ Ah, const bf16_t* __restrict__ Bh,
                  float* __restrict__ Cf)
{
    constexpr int lda = 1024, ldb = 1024, ldc = 32000;
    constexpr int NT = 16;   // K-tiles of 64
    __shared__ __align__(16) bf16_t sA[2][2][256 * 32];
    __shared__ __align__(16) bf16_t sB[2][2][256 * 32];

    const int gx = gridDim.x;
    int id = blockIdx.x + gx * blockIdx.y;
    {   // bijective XCD swizzle
        int nwg = gx * gridDim.y;
        int q = nwg >> 3, r = nwg & 7;
        int xcd = id & 7, ix = id >> 3;
        id = (xcd < r ? xcd * (q + 1) : r * (q + 1) + (xcd - r) * q) + ix;
    }
    const int bm = id % gx, bn = id / gx;
    const int row0 = bm * 256, col0 = bn * 256;

    const int tid = threadIdx.x, lane = tid & 63, wave = tid >> 6;
    const int lr = lane & 15, lg = lane >> 4;
    const int wr = wave >> 2, wc = wave & 3;   // 2x4 wave grid

    f32x4 acc[8][4];
    #pragma unroll
    for (int m = 0; m < 8; ++m)
        #pragma unroll
        for (int n = 0; n < 4; ++n) acc[m][n] = (f32x4){0.f, 0.f, 0.f, 0.f};

    auto stageA = [&](int chunk, int buf, int ks) {
        int k0 = chunk * 32;
        #pragma unroll
        for (int i = wave; i < 16; i += 8) {
            int s = i * 64 + lane, rr = s >> 2, c = s & 3;
            size_t go = (size_t)(row0 + rr) * lda + k0 + ((c ^ ((rr >> 1) & 3)) << 3);
            GLDS(Ah + go, &sA[buf][ks][i * 512]);
        }
    };
    auto stageB = [&](int chunk, int buf, int ks) {
        int k0 = chunk * 32;
        #pragma unroll
        for (int i = wave; i < 16; i += 8) {
            int s = i * 64 + lane, rr = s >> 2, c = s & 3;
            size_t go = (size_t)(col0 + rr) * ldb + k0 + ((c ^ ((rr >> 1) & 3)) << 3);
            GLDS(Bh + go, &sB[buf][ks][i * 512]);
        }
    };

    auto phase = [&](int t, auto ksc) {
        constexpr int ks = decltype(ksc)::value;
        const int buf = t & 1;
        bf16x8 af[8], bf4[4];
        #pragma unroll
        for (int m = 0; m < 8; ++m) {
            int rr = wr * 128 + m * 16 + lr;
            int by = rr * 64 + ((lg ^ ((rr >> 1) & 3)) << 4);
            af[m] = *(const bf16x8*)((const char*)&sA[buf][ks][0] + by);
        }
        #pragma unroll
        for (int n = 0; n < 4; ++n) {
            int rr = wc * 64 + n * 16 + lr;
            int by = rr * 64 + ((lg ^ ((rr >> 1) & 3)) << 4);
            bf4[n] = *(const bf16x8*)((const char*)&sB[buf][ks][0] + by);
        }
        if constexpr (ks == 0) {
            if (t + 1 < NT) {
                stageA(2 * (t + 1) + 1, (t + 1) & 1, 1);
                stageB(2 * (t + 1) + 1, (t + 1) & 1, 1);
                vmwait<8>();
            } else {
                vmwait<0>();
            }
        } else {
            if (t + 2 < NT) {
                stageA(2 * (t + 2), t & 1, 0);
                stageB(2 * (t + 2), t & 1, 0);
                vmwait<8>();
            } else if (t + 1 < NT) {
                vmwait<4>();
            } else {
                vmwait<0>();
            }
        }
        bar();
        lgkm0();
        __builtin_amdgcn_s_setprio(1);
        #pragma unroll
        for (int m = 0; m < 8; ++m)
            #pragma unroll
            for (int n = 0; n < 4; ++n)
                acc[m][n] = mfma16(af[m], bf4[n], acc[m][n]);
        __builtin_amdgcn_s_setprio(0);
        bar();
    };

    stageA(0, 0, 0); stageB(0, 0, 0);
    stageA(1, 0, 1); stageB(1, 0, 1);
    stageA(2, 1, 0); stageB(2, 1, 0);
    vmwait<8>(); bar();

    for (int t = 0; t < NT; ++t) {
        phase(t, IC<0>{});
        phase(t, IC<1>{});
    }

    #pragma unroll
    for (int m = 0; m < 8; ++m)
        #pragma unroll
        for (int n = 0; n < 4; ++n)
            #pragma unroll
            for (int r = 0; r < 4; ++r) {
                int grow = row0 + wr * 128 + m * 16 + lg * 4 + r;
                int gcol = col0 + wc * 64 + n * 16 + lr;
                Cf[(size_t)grow * ldc + gcol] = acc[m][n][r];
            }
}

// weight-pack body: b2 in [0,4096); handles 4 chunks of 1024 f32 each.
static __device__ __forceinline__ void wsplit_body(
    int b2, int tid,
    const float* wq, const float* wk, const float* wv, const float* wo,
    const float* wg, const float* wu, const float* wd,
    bf16_t* wAh, bf16_t* wGUh, bf16_t* wdh)
{
    #pragma unroll
    for (int k = 0; k < 4; ++k) {
        int b = b2 * 4 + k;
        const float* src;
        bf16_t* dst;
        size_t so, doff;
        if (b < 4096) {
            src = b < 1024 ? wq : b < 2048 ? wk : b < 3072 ? wv : wo;
            so = (size_t)(b & 1023) * 256 + tid;
            doff = (size_t)b * 256 + tid;
            dst = wAh;
        } else if (b < 12288) {
            int bb = b - 4096;
            int row = bb < 4096 ? 2 * bb : 2 * (bb - 4096) + 1;
            src = bb < 4096 ? wg : wu;
            so = (size_t)(bb & 4095) * 256 + tid;
            doff = (size_t)row * 256 + tid;
            dst = wGUh;
        } else {
            src = wd;
            so = (size_t)(b - 12288) * 256 + tid;
            doff = so;
            dst = wdh;
        }
        f32x4 v = ((const f32x4*)src)[so];
        bf16x4 hv;
        #pragma unroll
        for (int j = 0; j < 4; ++j) hv[j] = (bf16_t)v[j];
        ((bf16x4*)dst)[doff] = hv;
    }
}

// blocks 0-1023: h += 4 split-K partials then RMS-norm -> hi plane.
__global__ __launch_bounds__(256)
void reduce_rms(const float* __restrict__ p, float* __restrict__ h,
                const float* __restrict__ w, bf16_t* __restrict__ outh)
{
    int blk = blockIdx.x, tid = threadIdx.x;
    size_t i = (size_t)blk * 256 + tid;
    const size_t S = (1024 * 1024) / 4;
    f32x4 a = ((const f32x4*)p)[i];
    f32x4 b = ((const f32x4*)p)[i + S];
    f32x4 c = ((const f32x4*)p)[i + 2 * S];
    f32x4 d = ((const f32x4*)p)[i + 3 * S];
    f32x4 hv = ((const f32x4*)h)[i];
    #pragma unroll
    for (int j = 0; j < 4; ++j) hv[j] += (a[j] + b[j]) + (c[j] + d[j]);
    ((f32x4*)h)[i] = hv;

    float ss = hv[0]*hv[0] + hv[1]*hv[1] + hv[2]*hv[2] + hv[3]*hv[3];
    #pragma unroll
    for (int m = 1; m < 64; m <<= 1) ss += __shfl_xor(ss, m, 64);
    __shared__ float red[4];
    if ((tid & 63) == 0) red[tid >> 6] = ss;
    __syncthreads();
    float tot = red[0] + red[1] + red[2] + red[3];
    float inv = rsqrtf(tot * (1.0f / 1024.0f) + RMS_EPS);
    f32x4 wt4 = *(const f32x4*)(w + tid * 4);
    bf16x4 hv4;
    #pragma unroll
    for (int j = 0; j < 4; ++j) hv4[j] = (bf16_t)(hv[j] * inv * wt4[j]);
    ((bf16x4*)outh)[i] = hv4;
}

// blocks 0-1023: gather embed row, write fp32 h, RMS-norm -> hi.
// blocks 1024-5119: pack layer-0 weights (set 0).
// block 5120: precompute rope cos/sin tables (bitwise == epilogue's old calc).
__global__ __launch_bounds__(256)
void gather_rms_wsplit(const int* __restrict__ ids, const float* __restrict__ embed,
                       const float* __restrict__ w, float* __restrict__ h,
                       bf16_t* __restrict__ outh,
                       const float* wq, const float* wk, const float* wv,
                       const float* wo, const float* wg, const float* wu,
                       const float* wd, bf16_t* wAh, bf16_t* wGUh, bf16_t* wdh,
                       float* __restrict__ ctab, float* __restrict__ stab)
{
    int blk = blockIdx.x, tid = threadIdx.x;
    if (blk == 5120) {
        constexpr float kLogF = -0.41524101186092029f;  // -log2(10000)/32
        for (int e = tid; e < 512; e += 256) {
            int hh = e >> 5, p0 = e & 31;
            float f = exp2f((float)p0 * kLogF);
            float ang = (float)hh * f;
            ctab[e] = cosf(ang);
            stab[e] = sinf(ang);
        }
        return;
    }
    if (blk >= 1024) {
        wsplit_body(blk - 1024, tid, wq, wk, wv, wo, wg, wu, wd, wAh, wGUh, wdh);
        return;
    }
    int row = ids[blk];
    f32x4 v = ((const f32x4*)(embed + (size_t)row * 1024))[tid];
    ((f32x4*)(h + (size_t)blk * 1024))[tid] = v;

    float ss = v[0]*v[0] + v[1]*v[1] + v[2]*v[2] + v[3]*v[3];
    #pragma unroll
    for (int m = 1; m < 64; m <<= 1) ss += __shfl_xor(ss, m, 64);
    __shared__ float red[4];
    if ((tid & 63) == 0) red[tid >> 6] = ss;
    __syncthreads();
    float tot = red[0] + red[1] + red[2] + red[3];
    float inv = rsqrtf(tot * (1.0f / 1024.0f) + RMS_EPS);
    f32x4 wt4 = *(const f32x4*)(w + tid * 4);
    bf16x4 hv;
    #pragma unroll
    for (int j = 0; j < 4; ++j) hv[j] = (bf16_t)(v[j] * inv * wt4[j]);
    ((bf16x4*)outh)[(size_t)blk * 256 + tid] = hv;
}

// Flash attention: block (qb,hh) handles q-chunk qb (32 rows), KB=64 keys/tile.
// K/V DOUBLE-BUFFERED with counted vmcnt (12 loads/tile stay in flight while
// the previous tile computes) — no vmcnt(0) drain per tile. 60 KB LDS,
// 2 blocks/CU. Per-tile math order unchanged (bitwise-identical output).
__global__ __launch_bounds__(128, 2)
void flash_attn(const bf16_t* __restrict__ qkvh,
                const bf16_t* __restrict__ vTh, const bf16_t* __restrict__ vTl,
                bf16_t* __restrict__ oh)
{
    __shared__ __align__(16) bf16_t sQ[32*64];
    __shared__ __align__(16) bf16_t sK[2][64*64], sVh[2][64*64], sVl[2][64*64];
    __shared__ __align__(16) bf16_t sPh[32*64], sPl[32*64];

    const int q0 = blockIdx.x * 32;
    const int hh = blockIdx.y;
    const int tid = threadIdx.x, lane = tid & 63, w = tid >> 6;
    const int lr = lane & 15, lg = lane >> 4;

    // stage Q (2 loads/wave)
    #pragma unroll
    for (int ii = 0; ii < 2; ++ii) {
        int r0 = w * 16 + ii * 8;
        int r  = r0 + (lane >> 3);
        int i  = lane & 7;
        GLDS(qkvh + (size_t)(q0 + r) * 3072 + hh * 64 + ((i ^ (r & 7)) << 3),
             sQ + r0 * 64);
    }

    auto stageKV = [&](int t, int buf) {
        const int kv0 = t * 64;
        #pragma unroll
        for (int ii = 0; ii < 4; ++ii) {
            int r0 = w * 32 + ii * 8;
            int r  = r0 + (lane >> 3);
            int i  = lane & 7;
            GLDS(qkvh + (size_t)(kv0 + r) * 3072 + 1024 + hh * 64 + ((i ^ (r & 7)) << 3),
                 sK[buf] + r0 * 64);
            GLDS(vTh + (size_t)(hh * 64 + r) * 1024 + kv0 + ((i ^ (r & 7)) << 3),
                 sVh[buf] + r0 * 64);
            GLDS(vTl + (size_t)(hh * 64 + r) * 1024 + kv0 + ((i ^ (r & 7)) << 3),
                 sVl[buf] + r0 * 64);
        }
    };

    const int ntiles = ((q0 + 31) >> 6) + 1;
    stageKV(0, 0);

    bf16x8 qa[2];
    f32x4 o_acc[4];
    #pragma unroll
    for (int n = 0; n < 4; ++n) o_acc[n] = (f32x4){0.f, 0.f, 0.f, 0.f};
    float m_run[4] = {-1e30f, -1e30f, -1e30f, -1e30f};
    float l_run[4] = {0.f, 0.f, 0.f, 0.f};

    for (int t = 0; t < ntiles; ++t) {
        const int kv0 = t * 64;
        const int buf = t & 1;
        if (t + 1 < ntiles) {
            stageKV(t + 1, buf ^ 1);   // 12 loads stay in flight across barrier
            vmwait<12>();              // tile t (and Q) landed
        } else {
            vmwait<0>();
        }
        bar();
        if (t == 0) {
            #pragma unroll
            for (int ks = 0; ks < 2; ++ks) {
                int r = w * 16 + lr;
                qa[ks] = *(const bf16x8*)((const char*)sQ + r * 128 +
                                          ((((ks << 2) | lg) ^ (r & 7)) << 4));
            }
        }

        f32x4 s_acc[4];
        #pragma unroll
        for (int n = 0; n < 4; ++n) s_acc[n] = (f32x4){0.f, 0.f, 0.f, 0.f};
        #pragma unroll
        for (int ks = 0; ks < 2; ++ks)
            #pragma unroll
            for (int n = 0; n < 4; ++n) {
                int r = n * 16 + lr;
                bf16x8 kb = *(const bf16x8*)((const char*)&sK[buf][0] + r * 128 +
                                             ((((ks << 2) | lg) ^ (r & 7)) << 4));
                s_acc[n] = mfma16(qa[ks], kb, s_acc[n]);
            }

        #pragma unroll
        for (int j = 0; j < 4; ++j) {
            int qr = q0 + w * 16 + lg * 4 + j;
            float p[4];
            float mx = -1e30f;
            #pragma unroll
            for (int n = 0; n < 4; ++n) {
                float sx = s_acc[n][j] * (0.125f * 0.02f);       // x = s*scale/50
                float v = 50.f * (1.f - 2.f / (1.f + __expf(2.f * sx)));
                int key = kv0 + n * 16 + lr;
                if (key > qr) v = -1e30f;
                p[n] = v;
                mx = fmaxf(mx, v);
            }
            #pragma unroll
            for (int m = 1; m < 16; m <<= 1) mx = fmaxf(mx, __shfl_xor(mx, m, 64));
            float mn = fmaxf(m_run[j], mx);
            float ef = __expf(m_run[j] - mn);
            m_run[j] = mn;
            float rs = 0.f;
            #pragma unroll
            for (int n = 0; n < 4; ++n) {
                float e = __expf(p[n] - mn);
                p[n] = e;
                rs += e;
            }
            #pragma unroll
            for (int m = 1; m < 16; m <<= 1) rs += __shfl_xor(rs, m, 64);
            l_run[j] = l_run[j] * ef + rs;
            #pragma unroll
            for (int n = 0; n < 4; ++n) o_acc[n][j] *= ef;
            int r = w * 16 + lg * 4 + j;
            #pragma unroll
            for (int n = 0; n < 4; ++n) {
                int c = n * 16 + lr;
                int byo = r * 128 + ((((c >> 3) ^ (r & 7)) << 4)) + ((c & 7) << 1);
                bf16_t hb = (bf16_t)p[n];
                *(bf16_t*)((char*)sPh + byo) = hb;
                *(bf16_t*)((char*)sPl + byo) = (bf16_t)(p[n] - (float)hb);
            }
        }

        #pragma unroll
        for (int ks = 0; ks < 2; ++ks) {
            int pr = w * 16 + lr;
            int pby = pr * 128 + ((((ks << 2) | lg) ^ (pr & 7)) << 4);
            bf16x8 pa  = *(const bf16x8*)((const char*)sPh + pby);
            bf16x8 pl_ = *(const bf16x8*)((const char*)sPl + pby);
            #pragma unroll
            for (int n = 0; n < 4; ++n) {
                int vr = n * 16 + lr;
                int vby = vr * 128 + ((((ks << 2) | lg) ^ (vr & 7)) << 4);
                bf16x8 vhf = *(const bf16x8*)((const char*)&sVh[buf][0] + vby);
                bf16x8 vlf = *(const bf16x8*)((const char*)&sVl[buf][0] + vby);
                o_acc[n] = mfma16(pa,  vhf, o_acc[n]);
                o_acc[n] = mfma16(pl_, vhf, o_acc[n]);
                o_acc[n] = mfma16(pa,  vlf, o_acc[n]);
            }
        }
        bar();   // all waves done with buf before next iter's stage overwrites it
    }

    #pragma unroll
    for (int j = 0; j < 4; ++j) {
        float inv = 1.0f / l_run[j];
        int qr = q0 + w * 16 + lg * 4 + j;
        #pragma unroll
        for (int n = 0; n < 4; ++n) {
            size_t off = (size_t)qr * 1024 + hh * 64 + n * 16 + lr;
            oh[off] = (bf16_t)(o_acc[n][j] * inv);
        }
    }
}

__global__ __launch_bounds__(256)
void rmsnorm_split(const float* __restrict__ in, const float* __restrict__ w,
                   bf16_t* __restrict__ outh)
{
    int row = blockIdx.x, tid = threadIdx.x;
    f32x4 v = *(const f32x4*)(in + (size_t)row * 1024 + tid * 4);
    float ss = v[0]*v[0] + v[1]*v[1] + v[2]*v[2] + v[3]*v[3];
    #pragma unroll
    for (int m = 1; m < 64; m <<= 1) ss += __shfl_xor(ss, m, 64);
    __shared__ float red[4];
    if ((tid & 63) == 0) red[tid >> 6] = ss;
    __syncthreads();
    float tot = red[0] + red[1] + red[2] + red[3];
    float inv = rsqrtf(tot * (1.0f / 1024.0f) + RMS_EPS);
    f32x4 wt4 = *(const f32x4*)(w + tid * 4);
    bf16x4 hv;
    #pragma unroll
    for (int j = 0; j < 4; ++j) hv[j] = (bf16_t)(v[j] * inv * wt4[j]);
    ((bf16x4*)outh)[(size_t)row * 256 + tid] = hv;
}

extern "C" void kernel_launch(void* const* d_in, const int* in_sizes, int n_in,
                              void* d_out, int out_size, void* d_ws, size_t ws_size,
                              hipStream_t stream)
{
    (void)in_sizes; (void)n_in; (void)out_size; (void)ws_size;
    const int*   x_ids = (const int*)  d_in[0];
    const float* embed = (const float*)d_in[1];
    const float* ln1   = (const float*)d_in[2];
    const float* Wq    = (const float*)d_in[3];
    const float* Wk    = (const float*)d_in[4];
    const float* Wv    = (const float*)d_in[5];
    const float* Wo    = (const float*)d_in[6];
    const float* qn    = (const float*)d_in[7];
    const float* kn    = (const float*)d_in[8];
    const float* ln2   = (const float*)d_in[9];
    const float* Wg    = (const float*)d_in[10];
    const float* Wu    = (const float*)d_in[11];
    const float* Wd    = (const float*)d_in[12];
    const float* lnout = (const float*)d_in[13];
    float* out = (float*)d_out;

    char* ws = (char*)d_ws;
    const size_t MB = 1 << 20;
    float*  h    = (float*) (ws +   0 * MB);  // 4 MB fp32 residual
    bf16_t* hnh  = (bf16_t*)(ws +   4 * MB);
    bf16_t* qkvh = (bf16_t*)(ws +   8 * MB);  // 6 MB [1024][3072] (q,k cols)
    bf16_t* vTh  = (bf16_t*)(ws +  20 * MB);
    bf16_t* vTl  = (bf16_t*)(ws +  22 * MB);
    bf16_t* oh   = (bf16_t*)(ws +  24 * MB);
    // double-buffered packed weight sets (layer l uses set l&1):
    bf16_t* wA[2]  = {(bf16_t*)(ws +  28 * MB), (bf16_t*)(ws +  84 * MB)};
    bf16_t* wGU[2] = {(bf16_t*)(ws +  36 * MB), (bf16_t*)(ws +  92 * MB)};
    bf16_t* wD[2]  = {(bf16_t*)(ws +  52 * MB), (bf16_t*)(ws + 108 * MB)};
    bf16_t* silh = (bf16_t*)(ws +  60 * MB);  //  8 MB [1024][4096]
    float*  wdp  = (float*) (ws +  68 * MB);  // 16 MB split-K partials
    bf16_t* eh   = (bf16_t*)(ws + 116 * MB);  // 62.5 MB
    float*  ctab = (float*) (ws + 179 * MB);  // 2 KB rope cos table
    float*  stab = (float*) (ws + 179 * MB + 4096);  // 2 KB rope sin table

    const long long M1 = 1024 * 1024;
    const int ETOT = 8192000;                 // embed f32x4 units
    const int ESL  = 1365334;                 // per-layer conversion slice

    // gather+rms (1024) | layer-0 weight pack (4096) | rope tables (1)
    gather_rms_wsplit<<<5121, 256, 0, stream>>>(
        x_ids, embed, ln1, h, hnh,
        Wq, Wk, Wv, Wo, Wg, Wu, Wd, wA[0], wGU[0], wD[0], ctab, stab);

    for (int l = 0; l < 6; ++l) {
        const int s = l & 1, nx = s ^ 1;

        // fused QKV + qk-RMSnorm + RoPE + V-transpose (1-plane, 3-buffer)
        gemm_bf16<64,128,2,2,1,EP_QKV,4,3><<<dim3(16,24),256,0,stream>>>(
            hnh, nullptr, wA[s], (float*)vTl, qkvh, vTh, 1024, 1024, 1024, 3072, 0,
            qn + l * 64, kn + l * 64, ctab, stab);

        // fused scores+softcap+mask+softmax+PV (K/V double-buffered); O hi-only
        flash_attn<<<dim3(32,16), 128, 0, stream>>>(qkvh, vTh, vTl, oh);

        // Wo residual (1-plane, 3-buffer, 64^2 tiles)
        gemm_bf16<64,64,2,2,1,EP_RESID,4,3><<<dim3(16,16),256,0,stream>>>(
            oh, nullptr, wA[s] + 3 * M1, h, nullptr, nullptr, 1024, 1024, 1024, 1024, 0,
            nullptr, nullptr, nullptr, nullptr);

        rmsnorm_split<<<1024, 256, 0, stream>>>(h, ln2 + l * 1024, hnh);

        // fused gate+up+silu GEMM + next-layer weight pack (z=1)
        //                         + embed->bf16 slice l (z=2)
        int es = l * ESL, ee = (l + 1) * ESL < ETOT ? (l + 1) * ESL : ETOT;
        gemm_gu_pack<<<dim3(8,32,3), 512, 0, stream>>>(
            hnh, wGU[s], silh,
            l < 5 ? Wq + (size_t)(l+1) * M1 : nullptr,
            l < 5 ? Wk + (size_t)(l+1) * M1 : nullptr,
            l < 5 ? Wv + (size_t)(l+1) * M1 : nullptr,
            l < 5 ? Wo + (size_t)(l+1) * M1 : nullptr,
            l < 5 ? Wg + (size_t)(l+1) * 4 * M1 : nullptr,
            l < 5 ? Wu + (size_t)(l+1) * 4 * M1 : nullptr,
            l < 5 ? Wd + (size_t)(l+1) * 4 * M1 : nullptr,
            wA[nx], wGU[nx], wD[nx],
            embed, eh, es, ee);

        // down-proj: split-K x4 (1-plane, 3-buffer) -> partials
        gemm_bf16<128,128,2,2,1,EP_STORE,4,3><<<dim3(8,8,4),256,0,stream>>>(
            silh, nullptr, wD[s], wdp, nullptr, nullptr, 1024, 4096, 4096, 1024, M1,
            nullptr, nullptr, nullptr, nullptr);

        // reduce partials into h + next pre-norm (ln1[l+1], or ln_out last)
        const float* wnext = (l < 5) ? (ln1 + (l + 1) * 1024) : lnout;
        reduce_rms<<<1024, 256, 0, stream>>>(wdp, h, wnext, hnh);
    }

    // logits: phase-split deep pipeline, 256x256, 8 waves, 128 KB LDS
    gemm_logits8<<<dim3(4,125), 512, 0, stream>>>(hnh, eh, out);
}